// Round 1
// baseline (5634.316 us; speedup 1.0000x reference)
//
#include <hip/hip_runtime.h>
#include <hip/hip_bf16.h>

#define NN 10000
#define EE 160000
#define GG 64
#define DD 480
#define HH 4
#define LLAYERS 6
#define DHD 120
#define NB_ 128

#define INV_DH 0.09128709291752768f
#define INV_SQRT_DEG 0.25335277f
#define INV_AVG_NODES (1.0f/18.03065905448718f)

__device__ __forceinline__ float wsum(float v){
  #pragma unroll
  for (int off=32; off>0; off>>=1) v += __shfl_xor(v, off, 64);
  return v;
}

// ---------------- zero ----------------
__global__ __launch_bounds__(256) void zero_kernel(int* __restrict__ cnt, float* __restrict__ out){
  int i = blockIdx.x*256 + threadIdx.x;
  if (i < NN) cnt[i] = 0;
  if (i < GG) out[i] = 0.f;
}

// ---------------- x = atom_table[node_atom] ----------------
__global__ __launch_bounds__(256) void gather_x_kernel(const float* __restrict__ at,
    const int* __restrict__ atom, float* __restrict__ x){
  int n = blockIdx.x;
  int a = atom[n];
  for (int d = threadIdx.x; d < DD; d += 256)
    x[(size_t)n*DD + d] = at[(size_t)a*DD + d];
}

// ---------------- edge geometry: sh (E x 9), rbf (E x 128) ----------------
__global__ __launch_bounds__(256) void edge_geom_kernel(const float* __restrict__ pos,
    const int* __restrict__ esrc, const int* __restrict__ edst,
    float* __restrict__ sh, float* __restrict__ rbf){
  __shared__ float d_s[256];
  const int e0 = blockIdx.x*256;
  const int e = e0 + threadIdx.x;
  if (e < EE) {
    int s = esrc[e], d = edst[e];
    float vx = pos[s*3+0]-pos[d*3+0];
    float vy = pos[s*3+1]-pos[d*3+1];
    float vz = pos[s*3+2]-pos[d*3+2];
    float rr = sqrtf(vx*vx+vy*vy+vz*vz);
    d_s[threadIdx.x] = rr;
    float r = rr + 1e-12f;
    float x = vx/r, y = vy/r, z = vz/r;
    const float s3 = 1.7320508075688772f;
    const float s5 = 2.23606797749979f;
    const float s15 = 3.872983346207417f;
    float* o = sh + (size_t)e*9;
    o[0] = 1.f;
    o[1] = s3*x; o[2] = s3*y; o[3] = s3*z;
    o[4] = s15*x*y; o[5] = s15*y*z;
    o[6] = 0.5f*s5*(3.f*z*z-1.f);
    o[7] = s15*x*z;
    o[8] = 0.5f*s15*(x*x-y*y);
  }
  __syncthreads();
  const float wdt = 5.0f/128.0f;
  const float stp = 5.0f/127.0f;
  #pragma unroll 4
  for (int it = 0; it < 128; ++it) {
    int idx = it*256 + threadIdx.x;
    int el = idx >> 7, j = idx & 127;
    int ee = e0 + el;
    if (ee < EE) {
      float zz = (d_s[el] - stp*(float)j) / wdt;
      rbf[(size_t)ee*NB_ + j] = __expf(-zz*zz);
    }
  }
}

// ---------------- sort by dst ----------------
__global__ __launch_bounds__(256) void hist_kernel(const int* __restrict__ edst, int* __restrict__ cnt){
  int e = blockIdx.x*256 + threadIdx.x;
  if (e < EE) atomicAdd(&cnt[edst[e]], 1);
}

__global__ __launch_bounds__(1024) void scan_kernel(const int* __restrict__ cnt,
    int* __restrict__ row_ptr, int* __restrict__ cursor){
  __shared__ int sd[1024];
  __shared__ int s_carry;
  if (threadIdx.x == 0) s_carry = 0;
  __syncthreads();
  for (int base = 0; base < NN; base += 1024) {
    int i = base + threadIdx.x;
    int v = (i < NN) ? cnt[i] : 0;
    sd[threadIdx.x] = v;
    __syncthreads();
    for (int off = 1; off < 1024; off <<= 1) {
      int t = 0;
      if ((int)threadIdx.x >= off) t = sd[threadIdx.x - off];
      __syncthreads();
      sd[threadIdx.x] += t;
      __syncthreads();
    }
    int incl = sd[threadIdx.x];
    int carry = s_carry;
    if (i < NN) { row_ptr[i] = carry + incl - v; cursor[i] = carry + incl - v; }
    __syncthreads();
    if (threadIdx.x == 1023) s_carry = carry + incl;
    __syncthreads();
  }
  if (threadIdx.x == 0) row_ptr[NN] = s_carry;
}

__global__ __launch_bounds__(256) void scatter_kernel(const int* __restrict__ esrc,
    const int* __restrict__ edst, int* __restrict__ cursor,
    int* __restrict__ eid, int* __restrict__ srcs){
  int e = blockIdx.x*256 + threadIdx.x;
  if (e < EE) {
    int n = edst[e];
    int p = atomicAdd(&cursor[n], 1);
    eid[p] = e;
    srcs[p] = esrc[e];
  }
}

// ---------------- generic tiled f32 GEMM: C[M,Nc] = act(A[M,K] @ B[K,Nc]) ----------------
template<int SILU>
__global__ __launch_bounds__(256) void gemm_f32_kernel(
    const float* __restrict__ A, const float* __restrict__ B, float* __restrict__ C,
    int M, int K, int Nc) {
  __shared__ float As[16][68];
  __shared__ float Bs[16][68];
  const int tid = threadIdx.x;
  const int tx = tid & 15, ty = tid >> 4;
  const long long m0 = (long long)blockIdx.y * 64;
  const int n0 = blockIdx.x * 64;
  const int lm  = tid >> 2;
  const int lk4 = (tid & 3) << 2;
  const int lbk = tid >> 4;
  const int lbn = (tid & 15) << 2;
  float acc[4][4] = {};
  for (int kt = 0; kt < K; kt += 16) {
    float4 av = make_float4(0.f,0.f,0.f,0.f);
    if (m0 + lm < M)
      av = *reinterpret_cast<const float4*>(A + (m0+lm)*K + kt + lk4);
    As[lk4+0][lm]=av.x; As[lk4+1][lm]=av.y; As[lk4+2][lm]=av.z; As[lk4+3][lm]=av.w;
    float4 bv = make_float4(0.f,0.f,0.f,0.f);
    const float* bp = B + (long long)(kt+lbk)*Nc + n0 + lbn;
    if (n0 + lbn + 3 < Nc) {
      bv = *reinterpret_cast<const float4*>(bp);
    } else {
      if (n0+lbn+0 < Nc) bv.x = bp[0];
      if (n0+lbn+1 < Nc) bv.y = bp[1];
      if (n0+lbn+2 < Nc) bv.z = bp[2];
    }
    *reinterpret_cast<float4*>(&Bs[lbk][lbn]) = bv;
    __syncthreads();
    #pragma unroll
    for (int kk = 0; kk < 16; ++kk) {
      const float4 a = *reinterpret_cast<const float4*>(&As[kk][ty<<2]);
      const float4 b = *reinterpret_cast<const float4*>(&Bs[kk][tx<<2]);
      acc[0][0] += a.x*b.x; acc[0][1] += a.x*b.y; acc[0][2] += a.x*b.z; acc[0][3] += a.x*b.w;
      acc[1][0] += a.y*b.x; acc[1][1] += a.y*b.y; acc[1][2] += a.y*b.z; acc[1][3] += a.y*b.w;
      acc[2][0] += a.z*b.x; acc[2][1] += a.z*b.y; acc[2][2] += a.z*b.z; acc[2][3] += a.z*b.w;
      acc[3][0] += a.w*b.x; acc[3][1] += a.w*b.y; acc[3][2] += a.w*b.z; acc[3][3] += a.w*b.w;
    }
    __syncthreads();
  }
  #pragma unroll
  for (int i = 0; i < 4; ++i) {
    long long m = m0 + (ty<<2) + i;
    if (m < M) {
      #pragma unroll
      for (int j = 0; j < 4; ++j) {
        int nn = n0 + (tx<<2) + j;
        if (nn < Nc) {
          float v = acc[i][j];
          if (SILU) v = v / (1.f + __expf(-v));
          C[m*Nc + nn] = v;
        }
      }
    }
  }
}

// ---------------- small final matmul: out[M,NC] = T[M,64] @ W[64,NC] ----------------
template<int NC>
__global__ __launch_bounds__(256) void colmat_kernel(const float* __restrict__ Tin,
    const float* __restrict__ W, float* __restrict__ outv, int M) {
  int e = blockIdx.x*256 + threadIdx.x;
  if (e >= M) return;
  const float* row = Tin + (size_t)e*64;
  float acc[NC];
  #pragma unroll
  for (int c = 0; c < NC; ++c) acc[c] = 0.f;
  #pragma unroll 8
  for (int j = 0; j < 64; ++j) {
    float tv = row[j];
    #pragma unroll
    for (int c = 0; c < NC; ++c) acc[c] += tv * W[j*NC + c];
  }
  #pragma unroll
  for (int c = 0; c < NC; ++c) outv[(size_t)e*NC + c] = acc[c];
}

// ---------------- deg: x[n] += ((sum_e g0*sh) @ Wdeg) * scale ----------------
__global__ __launch_bounds__(64) void deg_kernel(const float* __restrict__ g0,
    const float* __restrict__ sh, const int* __restrict__ row_ptr,
    const int* __restrict__ eid, const float* __restrict__ Wdeg, float* __restrict__ x) {
  const int n = blockIdx.x, lane = threadIdx.x;
  const int e0 = row_ptr[n], e1 = row_ptr[n+1];
  float s9[9] = {0,0,0,0,0,0,0,0,0};
  for (int p = e0 + lane; p < e1; p += 64) {
    int e = eid[p];
    float g = g0[e];
    const float* srow = sh + (size_t)e*9;
    #pragma unroll
    for (int s = 0; s < 9; ++s) s9[s] += g*srow[s];
  }
  #pragma unroll
  for (int s = 0; s < 9; ++s) s9[s] = wsum(s9[s]);
  #pragma unroll
  for (int r = 0; r < 8; ++r) {
    int d = lane + (r<<6);
    if (d < DD) {
      float acc = 0.f;
      #pragma unroll
      for (int s = 0; s < 9; ++s) acc += s9[s]*Wdeg[s*DD + d];
      x[(size_t)n*DD + d] += acc * INV_SQRT_DEG;
    }
  }
}

// ---------------- P[n,h,s] = sum_{d in head h} xq[n,d]*Wsh[s,d] ----------------
__global__ __launch_bounds__(64) void p_kernel(const float* __restrict__ xq,
    const float* __restrict__ Wsh_l, float* __restrict__ P) {
  const int n = blockIdx.x, lane = threadIdx.x;
  if (lane < 36) {
    int h = lane / 9, s = lane % 9;
    const float* q = xq + (size_t)n*DD + h*DHD;
    const float* w = Wsh_l + s*DD + h*DHD;
    float acc = 0.f;
    #pragma unroll 8
    for (int d = 0; d < DHD; ++d) acc += q[d]*w[d];
    P[(size_t)n*36 + lane] = acc;
  }
}

// ---------------- fused attention (per node, one wave) ----------------
__global__ __launch_bounds__(64) void attn_kernel(
    const float* __restrict__ xq, const float* __restrict__ xk, const float* __restrict__ xv,
    const float* __restrict__ sh, const float* __restrict__ gate, const float* __restrict__ P,
    const int* __restrict__ row_ptr, const int* __restrict__ eid, const int* __restrict__ srcs,
    float* __restrict__ aggout) {
  const int n = blockIdx.x, lane = threadIdx.x;
  __shared__ float q_s[DD];
  __shared__ float P_s[36];
  __shared__ float l_s[64][4];
  __shared__ int   src_s[64];
  __shared__ float m_s[4], den_s[4], f_s[4];
  const int e0 = row_ptr[n], e1 = row_ptr[n+1];
  #pragma unroll
  for (int r = 0; r < 8; ++r) { int d = lane + (r<<6); if (d < DD) q_s[d] = xq[(size_t)n*DD + d]; }
  if (lane < 36) P_s[lane] = P[(size_t)n*36 + lane];
  if (lane < 4) { m_s[lane] = -1e30f; den_s[lane] = 0.f; }
  __syncthreads();
  float agg[8] = {0,0,0,0,0,0,0,0};
  const int hh = lane >> 4;    // head of this lane (logit phase)
  const int li = lane & 15;
  for (int c0 = e0; c0 < e1; c0 += 64) {
    const int cn = min(64, e1 - c0);
    // logits
    for (int i = 0; i < cn; ++i) {
      const int p = c0 + i;
      const int e = eid[p];
      const int s = srcs[p];
      if (lane == 0) src_s[i] = s;
      const float* krow = xk + (size_t)s*DD;
      float acc = 0.f;
      #pragma unroll
      for (int r = 0; r < 8; ++r) {
        int dd = li + (r<<4);
        if (dd < DHD) {
          int d = hh*DHD + dd;
          acc += q_s[d]*krow[d];
        }
      }
      #pragma unroll
      for (int off = 1; off < 16; off <<= 1) acc += __shfl_xor(acc, off, 64);
      if (li == 0) {
        float lp = 0.f;
        const float* srow = sh + (size_t)e*9;
        #pragma unroll
        for (int ss = 0; ss < 9; ++ss) lp += srow[ss]*P_s[hh*9 + ss];
        l_s[i][hh] = (acc + lp) * INV_DH * gate[(size_t)e*4 + hh];
      }
    }
    __syncthreads();
    // online softmax update
    {
      const int h = lane & 3, i0 = lane >> 2;
      float cm = -1e30f;
      for (int i = i0; i < cn; i += 16) cm = fmaxf(cm, l_s[i][h]);
      #pragma unroll
      for (int off = 4; off < 64; off <<= 1) cm = fmaxf(cm, __shfl_xor(cm, off, 64));
      const float mold = m_s[h];
      const float newm = fmaxf(mold, cm);
      const float f = __expf(mold - newm);
      float cs = 0.f;
      for (int i = i0; i < cn; i += 16) {
        float a = __expf(l_s[i][h] - newm);
        l_s[i][h] = a;
        cs += a;
      }
      #pragma unroll
      for (int off = 4; off < 64; off <<= 1) cs += __shfl_xor(cs, off, 64);
      __syncthreads();
      if (i0 == 0) { m_s[h] = newm; den_s[h] = den_s[h]*f + cs; f_s[h] = f; }
    }
    __syncthreads();
    #pragma unroll
    for (int r = 0; r < 8; ++r) { int d = lane + (r<<6); if (d < DD) agg[r] *= f_s[d/DHD]; }
    // aggregate
    for (int i = 0; i < cn; ++i) {
      const int s = src_s[i];
      const float* vrow = xv + (size_t)s*DD;
      #pragma unroll
      for (int r = 0; r < 8; ++r) {
        int d = lane + (r<<6);
        if (d < DD) agg[r] += l_s[i][d/DHD]*vrow[d];
      }
    }
    __syncthreads();
  }
  #pragma unroll
  for (int r = 0; r < 8; ++r) {
    int d = lane + (r<<6);
    if (d < DD) aggout[(size_t)n*DD + d] = agg[r]/(den_s[d/DHD] + 1e-12f) * INV_SQRT_DEG;
  }
}

// ---------------- residual + LayerNorm: x = LN(x + t) ----------------
__global__ __launch_bounds__(64) void ln_kernel(float* __restrict__ x, const float* __restrict__ t) {
  const int n = blockIdx.x, lane = threadIdx.x;
  float v[8];
  float s = 0.f, s2 = 0.f;
  #pragma unroll
  for (int r = 0; r < 8; ++r) {
    int d = lane + (r<<6);
    if (d < DD) {
      float vv = x[(size_t)n*DD + d] + t[(size_t)n*DD + d];
      v[r] = vv; s += vv; s2 += vv*vv;
    }
  }
  s = wsum(s); s2 = wsum(s2);
  const float mu = s * (1.f/(float)DD);
  const float var = s2 * (1.f/(float)DD) - mu*mu;
  const float rs = rsqrtf(var + 1e-5f);
  #pragma unroll
  for (int r = 0; r < 8; ++r) {
    int d = lane + (r<<6);
    if (d < DD) x[(size_t)n*DD + d] = (v[r]-mu)*rs;
  }
}

// ---------------- final: energy += (t[n] . Wh2) / AVG_NODES into out[batch[n]] ----------------
__global__ __launch_bounds__(64) void h2_kernel(const float* __restrict__ t,
    const float* __restrict__ Wh2, const int* __restrict__ batch, float* __restrict__ out) {
  const int n = blockIdx.x, lane = threadIdx.x;
  float s = 0.f;
  #pragma unroll
  for (int r = 0; r < 8; ++r) {
    int d = lane + (r<<6);
    if (d < DD) s += t[(size_t)n*DD + d]*Wh2[d];
  }
  s = wsum(s);
  if (lane == 0) atomicAdd(&out[batch[n]], s * INV_AVG_NODES);
}

extern "C" void kernel_launch(void* const* d_in, const int* in_sizes, int n_in,
                              void* d_out, int out_size, void* d_ws, size_t ws_size,
                              hipStream_t stream) {
  const float* pos        = (const float*)d_in[0];
  const int*   node_atom  = (const int*)  d_in[1];
  const int*   edge_src   = (const int*)  d_in[2];
  const int*   edge_dst   = (const int*)  d_in[3];
  const int*   batch      = (const int*)  d_in[4];
  const float* atom_table = (const float*)d_in[5];
  const float* Wdeg       = (const float*)d_in[6];
  const float* Wd1        = (const float*)d_in[7];
  const float* Wd2        = (const float*)d_in[8];
  const float* Wd3        = (const float*)d_in[9];
  const float* Wq         = (const float*)d_in[10];
  const float* Wk         = (const float*)d_in[11];
  const float* Wv         = (const float*)d_in[12];
  const float* Wsh        = (const float*)d_in[13];
  const float* W1         = (const float*)d_in[14];
  const float* W2         = (const float*)d_in[15];
  const float* W3         = (const float*)d_in[16];
  const float* Wo         = (const float*)d_in[17];
  const float* Wf1        = (const float*)d_in[18];
  const float* Wf2        = (const float*)d_in[19];
  const float* Wh1        = (const float*)d_in[20];
  const float* Wh2        = (const float*)d_in[21];
  float* out = (float*)d_out;
  float* ws  = (float*)d_ws;

  // ---- workspace layout (floats) ----
  const size_t off_x    = 0;
  const size_t off_xq   = off_x   + (size_t)NN*DD;
  const size_t off_xk   = off_xq  + (size_t)NN*DD;
  const size_t off_xv   = off_xk  + (size_t)NN*DD;
  const size_t off_sh   = off_xv  + (size_t)NN*DD;
  const size_t off_rbf  = off_sh  + (size_t)EE*9;
  const size_t off_gate = off_rbf + (size_t)EE*NB_;
  const size_t off_P    = off_gate+ (size_t)EE*4;
  const size_t off_g0   = off_P   + (size_t)NN*36;
  const size_t off_pool = off_g0  + (size_t)EE;
  const size_t pool_sz  = 2*(size_t)EE*64;  // >= agg+tmp480+tmp960
  const size_t off_int  = off_pool + pool_sz;

  float* x    = ws + off_x;
  float* xq   = ws + off_xq;
  float* xk   = ws + off_xk;
  float* xv   = ws + off_xv;
  float* shb  = ws + off_sh;
  float* rbf  = ws + off_rbf;
  float* gate = ws + off_gate;
  float* P    = ws + off_P;
  float* g0   = ws + off_g0;
  // pool aliases
  float* t64a   = ws + off_pool;                       // E*64
  float* t64b   = ws + off_pool + (size_t)EE*64;       // E*64
  float* agg    = ws + off_pool;                       // N*480
  float* tmp480 = ws + off_pool + (size_t)NN*DD;       // N*480
  float* tmp960 = ws + off_pool + 2*(size_t)NN*DD;     // N*960

  int* cnt     = (int*)(ws + off_int);
  int* row_ptr = cnt + NN;
  int* cursor  = row_ptr + NN + 1;
  int* eid     = cursor + NN;
  int* srcs    = eid + EE;

  auto gemm = [&](const float* A, const float* B, float* C, int M, int K, int Nc, bool act){
    dim3 g((Nc+63)/64, (M+63)/64);
    if (act) gemm_f32_kernel<1><<<g, 256, 0, stream>>>(A, B, C, M, K, Nc);
    else     gemm_f32_kernel<0><<<g, 256, 0, stream>>>(A, B, C, M, K, Nc);
  };

  // setup
  zero_kernel<<<(NN+255)/256, 256, 0, stream>>>(cnt, out);
  gather_x_kernel<<<NN, 256, 0, stream>>>(atom_table, node_atom, x);
  edge_geom_kernel<<<(EE+255)/256, 256, 0, stream>>>(pos, edge_src, edge_dst, shb, rbf);
  hist_kernel<<<(EE+255)/256, 256, 0, stream>>>(edge_dst, cnt);
  scan_kernel<<<1, 1024, 0, stream>>>(cnt, row_ptr, cursor);
  scatter_kernel<<<(EE+255)/256, 256, 0, stream>>>(edge_src, edge_dst, cursor, eid, srcs);

  // g0 = silu(silu(rbf@Wd1)@Wd2)@Wd3 ; deg update
  gemm(rbf, Wd1, t64a, EE, NB_, 64, true);
  gemm(t64a, Wd2, t64b, EE, 64, 64, true);
  colmat_kernel<1><<<(EE+255)/256, 256, 0, stream>>>(t64b, Wd3, g0, EE);
  deg_kernel<<<NN, 64, 0, stream>>>(g0, shb, row_ptr, eid, Wdeg, x);

  for (int l = 0; l < LLAYERS; ++l) {
    const float* Wq_l  = Wq  + (size_t)l*DD*DD;
    const float* Wk_l  = Wk  + (size_t)l*DD*DD;
    const float* Wv_l  = Wv  + (size_t)l*DD*DD;
    const float* Wsh_l = Wsh + (size_t)l*9*DD;
    const float* W1_l  = W1  + (size_t)l*NB_*64;
    const float* W2_l  = W2  + (size_t)l*64*64;
    const float* W3_l  = W3  + (size_t)l*64*4;
    const float* Wo_l  = Wo  + (size_t)l*DD*DD;
    const float* Wf1_l = Wf1 + (size_t)l*DD*(2*DD);
    const float* Wf2_l = Wf2 + (size_t)l*(2*DD)*DD;

    gemm(x, Wq_l, xq, NN, DD, DD, false);
    gemm(x, Wk_l, xk, NN, DD, DD, false);
    gemm(x, Wv_l, xv, NN, DD, DD, false);
    p_kernel<<<NN, 64, 0, stream>>>(xq, Wsh_l, P);
    gemm(rbf, W1_l, t64a, EE, NB_, 64, true);
    gemm(t64a, W2_l, t64b, EE, 64, 64, true);
    colmat_kernel<4><<<(EE+255)/256, 256, 0, stream>>>(t64b, W3_l, gate, EE);
    attn_kernel<<<NN, 64, 0, stream>>>(xq, xk, xv, shb, gate, P, row_ptr, eid, srcs, agg);
    gemm(agg, Wo_l, tmp480, NN, DD, DD, false);
    ln_kernel<<<NN, 64, 0, stream>>>(x, tmp480);
    gemm(x, Wf1_l, tmp960, NN, DD, 2*DD, true);
    gemm(tmp960, Wf2_l, tmp480, NN, 2*DD, DD, false);
    ln_kernel<<<NN, 64, 0, stream>>>(x, tmp480);
  }

  gemm(x, Wh1, tmp480, NN, DD, DD, true);
  h2_kernel<<<NN, 64, 0, stream>>>(tmp480, Wh2, batch, out);
}

// Round 2
// 2440.594 us; speedup vs baseline: 2.3086x; 2.3086x over previous
//
#include <hip/hip_runtime.h>
#include <hip/hip_bf16.h>

#define NN 10000
#define EE 160000
#define GG 64
#define DD 480
#define HH 4
#define LLAYERS 6
#define DHD 120
#define NB_ 128

#define INV_DH 0.09128709291752768f
#define INV_SQRT_DEG 0.25335277f
#define INV_AVG_NODES (1.0f/18.03065905448718f)

typedef __attribute__((ext_vector_type(8))) short bf16x8;
typedef __attribute__((ext_vector_type(4))) float f32x4;
typedef __attribute__((ext_vector_type(8))) unsigned short u16x8;

__device__ __forceinline__ float b2f(unsigned short u){ return __uint_as_float(((unsigned)u)<<16); }
__device__ __forceinline__ unsigned short f2b(float f){
  unsigned u = __float_as_uint(f);
  return (unsigned short)((u + 0x7fffu + ((u>>16)&1u)) >> 16);
}
__device__ __forceinline__ float wsum(float v){
  #pragma unroll
  for (int off=32; off>0; off>>=1) v += __shfl_xor(v, off, 64);
  return v;
}
__device__ __forceinline__ void glds16(const void* g, void* l) {
  __builtin_amdgcn_global_load_lds((const __attribute__((address_space(1))) unsigned int*)g,
                                   (__attribute__((address_space(3))) unsigned int*)l, 16, 0, 0);
}

// ---------------- zero ----------------
__global__ __launch_bounds__(256) void zero_kernel(int* __restrict__ cnt, float* __restrict__ out){
  int i = blockIdx.x*256 + threadIdx.x;
  if (i < NN) cnt[i] = 0;
  if (i < GG) out[i] = 0.f;
}

// ---------------- x = atom_table[node_atom] ----------------
__global__ __launch_bounds__(256) void gather_x_kernel(const float* __restrict__ at,
    const int* __restrict__ atom, float* __restrict__ x){
  int n = blockIdx.x;
  int a = atom[n];
  for (int d = threadIdx.x; d < DD; d += 256)
    x[(size_t)n*DD + d] = at[(size_t)a*DD + d];
}

// ---------------- edge geometry: sh (E x 9 f32), rbf (E x 128 bf16) ----------------
__global__ __launch_bounds__(256) void edge_geom_kernel(const float* __restrict__ pos,
    const int* __restrict__ esrc, const int* __restrict__ edst,
    float* __restrict__ sh, __hip_bfloat16* __restrict__ rbf){
  __shared__ float d_s[256];
  const int e0 = blockIdx.x*256;
  const int e = e0 + threadIdx.x;
  if (e < EE) {
    int s = esrc[e], d = edst[e];
    float vx = pos[s*3+0]-pos[d*3+0];
    float vy = pos[s*3+1]-pos[d*3+1];
    float vz = pos[s*3+2]-pos[d*3+2];
    float rr = sqrtf(vx*vx+vy*vy+vz*vz);
    d_s[threadIdx.x] = rr;
    float r = rr + 1e-12f;
    float x = vx/r, y = vy/r, z = vz/r;
    const float s3 = 1.7320508075688772f;
    const float s5 = 2.23606797749979f;
    const float s15 = 3.872983346207417f;
    float* o = sh + (size_t)e*9;
    o[0] = 1.f;
    o[1] = s3*x; o[2] = s3*y; o[3] = s3*z;
    o[4] = s15*x*y; o[5] = s15*y*z;
    o[6] = 0.5f*s5*(3.f*z*z-1.f);
    o[7] = s15*x*z;
    o[8] = 0.5f*s15*(x*x-y*y);
  }
  __syncthreads();
  const float wdt = 5.0f/128.0f;
  const float stp = 5.0f/127.0f;
  #pragma unroll 4
  for (int it = 0; it < 128; ++it) {
    int idx = it*256 + threadIdx.x;
    int el = idx >> 7, j = idx & 127;
    int ee = e0 + el;
    if (ee < EE) {
      float zz = (d_s[el] - stp*(float)j) / wdt;
      rbf[(size_t)ee*NB_ + j] = __hip_bfloat16(); // placeholder overwritten below
      unsigned short b = f2b(__expf(-zz*zz));
      ((unsigned short*)rbf)[(size_t)ee*NB_ + j] = b;
    }
  }
}

// ---------------- sort by dst ----------------
__global__ __launch_bounds__(256) void hist_kernel(const int* __restrict__ edst, int* __restrict__ cnt){
  int e = blockIdx.x*256 + threadIdx.x;
  if (e < EE) atomicAdd(&cnt[edst[e]], 1);
}

__global__ __launch_bounds__(1024) void scan_kernel(const int* __restrict__ cnt,
    int* __restrict__ row_ptr, int* __restrict__ cursor){
  __shared__ int sd[1024];
  __shared__ int s_carry;
  if (threadIdx.x == 0) s_carry = 0;
  __syncthreads();
  for (int base = 0; base < NN; base += 1024) {
    int i = base + threadIdx.x;
    int v = (i < NN) ? cnt[i] : 0;
    sd[threadIdx.x] = v;
    __syncthreads();
    for (int off = 1; off < 1024; off <<= 1) {
      int t = 0;
      if ((int)threadIdx.x >= off) t = sd[threadIdx.x - off];
      __syncthreads();
      sd[threadIdx.x] += t;
      __syncthreads();
    }
    int incl = sd[threadIdx.x];
    int carry = s_carry;
    if (i < NN) { row_ptr[i] = carry + incl - v; cursor[i] = carry + incl - v; }
    __syncthreads();
    if (threadIdx.x == 1023) s_carry = carry + incl;
    __syncthreads();
  }
  if (threadIdx.x == 0) row_ptr[NN] = s_carry;
}

__global__ __launch_bounds__(256) void scatter_kernel(const int* __restrict__ esrc,
    const int* __restrict__ edst, int* __restrict__ cursor,
    int* __restrict__ eid, int* __restrict__ srcs){
  int e = blockIdx.x*256 + threadIdx.x;
  if (e < EE) {
    int n = edst[e];
    int p = atomicAdd(&cursor[n], 1);
    eid[p] = e;
    srcs[p] = esrc[e];
  }
}

// ---------------- weight transpose+convert: Wt[n][k] = bf16(W[k][n]), zero pad rows ----------------
__global__ __launch_bounds__(256) void transpose_w_kernel(const float* __restrict__ W,
    __hip_bfloat16* __restrict__ Wt, int K, int N, int Npad) {
  __shared__ float T[32][33];
  const int l = blockIdx.z;
  W  += (size_t)l*K*N;
  Wt += (size_t)l*Npad*K;
  const int k0 = blockIdx.y*32, n0 = blockIdx.x*32;
  const int tx = threadIdx.x & 31, ty = threadIdx.x >> 5;
  #pragma unroll
  for (int r = 0; r < 32; r += 8) {
    int k = k0 + ty + r, n = n0 + tx;
    T[ty+r][tx] = (k < K && n < N) ? W[(size_t)k*N + n] : 0.f;
  }
  __syncthreads();
  #pragma unroll
  for (int r = 0; r < 32; r += 8) {
    int n = n0 + ty + r, k = k0 + tx;
    if (n < Npad && k < K)
      ((unsigned short*)Wt)[(size_t)n*K + k] = f2b(T[tx][ty+r]);
  }
}

// ---------------- bf16 MFMA GEMM: C[M,Nc] = act(A[M,K] @ Bt[n][k]^T) ----------------
// A bf16 [M,K]; Bt bf16 [Npad,K] (transposed, padded); tile 128x64x32, 4 waves.
template<int SILU, int WF32, int WB16>
__global__ __launch_bounds__(256) void gemm_bf16_kernel(
    const __hip_bfloat16* __restrict__ A, const __hip_bfloat16* __restrict__ Bt,
    float* __restrict__ Cf, __hip_bfloat16* __restrict__ Cb,
    int M, int K, int Nc) {
  __shared__ char smem[(512 + 256) * 16];   // As 8192 B + Bs 4096 B
  char* AsB = smem;
  char* BsB = smem + 8192;
  const int tid = threadIdx.x;
  const int lane = tid & 63, wid = tid >> 6;
  const int wm = wid >> 1, wn = wid & 1;
  const long long m0 = (long long)blockIdx.y * 128;
  const int n0 = blockIdx.x * 64;

  // A staging: it0: khi=wid>>1, rows (wid&1)*64+lane; it1: khi=2+(wid>>1)
  const int arow_loc = (wid & 1)*64 + lane;
  long long gr = m0 + arow_loc; if (gr >= M) gr = M - 1;
  const __hip_bfloat16* aptr = A + gr * (size_t)K;
  const int khiA0 = wid >> 1, khiA1 = 2 + (wid >> 1);
  char* adst0 = AsB + wid*64*16;
  char* adst1 = AsB + 4096 + wid*64*16;
  // B staging: khi=wid, col=lane
  const __hip_bfloat16* bptr = Bt + (size_t)(n0 + lane) * K;
  char* bdst = BsB + wid*64*16;

  f32x4 acc[4][2];
  #pragma unroll
  for (int i = 0; i < 4; ++i)
    #pragma unroll
    for (int j = 0; j < 2; ++j)
      acc[i][j] = (f32x4){0.f,0.f,0.f,0.f};

  const int lr = lane & 15, lkh = lane >> 4;

  for (int kt = 0; kt < K; kt += 32) {
    __syncthreads();
    glds16(aptr + kt + khiA0*8, adst0);
    glds16(aptr + kt + khiA1*8, adst1);
    glds16(bptr + kt + wid*8, bdst);
    __syncthreads();
    bf16x8 afr[4], bfr[2];
    #pragma unroll
    for (int fm = 0; fm < 4; ++fm)
      afr[fm] = *reinterpret_cast<const bf16x8*>(AsB + (lkh*128 + wm*64 + fm*16 + lr)*16);
    #pragma unroll
    for (int fn = 0; fn < 2; ++fn)
      bfr[fn] = *reinterpret_cast<const bf16x8*>(BsB + (lkh*64 + wn*32 + fn*16 + lr)*16);
    #pragma unroll
    for (int fm = 0; fm < 4; ++fm)
      #pragma unroll
      for (int fn = 0; fn < 2; ++fn)
        acc[fm][fn] = __builtin_amdgcn_mfma_f32_16x16x32_bf16(afr[fm], bfr[fn], acc[fm][fn], 0, 0, 0);
  }

  #pragma unroll
  for (int fm = 0; fm < 4; ++fm) {
    #pragma unroll
    for (int fn = 0; fn < 2; ++fn) {
      #pragma unroll
      for (int j = 0; j < 4; ++j) {
        long long r = m0 + wm*64 + fm*16 + lkh*4 + j;
        int c = n0 + wn*32 + fn*16 + lr;
        if (r < M && c < Nc) {
          float v = acc[fm][fn][j];
          if (SILU) v = v / (1.f + __expf(-v));
          if (WF32) Cf[r*(size_t)Nc + c] = v;
          if (WB16) ((unsigned short*)Cb)[r*(size_t)Nc + c] = f2b(v);
        }
      }
    }
  }
}

// ---------------- small final matmul: out[M,NC] = Tin[M,64](bf16) @ W[64,NC](f32) ----------------
template<int NC>
__global__ __launch_bounds__(256) void colmat_kernel(const __hip_bfloat16* __restrict__ Tin,
    const float* __restrict__ W, float* __restrict__ outv, int M) {
  int e = blockIdx.x*256 + threadIdx.x;
  if (e >= M) return;
  const unsigned short* row = (const unsigned short*)(Tin + (size_t)e*64);
  float acc[NC];
  #pragma unroll
  for (int c = 0; c < NC; ++c) acc[c] = 0.f;
  #pragma unroll
  for (int jb = 0; jb < 8; ++jb) {
    u16x8 v = *reinterpret_cast<const u16x8*>(row + jb*8);
    #pragma unroll
    for (int j = 0; j < 8; ++j) {
      float tv = b2f(v[j]);
      #pragma unroll
      for (int c = 0; c < NC; ++c) acc[c] += tv * W[(jb*8+j)*NC + c];
    }
  }
  #pragma unroll
  for (int c = 0; c < NC; ++c) outv[(size_t)e*NC + c] = acc[c];
}

// ---------------- deg: x[n] += ((sum_e g0*sh) @ Wdeg) * scale ; xb = bf16(x) ----------------
__global__ __launch_bounds__(64) void deg_kernel(const float* __restrict__ g0,
    const float* __restrict__ sh, const int* __restrict__ row_ptr,
    const int* __restrict__ eid, const float* __restrict__ Wdeg,
    float* __restrict__ x, __hip_bfloat16* __restrict__ xb) {
  const int n = blockIdx.x, lane = threadIdx.x;
  const int e0 = row_ptr[n], e1 = row_ptr[n+1];
  float s9[9] = {0,0,0,0,0,0,0,0,0};
  for (int p = e0 + lane; p < e1; p += 64) {
    int e = eid[p];
    float g = g0[e];
    const float* srow = sh + (size_t)e*9;
    #pragma unroll
    for (int s = 0; s < 9; ++s) s9[s] += g*srow[s];
  }
  #pragma unroll
  for (int s = 0; s < 9; ++s) s9[s] = wsum(s9[s]);
  #pragma unroll
  for (int r = 0; r < 8; ++r) {
    int d = lane + (r<<6);
    if (d < DD) {
      float acc = 0.f;
      #pragma unroll
      for (int s = 0; s < 9; ++s) acc += s9[s]*Wdeg[s*DD + d];
      float vv = x[(size_t)n*DD + d] + acc * INV_SQRT_DEG;
      x[(size_t)n*DD + d] = vv;
      ((unsigned short*)xb)[(size_t)n*DD + d] = f2b(vv);
    }
  }
}

// ---------------- P[n,h,s] = sum_{d in head h} xq[n,d]*Wsh[s,d] ----------------
__global__ __launch_bounds__(64) void p_kernel(const __hip_bfloat16* __restrict__ xq,
    const float* __restrict__ Wsh_l, float* __restrict__ P) {
  const int n = blockIdx.x, lane = threadIdx.x;
  if (lane >= 36) return;
  int h = lane/9, s = lane%9;
  const unsigned short* q = (const unsigned short*)(xq + (size_t)n*DD + h*DHD);
  const float* w = Wsh_l + s*DD + h*DHD;
  float acc = 0.f;
  #pragma unroll
  for (int db = 0; db < 15; ++db) {
    u16x8 v = *reinterpret_cast<const u16x8*>(q + db*8);
    #pragma unroll
    for (int j = 0; j < 8; ++j) acc += b2f(v[j])*w[db*8+j];
  }
  P[(size_t)n*36 + lane] = acc;
}

// ---------------- fused attention: 1 node per wave, 4 waves/block, no barriers ----------------
__global__ __launch_bounds__(256) void attn_kernel(
    const __hip_bfloat16* __restrict__ xq, const __hip_bfloat16* __restrict__ xk,
    const __hip_bfloat16* __restrict__ xv,
    const float* __restrict__ sh, const float* __restrict__ gate, const float* __restrict__ P,
    const int* __restrict__ row_ptr, const int* __restrict__ eid, const int* __restrict__ srcs,
    __hip_bfloat16* __restrict__ aggout) {
  const int wid = threadIdx.x >> 6, lane = threadIdx.x & 63;
  const int n = blockIdx.x*4 + wid;
  __shared__ float q_s[4][DD];
  __shared__ float l_s[4][64][4];
  __shared__ float P_s[4][36];
  if (n >= NN) return;
  float* q = q_s[wid];
  float (*ls)[4] = l_s[wid];
  float* Ps = P_s[wid];
  const int e0 = row_ptr[n], e1 = row_ptr[n+1];
  if (lane < 60) {
    u16x8 v = *reinterpret_cast<const u16x8*>((const unsigned short*)xq + (size_t)n*DD + lane*8);
    float4 f0 = make_float4(b2f(v[0]), b2f(v[1]), b2f(v[2]), b2f(v[3]));
    float4 f1 = make_float4(b2f(v[4]), b2f(v[5]), b2f(v[6]), b2f(v[7]));
    *reinterpret_cast<float4*>(&q[lane*8])     = f0;
    *reinterpret_cast<float4*>(&q[lane*8 + 4]) = f1;
  }
  if (lane < 36) Ps[lane] = P[(size_t)n*36 + lane];
  float m_reg = -1e30f, den_reg = 0.f;
  float agg[8] = {0,0,0,0,0,0,0,0};
  const int hh = lane >> 4, li = lane & 15;     // logit partition
  const int hd = (lane < 60) ? (lane/15) : 3;   // aggregate partition
  for (int c0 = e0; c0 < e1; c0 += 64) {
    const int cn = min(64, e1 - c0);
    // phase A: logits
    for (int i = 0; i < cn; ++i) {
      const int p = c0 + i;
      const int e = eid[p];
      const int s = srcs[p];
      float acc = 0.f;
      if (li < 15) {
        u16x8 kv = *reinterpret_cast<const u16x8*>((const unsigned short*)xk + (size_t)s*DD + hh*DHD + li*8);
        const float* qq = &q[hh*DHD + li*8];
        #pragma unroll
        for (int j = 0; j < 8; ++j) acc += qq[j]*b2f(kv[j]);
      }
      #pragma unroll
      for (int off = 1; off < 16; off <<= 1) acc += __shfl_xor(acc, off, 64);
      if (li == 0) {
        const float* srow = sh + (size_t)e*9;
        float lp = 0.f;
        #pragma unroll
        for (int t = 0; t < 9; ++t) lp += srow[t]*Ps[hh*9 + t];
        ls[i][hh] = (acc + lp) * INV_DH * gate[(size_t)e*4 + hh];
      }
    }
    // phase B: online softmax update (lane: h=lane&3, i0=lane>>2)
    const int h = lane & 3, i0 = lane >> 2;
    float cm = -1e30f;
    for (int i = i0; i < cn; i += 16) cm = fmaxf(cm, ls[i][h]);
    #pragma unroll
    for (int off = 4; off < 64; off <<= 1) cm = fmaxf(cm, __shfl_xor(cm, off, 64));
    const float newm = fmaxf(m_reg, cm);
    const float f = __expf(m_reg - newm);
    float cs = 0.f;
    for (int i = i0; i < cn; i += 16) {
      float a = __expf(ls[i][h] - newm);
      ls[i][h] = a;
      cs += a;
    }
    #pragma unroll
    for (int off = 4; off < 64; off <<= 1) cs += __shfl_xor(cs, off, 64);
    m_reg = newm;
    den_reg = den_reg*f + cs;
    // phase C: aggregate
    const float fh = __shfl(f, hd);
    #pragma unroll
    for (int j = 0; j < 8; ++j) agg[j] *= fh;
    for (int i = 0; i < cn; ++i) {
      const int s = srcs[c0 + i];
      const float a = ls[i][hd];
      if (lane < 60) {
        u16x8 v = *reinterpret_cast<const u16x8*>((const unsigned short*)xv + (size_t)s*DD + lane*8);
        #pragma unroll
        for (int j = 0; j < 8; ++j) agg[j] += a*b2f(v[j]);
      }
    }
  }
  const float dh = __shfl(den_reg, hd);
  if (lane < 60) {
    const float sc = INV_SQRT_DEG / (dh + 1e-12f);
    u16x8 o;
    #pragma unroll
    for (int j = 0; j < 8; ++j) o[j] = f2b(agg[j]*sc);
    *reinterpret_cast<u16x8*>((unsigned short*)aggout + (size_t)n*DD + lane*8) = o;
  }
}

// ---------------- residual + LayerNorm: x = LN(x + t); xb = bf16(x) ----------------
__global__ __launch_bounds__(64) void ln_kernel(float* __restrict__ x, const float* __restrict__ t,
    __hip_bfloat16* __restrict__ xb) {
  const int n = blockIdx.x, lane = threadIdx.x;
  float v[8];
  float s = 0.f, s2 = 0.f;
  #pragma unroll
  for (int r = 0; r < 8; ++r) {
    int d = lane + (r<<6);
    if (d < DD) {
      float vv = x[(size_t)n*DD + d] + t[(size_t)n*DD + d];
      v[r] = vv; s += vv; s2 += vv*vv;
    }
  }
  s = wsum(s); s2 = wsum(s2);
  const float mu = s * (1.f/(float)DD);
  const float var = s2 * (1.f/(float)DD) - mu*mu;
  const float rs = rsqrtf(var + 1e-5f);
  #pragma unroll
  for (int r = 0; r < 8; ++r) {
    int d = lane + (r<<6);
    if (d < DD) {
      float vv = (v[r]-mu)*rs;
      x[(size_t)n*DD + d] = vv;
      ((unsigned short*)xb)[(size_t)n*DD + d] = f2b(vv);
    }
  }
}

// ---------------- final: energy += (t[n] . Wh2) / AVG_NODES into out[batch[n]] ----------------
__global__ __launch_bounds__(64) void h2_kernel(const float* __restrict__ t,
    const float* __restrict__ Wh2, const int* __restrict__ batch, float* __restrict__ out) {
  const int n = blockIdx.x, lane = threadIdx.x;
  float s = 0.f;
  #pragma unroll
  for (int r = 0; r < 8; ++r) {
    int d = lane + (r<<6);
    if (d < DD) s += t[(size_t)n*DD + d]*Wh2[d];
  }
  s = wsum(s);
  if (lane == 0) atomicAdd(&out[batch[n]], s * INV_AVG_NODES);
}

extern "C" void kernel_launch(void* const* d_in, const int* in_sizes, int n_in,
                              void* d_out, int out_size, void* d_ws, size_t ws_size,
                              hipStream_t stream) {
  const float* pos        = (const float*)d_in[0];
  const int*   node_atom  = (const int*)  d_in[1];
  const int*   edge_src   = (const int*)  d_in[2];
  const int*   edge_dst   = (const int*)  d_in[3];
  const int*   batch      = (const int*)  d_in[4];
  const float* atom_table = (const float*)d_in[5];
  const float* Wdeg       = (const float*)d_in[6];
  const float* Wd1        = (const float*)d_in[7];
  const float* Wd2        = (const float*)d_in[8];
  const float* Wd3        = (const float*)d_in[9];
  const float* Wq         = (const float*)d_in[10];
  const float* Wk         = (const float*)d_in[11];
  const float* Wv         = (const float*)d_in[12];
  const float* Wsh        = (const float*)d_in[13];
  const float* W1         = (const float*)d_in[14];
  const float* W2         = (const float*)d_in[15];
  const float* W3         = (const float*)d_in[16];
  const float* Wo         = (const float*)d_in[17];
  const float* Wf1        = (const float*)d_in[18];
  const float* Wf2        = (const float*)d_in[19];
  const float* Wh1        = (const float*)d_in[20];
  const float* Wh2        = (const float*)d_in[21];
  float* out = (float*)d_out;
  char*  wsb = (char*)d_ws;

  // ---- workspace layout (bytes, 256-aligned) ----
  size_t off = 0;
  auto alloc = [&](size_t bytes) { size_t o = off; off += (bytes + 255) & ~(size_t)255; return o; };
  float*  x      = (float*) (wsb + alloc((size_t)NN*DD*4));
  __hip_bfloat16* xb   = (__hip_bfloat16*)(wsb + alloc((size_t)NN*DD*2));
  __hip_bfloat16* xq   = (__hip_bfloat16*)(wsb + alloc((size_t)NN*DD*2));
  __hip_bfloat16* xk   = (__hip_bfloat16*)(wsb + alloc((size_t)NN*DD*2));
  __hip_bfloat16* xv   = (__hip_bfloat16*)(wsb + alloc((size_t)NN*DD*2));
  float*  shb    = (float*) (wsb + alloc((size_t)EE*9*4));
  __hip_bfloat16* rbf  = (__hip_bfloat16*)(wsb + alloc((size_t)EE*NB_*2));
  float*  gate   = (float*) (wsb + alloc((size_t)EE*4*4));
  float*  P      = (float*) (wsb + alloc((size_t)NN*36*4));
  float*  g0     = (float*) (wsb + alloc((size_t)EE*4));
  __hip_bfloat16* aggb = (__hip_bfloat16*)(wsb + alloc((size_t)NN*DD*2));
  float*  tmp480 = (float*) (wsb + alloc((size_t)NN*DD*4));
  __hip_bfloat16* tmp960 = (__hip_bfloat16*)(wsb + alloc((size_t)NN*960*2));
  __hip_bfloat16* t64a = (__hip_bfloat16*)(wsb + alloc((size_t)EE*64*2));
  __hip_bfloat16* t64b = (__hip_bfloat16*)(wsb + alloc((size_t)EE*64*2));
  // transposed bf16 weights
  __hip_bfloat16* Wqt  = (__hip_bfloat16*)(wsb + alloc((size_t)LLAYERS*512*480*2));
  __hip_bfloat16* Wkt  = (__hip_bfloat16*)(wsb + alloc((size_t)LLAYERS*512*480*2));
  __hip_bfloat16* Wvt  = (__hip_bfloat16*)(wsb + alloc((size_t)LLAYERS*512*480*2));
  __hip_bfloat16* Wot  = (__hip_bfloat16*)(wsb + alloc((size_t)LLAYERS*512*480*2));
  __hip_bfloat16* Wf1t = (__hip_bfloat16*)(wsb + alloc((size_t)LLAYERS*960*480*2));
  __hip_bfloat16* Wf2t = (__hip_bfloat16*)(wsb + alloc((size_t)LLAYERS*512*960*2));
  __hip_bfloat16* W1t  = (__hip_bfloat16*)(wsb + alloc((size_t)LLAYERS*64*128*2));
  __hip_bfloat16* W2t  = (__hip_bfloat16*)(wsb + alloc((size_t)LLAYERS*64*64*2));
  __hip_bfloat16* Wd1t = (__hip_bfloat16*)(wsb + alloc((size_t)64*128*2));
  __hip_bfloat16* Wd2t = (__hip_bfloat16*)(wsb + alloc((size_t)64*64*2));
  __hip_bfloat16* Wh1t = (__hip_bfloat16*)(wsb + alloc((size_t)512*480*2));
  int* cnt     = (int*)(wsb + alloc((size_t)NN*4));
  int* row_ptr = (int*)(wsb + alloc((size_t)(NN+1)*4));
  int* cursor  = (int*)(wsb + alloc((size_t)NN*4));
  int* eid     = (int*)(wsb + alloc((size_t)EE*4));
  int* srcs    = (int*)(wsb + alloc((size_t)EE*4));
  (void)ws_size;

  auto tr = [&](const float* W, __hip_bfloat16* Wt, int K, int N, int Npad, int L) {
    dim3 g((Npad+31)/32, (K+31)/32, L);
    transpose_w_kernel<<<g, 256, 0, stream>>>(W, Wt, K, N, Npad);
  };
  // mode: 0 = f32 out; 1 = silu f32; 2 = bf16 out; 3 = silu bf16
  auto gemm = [&](const __hip_bfloat16* A, const __hip_bfloat16* Bt, float* Cf, __hip_bfloat16* Cb,
                  int M, int K, int Nc, int Npad, int mode) {
    dim3 g(Npad/64, (M+127)/128);
    switch (mode) {
      case 0: gemm_bf16_kernel<0,1,0><<<g, 256, 0, stream>>>(A, Bt, Cf, Cb, M, K, Nc); break;
      case 1: gemm_bf16_kernel<1,1,0><<<g, 256, 0, stream>>>(A, Bt, Cf, Cb, M, K, Nc); break;
      case 2: gemm_bf16_kernel<0,0,1><<<g, 256, 0, stream>>>(A, Bt, Cf, Cb, M, K, Nc); break;
      case 3: gemm_bf16_kernel<1,0,1><<<g, 256, 0, stream>>>(A, Bt, Cf, Cb, M, K, Nc); break;
    }
  };

  // weight transposes
  tr(Wq,  Wqt,  480, 480, 512, LLAYERS);
  tr(Wk,  Wkt,  480, 480, 512, LLAYERS);
  tr(Wv,  Wvt,  480, 480, 512, LLAYERS);
  tr(Wo,  Wot,  480, 480, 512, LLAYERS);
  tr(Wf1, Wf1t, 480, 960, 960, LLAYERS);
  tr(Wf2, Wf2t, 960, 480, 512, LLAYERS);
  tr(W1,  W1t,  128, 64,  64,  LLAYERS);
  tr(W2,  W2t,  64,  64,  64,  LLAYERS);
  tr(Wd1, Wd1t, 128, 64,  64,  1);
  tr(Wd2, Wd2t, 64,  64,  64,  1);
  tr(Wh1, Wh1t, 480, 480, 512, 1);

  // setup
  zero_kernel<<<(NN+255)/256, 256, 0, stream>>>(cnt, out);
  gather_x_kernel<<<NN, 256, 0, stream>>>(atom_table, node_atom, x);
  edge_geom_kernel<<<(EE+255)/256, 256, 0, stream>>>(pos, edge_src, edge_dst, shb, rbf);
  hist_kernel<<<(EE+255)/256, 256, 0, stream>>>(edge_dst, cnt);
  scan_kernel<<<1, 1024, 0, stream>>>(cnt, row_ptr, cursor);
  scatter_kernel<<<(EE+255)/256, 256, 0, stream>>>(edge_src, edge_dst, cursor, eid, srcs);

  // g0 chain + deg
  gemm(rbf, Wd1t, nullptr, t64a, EE, NB_, 64, 64, 3);
  gemm(t64a, Wd2t, nullptr, t64b, EE, 64, 64, 64, 3);
  colmat_kernel<1><<<(EE+255)/256, 256, 0, stream>>>(t64b, Wd3, g0, EE);
  deg_kernel<<<NN, 64, 0, stream>>>(g0, shb, row_ptr, eid, Wdeg, x, xb);

  for (int l = 0; l < LLAYERS; ++l) {
    const __hip_bfloat16* Wqt_l  = Wqt  + (size_t)l*512*480;
    const __hip_bfloat16* Wkt_l  = Wkt  + (size_t)l*512*480;
    const __hip_bfloat16* Wvt_l  = Wvt  + (size_t)l*512*480;
    const __hip_bfloat16* Wot_l  = Wot  + (size_t)l*512*480;
    const __hip_bfloat16* Wf1t_l = Wf1t + (size_t)l*960*480;
    const __hip_bfloat16* Wf2t_l = Wf2t + (size_t)l*512*960;
    const __hip_bfloat16* W1t_l  = W1t  + (size_t)l*64*128;
    const __hip_bfloat16* W2t_l  = W2t  + (size_t)l*64*64;
    const float* Wsh_l = Wsh + (size_t)l*9*DD;
    const float* W3_l  = W3  + (size_t)l*64*4;

    gemm(xb, Wqt_l, nullptr, xq, NN, 480, 480, 512, 2);
    gemm(xb, Wkt_l, nullptr, xk, NN, 480, 480, 512, 2);
    gemm(xb, Wvt_l, nullptr, xv, NN, 480, 480, 512, 2);
    p_kernel<<<NN, 64, 0, stream>>>(xq, Wsh_l, P);
    gemm(rbf, W1t_l, nullptr, t64a, EE, NB_, 64, 64, 3);
    gemm(t64a, W2t_l, nullptr, t64b, EE, 64, 64, 64, 3);
    colmat_kernel<4><<<(EE+255)/256, 256, 0, stream>>>(t64b, W3_l, gate, EE);
    attn_kernel<<<(NN+3)/4, 256, 0, stream>>>(xq, xk, xv, shb, gate, P, row_ptr, eid, srcs, aggb);
    gemm(aggb, Wot_l, tmp480, nullptr, NN, 480, 480, 512, 0);
    ln_kernel<<<NN, 64, 0, stream>>>(x, tmp480, xb);
    gemm(xb, Wf1t_l, nullptr, tmp960, NN, 480, 960, 960, 3);
    gemm(tmp960, Wf2t_l, tmp480, nullptr, NN, 960, 480, 512, 0);
    ln_kernel<<<NN, 64, 0, stream>>>(x, tmp480, xb);
  }

  gemm(xb, Wh1t, tmp480, nullptr, NN, 480, 480, 512, 1);
  h2_kernel<<<NN, 64, 0, stream>>>(tmp480, Wh2, batch, out);
}

// Round 3
// 2212.696 us; speedup vs baseline: 2.5464x; 1.1030x over previous
//
#include <hip/hip_runtime.h>
#include <hip/hip_bf16.h>

#define NN 10000
#define EE 160000
#define GG 64
#define DD 480
#define HH 4
#define LLAYERS 6
#define DHD 120
#define NB_ 128
#define TSIZE 4096
#define DMAXT 5.5f
#define LSCALE (4095.0f/5.5f)

#define INV_DH 0.09128709291752768f
#define INV_SQRT_DEG 0.25335277f
#define INV_AVG_NODES (1.0f/18.03065905448718f)

typedef __attribute__((ext_vector_type(8))) short bf16x8;
typedef __attribute__((ext_vector_type(4))) float f32x4;
typedef __attribute__((ext_vector_type(8))) unsigned short u16x8;

__device__ __forceinline__ float b2f(unsigned short u){ return __uint_as_float(((unsigned)u)<<16); }
__device__ __forceinline__ unsigned short f2b(float f){
  unsigned u = __float_as_uint(f);
  return (unsigned short)((u + 0x7fffu + ((u>>16)&1u)) >> 16);
}
__device__ __forceinline__ float wsum(float v){
  #pragma unroll
  for (int off=32; off>0; off>>=1) v += __shfl_xor(v, off, 64);
  return v;
}
__device__ __forceinline__ void glds16(const void* g, void* l) {
  __builtin_amdgcn_global_load_lds((const __attribute__((address_space(1))) unsigned int*)g,
                                   (__attribute__((address_space(3))) unsigned int*)l, 16, 0, 0);
}

// ---------------- zero ----------------
__global__ __launch_bounds__(256) void zero_kernel(int* __restrict__ cnt, float* __restrict__ out){
  int i = blockIdx.x*256 + threadIdx.x;
  if (i < NN) cnt[i] = 0;
  if (i < GG) out[i] = 0.f;
}

// ---------------- x = atom_table[node_atom] (4 waves/block, wave=node) ----------------
__global__ __launch_bounds__(256) void gather_x_kernel(const float* __restrict__ at,
    const int* __restrict__ atom, float* __restrict__ x){
  const int wid = threadIdx.x >> 6, lane = threadIdx.x & 63;
  for (int n = blockIdx.x*4 + wid; n < NN; n += gridDim.x*4) {
    int a = atom[n];
    if (lane < 60) {
      const float4* src = (const float4*)(at + (size_t)a*DD + lane*8);
      float4* dst = (float4*)(x + (size_t)n*DD + lane*8);
      dst[0] = src[0]; dst[1] = src[1];
    }
  }
}

// ---------------- edge geometry: sh (E x 9 f32), dedge (E f32) ----------------
__global__ __launch_bounds__(256) void edge_geom_kernel(const float* __restrict__ pos,
    const int* __restrict__ esrc, const int* __restrict__ edst,
    float* __restrict__ sh, float* __restrict__ dedge){
  const int e = blockIdx.x*256 + threadIdx.x;
  if (e >= EE) return;
  int s = esrc[e], d = edst[e];
  float vx = pos[s*3+0]-pos[d*3+0];
  float vy = pos[s*3+1]-pos[d*3+1];
  float vz = pos[s*3+2]-pos[d*3+2];
  float rr = sqrtf(vx*vx+vy*vy+vz*vz);
  dedge[e] = rr;
  float r = rr + 1e-12f;
  float x = vx/r, y = vy/r, z = vz/r;
  const float s3 = 1.7320508075688772f;
  const float s5 = 2.23606797749979f;
  const float s15 = 3.872983346207417f;
  float* o = sh + (size_t)e*9;
  o[0] = 1.f;
  o[1] = s3*x; o[2] = s3*y; o[3] = s3*z;
  o[4] = s15*x*y; o[5] = s15*y*z;
  o[6] = 0.5f*s5*(3.f*z*z-1.f);
  o[7] = s15*x*z;
  o[8] = 0.5f*s15*(x*x-y*y);
}

// ---------------- sort by dst ----------------
__global__ __launch_bounds__(256) void hist_kernel(const int* __restrict__ edst, int* __restrict__ cnt){
  int e = blockIdx.x*256 + threadIdx.x;
  if (e < EE) atomicAdd(&cnt[edst[e]], 1);
}

__global__ __launch_bounds__(1024) void scan_kernel(const int* __restrict__ cnt,
    int* __restrict__ row_ptr, int* __restrict__ cursor){
  __shared__ int sd[1024];
  __shared__ int s_carry;
  if (threadIdx.x == 0) s_carry = 0;
  __syncthreads();
  for (int base = 0; base < NN; base += 1024) {
    int i = base + threadIdx.x;
    int v = (i < NN) ? cnt[i] : 0;
    sd[threadIdx.x] = v;
    __syncthreads();
    for (int off = 1; off < 1024; off <<= 1) {
      int t = 0;
      if ((int)threadIdx.x >= off) t = sd[threadIdx.x - off];
      __syncthreads();
      sd[threadIdx.x] += t;
      __syncthreads();
    }
    int incl = sd[threadIdx.x];
    int carry = s_carry;
    if (i < NN) { row_ptr[i] = carry + incl - v; cursor[i] = carry + incl - v; }
    __syncthreads();
    if (threadIdx.x == 1023) s_carry = carry + incl;
    __syncthreads();
  }
  if (threadIdx.x == 0) row_ptr[NN] = s_carry;
}

__global__ __launch_bounds__(256) void scatter_kernel(const int* __restrict__ esrc,
    const int* __restrict__ edst, int* __restrict__ cursor,
    int* __restrict__ eid, int* __restrict__ srcs){
  int e = blockIdx.x*256 + threadIdx.x;
  if (e < EE) {
    int n = edst[e];
    int p = atomicAdd(&cursor[n], 1);
    eid[p] = e;
    srcs[p] = esrc[e];
  }
}

// ---------------- gate/g0 lookup tables: MLP(d) on a 4096 grid, f32 ----------------
__global__ __launch_bounds__(256) void table_kernel(
    const float* __restrict__ Wd1, const float* __restrict__ Wd2, const float* __restrict__ Wd3,
    const float* __restrict__ W1, const float* __restrict__ W2, const float* __restrict__ W3,
    float* __restrict__ Tg, float* __restrict__ Tl) {
  const int chain = blockIdx.y;
  const float *A1, *A2, *A3; int NC;
  if (chain == 0) { A1 = Wd1; A2 = Wd2; A3 = Wd3; NC = 1; }
  else { int l = chain-1; A1 = W1 + (size_t)l*128*64; A2 = W2 + (size_t)l*64*64; A3 = W3 + (size_t)l*64*4; NC = 4; }
  __shared__ float W1s[128*64];
  __shared__ float W2s[64*64];
  __shared__ float W3s[64*4];
  for (int i = threadIdx.x; i < 128*64; i += 256) W1s[i] = A1[i];
  for (int i = threadIdx.x; i < 64*64; i += 256) W2s[i] = A2[i];
  for (int i = threadIdx.x; i < 64*4; i += 256) W3s[i] = (i < 64*NC) ? A3[i] : 0.f;
  __syncthreads();
  const int t = blockIdx.x*256 + threadIdx.x;
  const float d = (float)t * (DMAXT/(float)(TSIZE-1));
  float t1[64];
  #pragma unroll
  for (int c = 0; c < 64; ++c) t1[c] = 0.f;
  for (int j = 0; j < 128; ++j) {
    float z = (d - (float)j*(5.0f/127.0f)) * (128.0f/5.0f);
    float f = __expf(-z*z);
    #pragma unroll
    for (int c = 0; c < 64; ++c) t1[c] += f * W1s[j*64 + c];
  }
  #pragma unroll
  for (int c = 0; c < 64; ++c) t1[c] = t1[c] / (1.f + __expf(-t1[c]));
  float t2[64];
  #pragma unroll
  for (int c = 0; c < 64; ++c) t2[c] = 0.f;
  for (int c = 0; c < 64; ++c) {
    float v = t1[c];
    #pragma unroll
    for (int c2 = 0; c2 < 64; ++c2) t2[c2] += v * W2s[c*64 + c2];
  }
  #pragma unroll
  for (int c = 0; c < 64; ++c) t2[c] = t2[c] / (1.f + __expf(-t2[c]));
  if (chain == 0) {
    float o = 0.f;
    for (int c = 0; c < 64; ++c) o += t2[c] * W3s[c];
    Tg[t] = o;
  } else {
    #pragma unroll
    for (int nc = 0; nc < 4; ++nc) {
      float o = 0.f;
      for (int c = 0; c < 64; ++c) o += t2[c] * W3s[c*4 + nc];
      Tl[((size_t)(chain-1)*TSIZE + t)*4 + nc] = o;
    }
  }
}

__device__ __forceinline__ float lookup1(const float* __restrict__ Tg, float d) {
  float u = d * LSCALE;
  if (u >= (float)(TSIZE-1)) return 0.f;
  int i = (int)u; float fr = u - (float)i;
  float a = Tg[i], b = Tg[i+1];
  return a + fr*(b-a);
}

// ---------------- weight transpose+convert ----------------
__global__ __launch_bounds__(256) void transpose_w_kernel(const float* __restrict__ W,
    __hip_bfloat16* __restrict__ Wt, int K, int N, int Npad,
    long long lstrideW, long long lstrideT) {
  __shared__ float T[32][33];
  const int l = blockIdx.z;
  W  += (size_t)l*lstrideW;
  Wt += (size_t)l*lstrideT;
  const int k0 = blockIdx.y*32, n0 = blockIdx.x*32;
  const int tx = threadIdx.x & 31, ty = threadIdx.x >> 5;
  #pragma unroll
  for (int r = 0; r < 32; r += 8) {
    int k = k0 + ty + r, n = n0 + tx;
    T[ty+r][tx] = (k < K && n < N) ? W[(size_t)k*N + n] : 0.f;
  }
  __syncthreads();
  #pragma unroll
  for (int r = 0; r < 32; r += 8) {
    int n = n0 + ty + r, k = k0 + tx;
    if (n < Npad && k < K)
      ((unsigned short*)Wt)[(size_t)n*K + k] = f2b(T[tx][ty+r]);
  }
}

// ---------------- bf16 MFMA GEMM: tile 128x64x32, 4 waves ----------------
// OUT: 0 = f32 (Cf), 1 = bf16 (Cb0), 2 = QKV 3-way bf16 (Cb0/Cb1/Cb2, Nc per segment)
template<int SILU, int OUT>
__global__ __launch_bounds__(256) void gemm_bf16_kernel(
    const __hip_bfloat16* __restrict__ A, const __hip_bfloat16* __restrict__ Bt,
    float* __restrict__ Cf, __hip_bfloat16* __restrict__ Cb0,
    __hip_bfloat16* __restrict__ Cb1, __hip_bfloat16* __restrict__ Cb2,
    int M, int K, int Nc) {
  __shared__ char smem[(512 + 256) * 16];
  char* AsB = smem;
  char* BsB = smem + 8192;
  const int tid = threadIdx.x;
  const int lane = tid & 63, wid = tid >> 6;
  const int wm = wid >> 1, wn = wid & 1;
  const long long m0 = (long long)blockIdx.y * 128;
  const int n0 = blockIdx.x * 64;

  const int arow_loc = (wid & 1)*64 + lane;
  long long gr = m0 + arow_loc; if (gr >= M) gr = M - 1;
  const __hip_bfloat16* aptr = A + gr * (size_t)K;
  const int khiA0 = wid >> 1, khiA1 = 2 + (wid >> 1);
  char* adst0 = AsB + wid*64*16;
  char* adst1 = AsB + 4096 + wid*64*16;
  const __hip_bfloat16* bptr = Bt + (size_t)(n0 + lane) * K;
  char* bdst = BsB + wid*64*16;

  f32x4 acc[4][2];
  #pragma unroll
  for (int i = 0; i < 4; ++i)
    #pragma unroll
    for (int j = 0; j < 2; ++j)
      acc[i][j] = (f32x4){0.f,0.f,0.f,0.f};

  const int lr = lane & 15, lkh = lane >> 4;

  for (int kt = 0; kt < K; kt += 32) {
    __syncthreads();
    glds16(aptr + kt + khiA0*8, adst0);
    glds16(aptr + kt + khiA1*8, adst1);
    glds16(bptr + kt + wid*8, bdst);
    __syncthreads();
    bf16x8 afr[4], bfr[2];
    #pragma unroll
    for (int fm = 0; fm < 4; ++fm)
      afr[fm] = *reinterpret_cast<const bf16x8*>(AsB + (lkh*128 + wm*64 + fm*16 + lr)*16);
    #pragma unroll
    for (int fn = 0; fn < 2; ++fn)
      bfr[fn] = *reinterpret_cast<const bf16x8*>(BsB + (lkh*64 + wn*32 + fn*16 + lr)*16);
    #pragma unroll
    for (int fm = 0; fm < 4; ++fm)
      #pragma unroll
      for (int fn = 0; fn < 2; ++fn)
        acc[fm][fn] = __builtin_amdgcn_mfma_f32_16x16x32_bf16(afr[fm], bfr[fn], acc[fm][fn], 0, 0, 0);
  }

  const int seg = n0 >> 9;
  const int c0 = (OUT == 2) ? (n0 & 511) : n0;
  unsigned short* qdst = nullptr;
  if (OUT == 2) qdst = (unsigned short*)(seg == 0 ? Cb0 : (seg == 1 ? Cb1 : Cb2));
  #pragma unroll
  for (int fm = 0; fm < 4; ++fm) {
    #pragma unroll
    for (int fn = 0; fn < 2; ++fn) {
      #pragma unroll
      for (int j = 0; j < 4; ++j) {
        long long r = m0 + wm*64 + fm*16 + lkh*4 + j;
        int c = c0 + wn*32 + fn*16 + lr;
        if (r < M && c < Nc) {
          float v = acc[fm][fn][j];
          if (SILU) v = v / (1.f + __expf(-v));
          if (OUT == 0) Cf[r*(size_t)Nc + c] = v;
          else if (OUT == 1) ((unsigned short*)Cb0)[r*(size_t)Nc + c] = f2b(v);
          else qdst[r*(size_t)Nc + c] = f2b(v);
        }
      }
    }
  }
}

// ---------------- deg: x[n] += ((sum_e g0(d_e)*sh_e) @ Wdeg)*scale ; xb = bf16(x) ----------------
__global__ __launch_bounds__(256) void deg_kernel(const float* __restrict__ dedge,
    const float* __restrict__ sh, const float* __restrict__ Tg,
    const int* __restrict__ row_ptr, const int* __restrict__ eid,
    const float* __restrict__ Wdeg, float* __restrict__ x, __hip_bfloat16* __restrict__ xb) {
  const int wid = threadIdx.x >> 6, lane = threadIdx.x & 63;
  for (int n = blockIdx.x*4 + wid; n < NN; n += gridDim.x*4) {
    const int e0 = row_ptr[n], e1 = row_ptr[n+1];
    float s9[9] = {0,0,0,0,0,0,0,0,0};
    for (int p = e0 + lane; p < e1; p += 64) {
      int e = eid[p];
      float g = lookup1(Tg, dedge[e]);
      const float* srow = sh + (size_t)e*9;
      #pragma unroll
      for (int s = 0; s < 9; ++s) s9[s] += g*srow[s];
    }
    #pragma unroll
    for (int s = 0; s < 9; ++s) s9[s] = wsum(s9[s]);
    #pragma unroll
    for (int r = 0; r < 8; ++r) {
      int d = lane + (r<<6);
      if (d < DD) {
        float acc = 0.f;
        #pragma unroll
        for (int s = 0; s < 9; ++s) acc += s9[s]*Wdeg[s*DD + d];
        float vv = x[(size_t)n*DD + d] + acc * INV_SQRT_DEG;
        x[(size_t)n*DD + d] = vv;
        ((unsigned short*)xb)[(size_t)n*DD + d] = f2b(vv);
      }
    }
  }
}

// ---------------- P[n,h,s] = sum_{d in head h} xq[n,d]*Wsh[s,d] ----------------
__global__ __launch_bounds__(256) void p_kernel(const __hip_bfloat16* __restrict__ xq,
    const float* __restrict__ Wsh_l, float* __restrict__ P) {
  const int wid = threadIdx.x >> 6, lane = threadIdx.x & 63;
  for (int n = blockIdx.x*4 + wid; n < NN; n += gridDim.x*4) {
    if (lane < 36) {
      int h = lane/9, s = lane%9;
      const unsigned short* q = (const unsigned short*)(xq + (size_t)n*DD + h*DHD);
      const float* w = Wsh_l + s*DD + h*DHD;
      float acc = 0.f;
      #pragma unroll
      for (int db = 0; db < 15; ++db) {
        u16x8 v = *reinterpret_cast<const u16x8*>(q + db*8);
        #pragma unroll
        for (int j = 0; j < 8; ++j) acc += b2f(v[j])*w[db*8+j];
      }
      P[(size_t)n*36 + lane] = acc;
    }
  }
}

// ---------------- fused attention: 1 node per wave, 4 waves/block, grid-stride ----------------
__global__ __launch_bounds__(256) void attn_kernel(
    const __hip_bfloat16* __restrict__ xq, const __hip_bfloat16* __restrict__ xk,
    const __hip_bfloat16* __restrict__ xv,
    const float* __restrict__ sh, const float* __restrict__ dedge,
    const float* __restrict__ Tl, const float* __restrict__ P,
    const int* __restrict__ row_ptr, const int* __restrict__ eid, const int* __restrict__ srcs,
    __hip_bfloat16* __restrict__ aggout) {
  const int wid = threadIdx.x >> 6, lane = threadIdx.x & 63;
  __shared__ float q_s[4][DD];
  __shared__ float l_s[4][64][4];
  __shared__ float P_s[4][36];
  float* q = q_s[wid];
  float (*ls)[4] = l_s[wid];
  float* Ps = P_s[wid];
  const int hh = lane >> 4, li = lane & 15;
  const int hd = (lane < 60) ? (lane/15) : 3;
  for (int n = blockIdx.x*4 + wid; n < NN; n += gridDim.x*4) {
    const int e0 = row_ptr[n], e1 = row_ptr[n+1];
    if (lane < 60) {
      u16x8 v = *reinterpret_cast<const u16x8*>((const unsigned short*)xq + (size_t)n*DD + lane*8);
      float4 f0 = make_float4(b2f(v[0]), b2f(v[1]), b2f(v[2]), b2f(v[3]));
      float4 f1 = make_float4(b2f(v[4]), b2f(v[5]), b2f(v[6]), b2f(v[7]));
      *reinterpret_cast<float4*>(&q[lane*8])     = f0;
      *reinterpret_cast<float4*>(&q[lane*8 + 4]) = f1;
    }
    if (lane < 36) Ps[lane] = P[(size_t)n*36 + lane];
    float m_reg = -1e30f, den_reg = 0.f;
    float agg[8] = {0,0,0,0,0,0,0,0};
    for (int c0 = e0; c0 < e1; c0 += 64) {
      const int cn = min(64, e1 - c0);
      // phase A: logits
      for (int i = 0; i < cn; ++i) {
        const int p = c0 + i;
        const int e = eid[p];
        const int s = srcs[p];
        float acc = 0.f;
        if (li < 15) {
          u16x8 kv = *reinterpret_cast<const u16x8*>((const unsigned short*)xk + (size_t)s*DD + hh*DHD + li*8);
          const float* qq = &q[hh*DHD + li*8];
          #pragma unroll
          for (int j = 0; j < 8; ++j) acc += qq[j]*b2f(kv[j]);
        }
        #pragma unroll
        for (int off = 1; off < 16; off <<= 1) acc += __shfl_xor(acc, off, 64);
        if (li == 0) {
          const float* srow = sh + (size_t)e*9;
          float lp = 0.f;
          #pragma unroll
          for (int t = 0; t < 9; ++t) lp += srow[t]*Ps[hh*9 + t];
          float gh;
          {
            float u = dedge[e] * LSCALE;
            if (u >= (float)(TSIZE-1)) gh = 0.f;
            else {
              int ti = (int)u; float fr = u - (float)ti;
              float a = Tl[ti*4 + hh], b = Tl[(ti+1)*4 + hh];
              gh = a + fr*(b-a);
            }
          }
          ls[i][hh] = (acc + lp) * INV_DH * gh;
        }
      }
      // phase B: online softmax
      const int h = lane & 3, i0 = lane >> 2;
      float cm = -1e30f;
      for (int i = i0; i < cn; i += 16) cm = fmaxf(cm, ls[i][h]);
      #pragma unroll
      for (int off = 4; off < 64; off <<= 1) cm = fmaxf(cm, __shfl_xor(cm, off, 64));
      const float newm = fmaxf(m_reg, cm);
      const float f = __expf(m_reg - newm);
      float cs = 0.f;
      for (int i = i0; i < cn; i += 16) {
        float a = __expf(ls[i][h] - newm);
        ls[i][h] = a;
        cs += a;
      }
      #pragma unroll
      for (int off = 4; off < 64; off <<= 1) cs += __shfl_xor(cs, off, 64);
      m_reg = newm;
      den_reg = den_reg*f + cs;
      // phase C: aggregate
      const float fh = __shfl(f, hd);
      #pragma unroll
      for (int j = 0; j < 8; ++j) agg[j] *= fh;
      for (int i = 0; i < cn; ++i) {
        const int s = srcs[c0 + i];
        const float a = ls[i][hd];
        if (lane < 60) {
          u16x8 v = *reinterpret_cast<const u16x8*>((const unsigned short*)xv + (size_t)s*DD + lane*8);
          #pragma unroll
          for (int j = 0; j < 8; ++j) agg[j] += a*b2f(v[j]);
        }
      }
    }
    const float dh2 = __shfl(den_reg, hd);
    if (lane < 60) {
      const float sc = INV_SQRT_DEG / (dh2 + 1e-12f);
      u16x8 o;
      #pragma unroll
      for (int j = 0; j < 8; ++j) o[j] = f2b(agg[j]*sc);
      *reinterpret_cast<u16x8*>((unsigned short*)aggout + (size_t)n*DD + lane*8) = o;
    }
  }
}

// ---------------- residual + LayerNorm: x = LN(x + t); xb = bf16(x) ----------------
__global__ __launch_bounds__(256) void ln_kernel(float* __restrict__ x, const float* __restrict__ t,
    __hip_bfloat16* __restrict__ xb) {
  const int wid = threadIdx.x >> 6, lane = threadIdx.x & 63;
  for (int n = blockIdx.x*4 + wid; n < NN; n += gridDim.x*4) {
    float4 a0 = make_float4(0,0,0,0), a1 = make_float4(0,0,0,0);
    float s = 0.f, s2 = 0.f;
    if (lane < 60) {
      const float4* xp = (const float4*)(x + (size_t)n*DD + lane*8);
      const float4* tp = (const float4*)(t + (size_t)n*DD + lane*8);
      float4 b0 = tp[0], b1 = tp[1];
      a0 = xp[0]; a1 = xp[1];
      a0.x += b0.x; a0.y += b0.y; a0.z += b0.z; a0.w += b0.w;
      a1.x += b1.x; a1.y += b1.y; a1.z += b1.z; a1.w += b1.w;
      s  = a0.x+a0.y+a0.z+a0.w + a1.x+a1.y+a1.z+a1.w;
      s2 = a0.x*a0.x+a0.y*a0.y+a0.z*a0.z+a0.w*a0.w
         + a1.x*a1.x+a1.y*a1.y+a1.z*a1.z+a1.w*a1.w;
    }
    s = wsum(s); s2 = wsum(s2);
    const float mu = s * (1.f/(float)DD);
    const float var = s2 * (1.f/(float)DD) - mu*mu;
    const float rs = rsqrtf(var + 1e-5f);
    if (lane < 60) {
      float4* xp = (float4*)(x + (size_t)n*DD + lane*8);
      a0.x = (a0.x-mu)*rs; a0.y = (a0.y-mu)*rs; a0.z = (a0.z-mu)*rs; a0.w = (a0.w-mu)*rs;
      a1.x = (a1.x-mu)*rs; a1.y = (a1.y-mu)*rs; a1.z = (a1.z-mu)*rs; a1.w = (a1.w-mu)*rs;
      xp[0] = a0; xp[1] = a1;
      u16x8 o;
      o[0]=f2b(a0.x); o[1]=f2b(a0.y); o[2]=f2b(a0.z); o[3]=f2b(a0.w);
      o[4]=f2b(a1.x); o[5]=f2b(a1.y); o[6]=f2b(a1.z); o[7]=f2b(a1.w);
      *reinterpret_cast<u16x8*>((unsigned short*)xb + (size_t)n*DD + lane*8) = o;
    }
  }
}

// ---------------- final: energy += (t[n] . Wh2)/AVG_NODES into out[batch[n]] ----------------
__global__ __launch_bounds__(256) void h2_kernel(const float* __restrict__ t,
    const float* __restrict__ Wh2, const int* __restrict__ batch, float* __restrict__ out) {
  const int wid = threadIdx.x >> 6, lane = threadIdx.x & 63;
  for (int n = blockIdx.x*4 + wid; n < NN; n += gridDim.x*4) {
    float s = 0.f;
    if (lane < 60) {
      const float4* tp = (const float4*)(t + (size_t)n*DD + lane*8);
      const float4* wp = (const float4*)(Wh2 + lane*8);
      float4 t0 = tp[0], t1 = tp[1], w0 = wp[0], w1 = wp[1];
      s = t0.x*w0.x+t0.y*w0.y+t0.z*w0.z+t0.w*w0.w
        + t1.x*w1.x+t1.y*w1.y+t1.z*w1.z+t1.w*w1.w;
    }
    s = wsum(s);
    if (lane == 0) atomicAdd(&out[batch[n]], s * INV_AVG_NODES);
  }
}

extern "C" void kernel_launch(void* const* d_in, const int* in_sizes, int n_in,
                              void* d_out, int out_size, void* d_ws, size_t ws_size,
                              hipStream_t stream) {
  const float* pos        = (const float*)d_in[0];
  const int*   node_atom  = (const int*)  d_in[1];
  const int*   edge_src   = (const int*)  d_in[2];
  const int*   edge_dst   = (const int*)  d_in[3];
  const int*   batch      = (const int*)  d_in[4];
  const float* atom_table = (const float*)d_in[5];
  const float* Wdeg       = (const float*)d_in[6];
  const float* Wd1        = (const float*)d_in[7];
  const float* Wd2        = (const float*)d_in[8];
  const float* Wd3        = (const float*)d_in[9];
  const float* Wq         = (const float*)d_in[10];
  const float* Wk         = (const float*)d_in[11];
  const float* Wv         = (const float*)d_in[12];
  const float* Wsh        = (const float*)d_in[13];
  const float* W1         = (const float*)d_in[14];
  const float* W2         = (const float*)d_in[15];
  const float* W3         = (const float*)d_in[16];
  const float* Wo         = (const float*)d_in[17];
  const float* Wf1        = (const float*)d_in[18];
  const float* Wf2        = (const float*)d_in[19];
  const float* Wh1        = (const float*)d_in[20];
  const float* Wh2        = (const float*)d_in[21];
  float* out = (float*)d_out;
  char*  wsb = (char*)d_ws;

  size_t off = 0;
  auto alloc = [&](size_t bytes) { size_t o = off; off += (bytes + 255) & ~(size_t)255; return o; };
  float*  x      = (float*) (wsb + alloc((size_t)NN*DD*4));
  __hip_bfloat16* xb   = (__hip_bfloat16*)(wsb + alloc((size_t)NN*DD*2));
  __hip_bfloat16* xq   = (__hip_bfloat16*)(wsb + alloc((size_t)NN*DD*2));
  __hip_bfloat16* xk   = (__hip_bfloat16*)(wsb + alloc((size_t)NN*DD*2));
  __hip_bfloat16* xv   = (__hip_bfloat16*)(wsb + alloc((size_t)NN*DD*2));
  float*  shb    = (float*) (wsb + alloc((size_t)EE*9*4));
  float*  dedge  = (float*) (wsb + alloc((size_t)EE*4));
  float*  P      = (float*) (wsb + alloc((size_t)NN*36*4));
  __hip_bfloat16* aggb = (__hip_bfloat16*)(wsb + alloc((size_t)NN*DD*2));
  float*  tmp480 = (float*) (wsb + alloc((size_t)NN*DD*4));
  __hip_bfloat16* tmp960 = (__hip_bfloat16*)(wsb + alloc((size_t)NN*960*2));
  float*  Tg     = (float*) (wsb + alloc((size_t)TSIZE*4));
  float*  Tl     = (float*) (wsb + alloc((size_t)LLAYERS*TSIZE*4*4));
  __hip_bfloat16* Wqkvt = (__hip_bfloat16*)(wsb + alloc((size_t)LLAYERS*1536*480*2));
  __hip_bfloat16* Wot   = (__hip_bfloat16*)(wsb + alloc((size_t)LLAYERS*512*480*2));
  __hip_bfloat16* Wf1t  = (__hip_bfloat16*)(wsb + alloc((size_t)LLAYERS*960*480*2));
  __hip_bfloat16* Wf2t  = (__hip_bfloat16*)(wsb + alloc((size_t)LLAYERS*512*960*2));
  __hip_bfloat16* Wh1t  = (__hip_bfloat16*)(wsb + alloc((size_t)512*480*2));
  int* cnt     = (int*)(wsb + alloc((size_t)NN*4));
  int* row_ptr = (int*)(wsb + alloc((size_t)(NN+1)*4));
  int* cursor  = (int*)(wsb + alloc((size_t)NN*4));
  int* eid     = (int*)(wsb + alloc((size_t)EE*4));
  int* srcs    = (int*)(wsb + alloc((size_t)EE*4));
  (void)ws_size;

  auto tr = [&](const float* W, __hip_bfloat16* Wt, int K, int N, int Npad,
                long long lsW, long long lsT, int L) {
    dim3 g((Npad+31)/32, (K+31)/32, L);
    transpose_w_kernel<<<g, 256, 0, stream>>>(W, Wt, K, N, Npad, lsW, lsT);
  };

  // weight transposes (QKV fused into one [1536][480] per layer)
  tr(Wq,  Wqkvt + 0*512*480,    480, 480, 512, 480*480, 1536*480, LLAYERS);
  tr(Wk,  Wqkvt + 1*512*480,    480, 480, 512, 480*480, 1536*480, LLAYERS);
  tr(Wv,  Wqkvt + 2*512*480,    480, 480, 512, 480*480, 1536*480, LLAYERS);
  tr(Wo,  Wot,  480, 480, 512, 480*480, 512*480, LLAYERS);
  tr(Wf1, Wf1t, 480, 960, 960, 480*960, 960*480, LLAYERS);
  tr(Wf2, Wf2t, 960, 480, 512, 960*480, 512*960, LLAYERS);
  tr(Wh1, Wh1t, 480, 480, 512, 480*480, 512*480, 1);

  // setup
  zero_kernel<<<(NN+255)/256, 256, 0, stream>>>(cnt, out);
  gather_x_kernel<<<640, 256, 0, stream>>>(atom_table, node_atom, x);
  edge_geom_kernel<<<(EE+255)/256, 256, 0, stream>>>(pos, edge_src, edge_dst, shb, dedge);
  hist_kernel<<<(EE+255)/256, 256, 0, stream>>>(edge_dst, cnt);
  scan_kernel<<<1, 1024, 0, stream>>>(cnt, row_ptr, cursor);
  scatter_kernel<<<(EE+255)/256, 256, 0, stream>>>(edge_src, edge_dst, cursor, eid, srcs);
  table_kernel<<<dim3(TSIZE/256, 1+LLAYERS), 256, 0, stream>>>(Wd1, Wd2, Wd3, W1, W2, W3, Tg, Tl);
  deg_kernel<<<640, 256, 0, stream>>>(dedge, shb, Tg, row_ptr, eid, Wdeg, x, xb);

  for (int l = 0; l < LLAYERS; ++l) {
    const __hip_bfloat16* Wqkvt_l = Wqkvt + (size_t)l*1536*480;
    const __hip_bfloat16* Wot_l   = Wot   + (size_t)l*512*480;
    const __hip_bfloat16* Wf1t_l  = Wf1t  + (size_t)l*960*480;
    const __hip_bfloat16* Wf2t_l  = Wf2t  + (size_t)l*512*960;
    const float* Wsh_l = Wsh + (size_t)l*9*DD;
    const float* Tl_l  = Tl  + (size_t)l*TSIZE*4;

    gemm_bf16_kernel<0,2><<<dim3(24, 79), 256, 0, stream>>>(xb, Wqkvt_l, nullptr, xq, xk, xv, NN, 480, 480);
    p_kernel<<<320, 256, 0, stream>>>(xq, Wsh_l, P);
    attn_kernel<<<1280, 256, 0, stream>>>(xq, xk, xv, shb, dedge, Tl_l, P, row_ptr, eid, srcs, aggb);
    gemm_bf16_kernel<0,0><<<dim3(8, 79), 256, 0, stream>>>(aggb, Wot_l, tmp480, nullptr, nullptr, nullptr, NN, 480, 480);
    ln_kernel<<<640, 256, 0, stream>>>(x, tmp480, xb);
    gemm_bf16_kernel<1,1><<<dim3(15, 79), 256, 0, stream>>>(xb, Wf1t_l, nullptr, tmp960, nullptr, nullptr, NN, 480, 960);
    gemm_bf16_kernel<0,0><<<dim3(8, 79), 256, 0, stream>>>(tmp960, Wf2t_l, tmp480, nullptr, nullptr, nullptr, NN, 960, 480);
    ln_kernel<<<640, 256, 0, stream>>>(x, tmp480, xb);
  }

  gemm_bf16_kernel<1,0><<<dim3(8, 79), 256, 0, stream>>>(xb, Wh1t, tmp480, nullptr, nullptr, nullptr, NN, 480, 480);
  h2_kernel<<<640, 256, 0, stream>>>(tmp480, Wh2, batch, out);
}

// Round 6
// 1893.021 us; speedup vs baseline: 2.9764x; 1.1689x over previous
//
#include <hip/hip_runtime.h>
#include <hip/hip_bf16.h>

#define NN 10000
#define EE 160000
#define GG 64
#define DD 480
#define HH 4
#define LLAYERS 6
#define DHD 120
#define NB_ 128
#define TSIZE 4096
#define DMAXT 5.5f
#define LSCALE (4095.0f/5.5f)

#define INV_DH 0.09128709291752768f
#define INV_SQRT_DEG 0.25335277f
#define INV_AVG_NODES (1.0f/18.03065905448718f)

typedef __attribute__((ext_vector_type(8))) short bf16x8;
typedef __attribute__((ext_vector_type(4))) float f32x4;
typedef __attribute__((ext_vector_type(8))) unsigned short u16x8;

__device__ __forceinline__ float b2f(unsigned short u){ return __uint_as_float(((unsigned)u)<<16); }
__device__ __forceinline__ unsigned short f2b(float f){
  unsigned u = __float_as_uint(f);
  return (unsigned short)((u + 0x7fffu + ((u>>16)&1u)) >> 16);
}
__device__ __forceinline__ float wsum(float v){
  #pragma unroll
  for (int off=32; off>0; off>>=1) v += __shfl_xor(v, off, 64);
  return v;
}
__device__ __forceinline__ void glds16(const void* g, void* l) {
  __builtin_amdgcn_global_load_lds((const __attribute__((address_space(1))) unsigned int*)g,
                                   (__attribute__((address_space(3))) unsigned int*)l, 16, 0, 0);
}

// ---------------- zero ----------------
__global__ __launch_bounds__(256) void zero_kernel(int* __restrict__ cnt, float* __restrict__ out){
  int i = blockIdx.x*256 + threadIdx.x;
  if (i < NN) cnt[i] = 0;
  if (i < GG) out[i] = 0.f;
}

// ---------------- x = atom_table[node_atom] ----------------
__global__ __launch_bounds__(256) void gather_x_kernel(const float* __restrict__ at,
    const int* __restrict__ atom, float* __restrict__ x){
  const int wid = threadIdx.x >> 6, lane = threadIdx.x & 63;
  for (int n = blockIdx.x*4 + wid; n < NN; n += gridDim.x*4) {
    int a = atom[n];
    if (lane < 60) {
      const float4* src = (const float4*)(at + (size_t)a*DD + lane*8);
      float4* dst = (float4*)(x + (size_t)n*DD + lane*8);
      dst[0] = src[0]; dst[1] = src[1];
    }
  }
}

// ---------------- edge geometry: sh (E x 9 f32), dedge (E f32) ----------------
__global__ __launch_bounds__(256) void edge_geom_kernel(const float* __restrict__ pos,
    const int* __restrict__ esrc, const int* __restrict__ edst,
    float* __restrict__ sh, float* __restrict__ dedge){
  const int e = blockIdx.x*256 + threadIdx.x;
  if (e >= EE) return;
  int s = esrc[e], d = edst[e];
  float vx = pos[s*3+0]-pos[d*3+0];
  float vy = pos[s*3+1]-pos[d*3+1];
  float vz = pos[s*3+2]-pos[d*3+2];
  float rr = sqrtf(vx*vx+vy*vy+vz*vz);
  dedge[e] = rr;
  float r = rr + 1e-12f;
  float x = vx/r, y = vy/r, z = vz/r;
  const float s3 = 1.7320508075688772f;
  const float s5 = 2.23606797749979f;
  const float s15 = 3.872983346207417f;
  float* o = sh + (size_t)e*9;
  o[0] = 1.f;
  o[1] = s3*x; o[2] = s3*y; o[3] = s3*z;
  o[4] = s15*x*y; o[5] = s15*y*z;
  o[6] = 0.5f*s5*(3.f*z*z-1.f);
  o[7] = s15*x*z;
  o[8] = 0.5f*s15*(x*x-y*y);
}

// ---------------- sort by dst ----------------
__global__ __launch_bounds__(256) void hist_kernel(const int* __restrict__ edst, int* __restrict__ cnt){
  int e = blockIdx.x*256 + threadIdx.x;
  if (e < EE) atomicAdd(&cnt[edst[e]], 1);
}

__global__ __launch_bounds__(1024) void scan_kernel(const int* __restrict__ cnt,
    int* __restrict__ row_ptr, int* __restrict__ cursor){
  __shared__ int sd[1024];
  __shared__ int s_carry;
  if (threadIdx.x == 0) s_carry = 0;
  __syncthreads();
  for (int base = 0; base < NN; base += 1024) {
    int i = base + threadIdx.x;
    int v = (i < NN) ? cnt[i] : 0;
    sd[threadIdx.x] = v;
    __syncthreads();
    for (int off = 1; off < 1024; off <<= 1) {
      int t = 0;
      if ((int)threadIdx.x >= off) t = sd[threadIdx.x - off];
      __syncthreads();
      sd[threadIdx.x] += t;
      __syncthreads();
    }
    int incl = sd[threadIdx.x];
    int carry = s_carry;
    if (i < NN) { row_ptr[i] = carry + incl - v; cursor[i] = carry + incl - v; }
    __syncthreads();
    if (threadIdx.x == 1023) s_carry = carry + incl;
    __syncthreads();
  }
  if (threadIdx.x == 0) row_ptr[NN] = s_carry;
}

__global__ __launch_bounds__(256) void scatter_kernel(const int* __restrict__ esrc,
    const int* __restrict__ edst, int* __restrict__ cursor,
    int* __restrict__ eid, int* __restrict__ srcs){
  int e = blockIdx.x*256 + threadIdx.x;
  if (e < EE) {
    int n = edst[e];
    int p = atomicAdd(&cursor[n], 1);
    eid[p] = e;
    srcs[p] = esrc[e];
  }
}

// ---------------- gate/g0 lookup tables ----------------
__global__ __launch_bounds__(256) void table_kernel(
    const float* __restrict__ Wd1, const float* __restrict__ Wd2, const float* __restrict__ Wd3,
    const float* __restrict__ W1, const float* __restrict__ W2, const float* __restrict__ W3,
    float* __restrict__ Tg, float* __restrict__ Tl) {
  const int chain = blockIdx.y;
  const float *A1, *A2, *A3; int NC;
  if (chain == 0) { A1 = Wd1; A2 = Wd2; A3 = Wd3; NC = 1; }
  else { int l = chain-1; A1 = W1 + (size_t)l*128*64; A2 = W2 + (size_t)l*64*64; A3 = W3 + (size_t)l*64*4; NC = 4; }
  __shared__ float W1s[128*64];
  __shared__ float W2s[64*64];
  __shared__ float W3s[64*4];
  for (int i = threadIdx.x; i < 128*64; i += 256) W1s[i] = A1[i];
  for (int i = threadIdx.x; i < 64*64; i += 256) W2s[i] = A2[i];
  for (int i = threadIdx.x; i < 64*4; i += 256) W3s[i] = (i < 64*NC) ? A3[i] : 0.f;
  __syncthreads();
  const int t = blockIdx.x*256 + threadIdx.x;
  const float d = (float)t * (DMAXT/(float)(TSIZE-1));
  float t1[64];
  #pragma unroll
  for (int c = 0; c < 64; ++c) t1[c] = 0.f;
  for (int j = 0; j < 128; ++j) {
    float z = (d - (float)j*(5.0f/127.0f)) * (128.0f/5.0f);
    float f = __expf(-z*z);
    #pragma unroll
    for (int c = 0; c < 64; ++c) t1[c] += f * W1s[j*64 + c];
  }
  #pragma unroll
  for (int c = 0; c < 64; ++c) t1[c] = t1[c] / (1.f + __expf(-t1[c]));
  float t2[64];
  #pragma unroll
  for (int c = 0; c < 64; ++c) t2[c] = 0.f;
  for (int c = 0; c < 64; ++c) {
    float v = t1[c];
    #pragma unroll
    for (int c2 = 0; c2 < 64; ++c2) t2[c2] += v * W2s[c*64 + c2];
  }
  #pragma unroll
  for (int c = 0; c < 64; ++c) t2[c] = t2[c] / (1.f + __expf(-t2[c]));
  if (chain == 0) {
    float o = 0.f;
    for (int c = 0; c < 64; ++c) o += t2[c] * W3s[c];
    Tg[t] = o;
  } else {
    #pragma unroll
    for (int nc = 0; nc < 4; ++nc) {
      float o = 0.f;
      for (int c = 0; c < 64; ++c) o += t2[c] * W3s[c*4 + nc];
      Tl[((size_t)(chain-1)*TSIZE + t)*4 + nc] = o;
    }
  }
}

__device__ __forceinline__ float lookup1(const float* __restrict__ Tg, float d) {
  float u = d * LSCALE;
  if (u >= (float)(TSIZE-1)) return 0.f;
  int i = (int)u; float fr = u - (float)i;
  float a = Tg[i], b = Tg[i+1];
  return a + fr*(b-a);
}

// ---------------- weight transpose+convert ----------------
__global__ __launch_bounds__(256) void transpose_w_kernel(const float* __restrict__ W,
    __hip_bfloat16* __restrict__ Wt, int K, int N, int Npad,
    long long lstrideW, long long lstrideT) {
  __shared__ float T[32][33];
  const int l = blockIdx.z;
  W  += (size_t)l*lstrideW;
  Wt += (size_t)l*lstrideT;
  const int k0 = blockIdx.y*32, n0 = blockIdx.x*32;
  const int tx = threadIdx.x & 31, ty = threadIdx.x >> 5;
  #pragma unroll
  for (int r = 0; r < 32; r += 8) {
    int k = k0 + ty + r, n = n0 + tx;
    T[ty+r][tx] = (k < K && n < N) ? W[(size_t)k*N + n] : 0.f;
  }
  __syncthreads();
  #pragma unroll
  for (int r = 0; r < 32; r += 8) {
    int n = n0 + ty + r, k = k0 + tx;
    if (n < Npad && k < K)
      ((unsigned short*)Wt)[(size_t)n*K + k] = f2b(T[tx][ty+r]);
  }
}

// ---------------- bf16 MFMA GEMM: tile 128x64x32, 4 waves ----------------
template<int SILU, int OUT>
__global__ __launch_bounds__(256) void gemm_bf16_kernel(
    const __hip_bfloat16* __restrict__ A, const __hip_bfloat16* __restrict__ Bt,
    float* __restrict__ Cf, __hip_bfloat16* __restrict__ Cb0,
    __hip_bfloat16* __restrict__ Cb1, __hip_bfloat16* __restrict__ Cb2,
    int M, int K, int Nc) {
  __shared__ char smem[(512 + 256) * 16];
  char* AsB = smem;
  char* BsB = smem + 8192;
  const int tid = threadIdx.x;
  const int lane = tid & 63, wid = tid >> 6;
  const int wm = wid >> 1, wn = wid & 1;
  const long long m0 = (long long)blockIdx.y * 128;
  const int n0 = blockIdx.x * 64;

  const int arow_loc = (wid & 1)*64 + lane;
  long long gr = m0 + arow_loc; if (gr >= M) gr = M - 1;
  const __hip_bfloat16* aptr = A + gr * (size_t)K;
  const int khiA0 = wid >> 1, khiA1 = 2 + (wid >> 1);
  char* adst0 = AsB + wid*64*16;
  char* adst1 = AsB + 4096 + wid*64*16;
  const __hip_bfloat16* bptr = Bt + (size_t)(n0 + lane) * K;
  char* bdst = BsB + wid*64*16;

  f32x4 acc[4][2];
  #pragma unroll
  for (int i = 0; i < 4; ++i)
    #pragma unroll
    for (int j = 0; j < 2; ++j)
      acc[i][j] = (f32x4){0.f,0.f,0.f,0.f};

  const int lr = lane & 15, lkh = lane >> 4;

  for (int kt = 0; kt < K; kt += 32) {
    __syncthreads();
    glds16(aptr + kt + khiA0*8, adst0);
    glds16(aptr + kt + khiA1*8, adst1);
    glds16(bptr + kt + wid*8, bdst);
    __syncthreads();
    bf16x8 afr[4], bfr[2];
    #pragma unroll
    for (int fm = 0; fm < 4; ++fm)
      afr[fm] = *reinterpret_cast<const bf16x8*>(AsB + (lkh*128 + wm*64 + fm*16 + lr)*16);
    #pragma unroll
    for (int fn = 0; fn < 2; ++fn)
      bfr[fn] = *reinterpret_cast<const bf16x8*>(BsB + (lkh*64 + wn*32 + fn*16 + lr)*16);
    #pragma unroll
    for (int fm = 0; fm < 4; ++fm)
      #pragma unroll
      for (int fn = 0; fn < 2; ++fn)
        acc[fm][fn] = __builtin_amdgcn_mfma_f32_16x16x32_bf16(afr[fm], bfr[fn], acc[fm][fn], 0, 0, 0);
  }

  const int seg = n0 >> 9;
  const int c0 = (OUT == 2) ? (n0 & 511) : n0;
  unsigned short* qdst = nullptr;
  if (OUT == 2) qdst = (unsigned short*)(seg == 0 ? Cb0 : (seg == 1 ? Cb1 : Cb2));
  #pragma unroll
  for (int fm = 0; fm < 4; ++fm) {
    #pragma unroll
    for (int fn = 0; fn < 2; ++fn) {
      #pragma unroll
      for (int j = 0; j < 4; ++j) {
        long long r = m0 + wm*64 + fm*16 + lkh*4 + j;
        int c = c0 + wn*32 + fn*16 + lr;
        if (r < M && c < Nc) {
          float v = acc[fm][fn][j];
          if (SILU) v = v / (1.f + __expf(-v));
          if (OUT == 0) Cf[r*(size_t)Nc + c] = v;
          else if (OUT == 1) ((unsigned short*)Cb0)[r*(size_t)Nc + c] = f2b(v);
          else qdst[r*(size_t)Nc + c] = f2b(v);
        }
      }
    }
  }
}

// ---------------- deg ----------------
__global__ __launch_bounds__(256) void deg_kernel(const float* __restrict__ dedge,
    const float* __restrict__ sh, const float* __restrict__ Tg,
    const int* __restrict__ row_ptr, const int* __restrict__ eid,
    const float* __restrict__ Wdeg, float* __restrict__ x, __hip_bfloat16* __restrict__ xb) {
  const int wid = threadIdx.x >> 6, lane = threadIdx.x & 63;
  for (int n = blockIdx.x*4 + wid; n < NN; n += gridDim.x*4) {
    const int e0 = row_ptr[n], e1 = row_ptr[n+1];
    float s9[9] = {0,0,0,0,0,0,0,0,0};
    for (int p = e0 + lane; p < e1; p += 64) {
      int e = eid[p];
      float g = lookup1(Tg, dedge[e]);
      const float* srow = sh + (size_t)e*9;
      #pragma unroll
      for (int s = 0; s < 9; ++s) s9[s] += g*srow[s];
    }
    #pragma unroll
    for (int s = 0; s < 9; ++s) s9[s] = wsum(s9[s]);
    #pragma unroll
    for (int r = 0; r < 8; ++r) {
      int d = lane + (r<<6);
      if (d < DD) {
        float acc = 0.f;
        #pragma unroll
        for (int s = 0; s < 9; ++s) acc += s9[s]*Wdeg[s*DD + d];
        float vv = x[(size_t)n*DD + d] + acc * INV_SQRT_DEG;
        x[(size_t)n*DD + d] = vv;
        ((unsigned short*)xb)[(size_t)n*DD + d] = f2b(vv);
      }
    }
  }
}

// ---------------- P[n,h,s] ----------------
__global__ __launch_bounds__(256) void p_kernel(const __hip_bfloat16* __restrict__ xq,
    const float* __restrict__ Wsh_l, float* __restrict__ P) {
  const int wid = threadIdx.x >> 6, lane = threadIdx.x & 63;
  for (int n = blockIdx.x*4 + wid; n < NN; n += gridDim.x*4) {
    if (lane < 36) {
      int h = lane/9, s = lane%9;
      const unsigned short* q = (const unsigned short*)(xq + (size_t)n*DD + h*DHD);
      const float* w = Wsh_l + s*DD + h*DHD;
      float acc = 0.f;
      #pragma unroll
      for (int db = 0; db < 15; ++db) {
        u16x8 v = *reinterpret_cast<const u16x8*>(q + db*8);
        #pragma unroll
        for (int j = 0; j < 8; ++j) acc += b2f(v[j])*w[db*8+j];
      }
      P[(size_t)n*36 + lane] = acc;
    }
  }
}

// ---------------- per-edge logit coefficients: sb[p][h] = {scale, bias} ----------------
// logit = qk_dot * scale + bias ;  scale = INV_DH*gate_h(d) ; bias = (sh . P[dst,h]) * scale
__global__ __launch_bounds__(256) void coef_kernel(
    const int* __restrict__ eid, const int* __restrict__ edst,
    const float* __restrict__ sh, const float* __restrict__ dedge,
    const float* __restrict__ Tl, const float* __restrict__ P,
    float2* __restrict__ sb) {
  const int p = blockIdx.x*256 + threadIdx.x;
  if (p >= EE) return;
  const int e = eid[p];
  const int n = edst[e];
  const float* srow = sh + (size_t)e*9;
  float s0 = srow[0], s1 = srow[1], s2 = srow[2], s3 = srow[3], s4 = srow[4];
  float s5 = srow[5], s6 = srow[6], s7 = srow[7], s8 = srow[8];
  const float* Pn = P + (size_t)n*36;
  float g[4];
  {
    float u = dedge[e] * LSCALE;
    if (u >= (float)(TSIZE-1)) { g[0]=g[1]=g[2]=g[3]=0.f; }
    else {
      int ti = (int)u; float fr = u - (float)ti;
      const float4 ga = *reinterpret_cast<const float4*>(Tl + ti*4);
      const float4 gb = *reinterpret_cast<const float4*>(Tl + ti*4 + 4);
      g[0] = ga.x + fr*(gb.x-ga.x); g[1] = ga.y + fr*(gb.y-ga.y);
      g[2] = ga.z + fr*(gb.z-ga.z); g[3] = ga.w + fr*(gb.w-ga.w);
    }
  }
  #pragma unroll
  for (int h = 0; h < 4; ++h) {
    const float* Ph = Pn + h*9;
    float lp = s0*Ph[0]+s1*Ph[1]+s2*Ph[2]+s3*Ph[3]+s4*Ph[4]
             + s5*Ph[5]+s6*Ph[6]+s7*Ph[7]+s8*Ph[8];
    float sc = INV_DH * g[h];
    sb[(size_t)p*4 + h] = make_float2(sc, lp*sc);
  }
}

// ---------------- fused attention: 1 node/wave, q in regs, unrolled, staged srcs ----------------
__global__ __launch_bounds__(256) void attn_kernel(
    const __hip_bfloat16* __restrict__ xq, const __hip_bfloat16* __restrict__ xk,
    const __hip_bfloat16* __restrict__ xv, const float2* __restrict__ sb,
    const int* __restrict__ row_ptr, const int* __restrict__ srcs,
    __hip_bfloat16* __restrict__ aggout) {
  const int wid = threadIdx.x >> 6, lane = threadIdx.x & 63;
  __shared__ float l_s[4][64][4];
  __shared__ int   src_sh[4][64];
  float (*ls)[4] = l_s[wid];
  int* srcS = src_sh[wid];
  const int hh = lane >> 4, li = lane & 15;
  const int hd = (lane < 60) ? (lane/15) : 3;
  const unsigned short* xkp = (const unsigned short*)xk;
  const unsigned short* xvp = (const unsigned short*)xv;
  const int doff = hh*DHD + li*8;
  for (int n = blockIdx.x*4 + wid; n < NN; n += gridDim.x*4) {
    const int e0 = row_ptr[n], e1 = row_ptr[n+1];
    // q fragment in registers (constant for this node)
    float qf[8] = {0,0,0,0,0,0,0,0};
    if (li < 15) {
      u16x8 v = *reinterpret_cast<const u16x8*>((const unsigned short*)xq + (size_t)n*DD + doff);
      #pragma unroll
      for (int j = 0; j < 8; ++j) qf[j] = b2f(v[j]);
    }
    float m_reg = -1e30f, den_reg = 0.f;
    float agg[8] = {0,0,0,0,0,0,0,0};
    for (int c0 = e0; c0 < e1; c0 += 64) {
      const int cn = min(64, e1 - c0);
      if (lane < cn) srcS[lane] = srcs[c0 + lane];
      asm volatile("s_waitcnt lgkmcnt(0)" ::: "memory");
      // ---- phase A: logits, unroll 4 ----
      int i = 0;
      for (; i + 4 <= cn; i += 4) {
        int sA = srcS[i], sB = srcS[i+1], sC = srcS[i+2], sD = srcS[i+3];
        float a0 = 0.f, a1 = 0.f, a2 = 0.f, a3 = 0.f;
        if (li < 15) {
          u16x8 k0 = *reinterpret_cast<const u16x8*>(xkp + (size_t)sA*DD + doff);
          u16x8 k1 = *reinterpret_cast<const u16x8*>(xkp + (size_t)sB*DD + doff);
          u16x8 k2 = *reinterpret_cast<const u16x8*>(xkp + (size_t)sC*DD + doff);
          u16x8 k3 = *reinterpret_cast<const u16x8*>(xkp + (size_t)sD*DD + doff);
          #pragma unroll
          for (int j = 0; j < 8; ++j) {
            a0 += qf[j]*b2f(k0[j]);
            a1 += qf[j]*b2f(k1[j]);
            a2 += qf[j]*b2f(k2[j]);
            a3 += qf[j]*b2f(k3[j]);
          }
        }
        #pragma unroll
        for (int off = 1; off < 16; off <<= 1) {
          a0 += __shfl_xor(a0, off, 64);
          a1 += __shfl_xor(a1, off, 64);
          a2 += __shfl_xor(a2, off, 64);
          a3 += __shfl_xor(a3, off, 64);
        }
        if (li == 0) {
          float2 cA = sb[(size_t)(c0+i+0)*4 + hh];
          float2 cB = sb[(size_t)(c0+i+1)*4 + hh];
          float2 cC = sb[(size_t)(c0+i+2)*4 + hh];
          float2 cD = sb[(size_t)(c0+i+3)*4 + hh];
          ls[i+0][hh] = a0*cA.x + cA.y;
          ls[i+1][hh] = a1*cB.x + cB.y;
          ls[i+2][hh] = a2*cC.x + cC.y;
          ls[i+3][hh] = a3*cD.x + cD.y;
        }
      }
      for (; i < cn; ++i) {
        int sA = srcS[i];
        float a0 = 0.f;
        if (li < 15) {
          u16x8 k0 = *reinterpret_cast<const u16x8*>(xkp + (size_t)sA*DD + doff);
          #pragma unroll
          for (int j = 0; j < 8; ++j) a0 += qf[j]*b2f(k0[j]);
        }
        #pragma unroll
        for (int off = 1; off < 16; off <<= 1) a0 += __shfl_xor(a0, off, 64);
        if (li == 0) {
          float2 cA = sb[(size_t)(c0+i)*4 + hh];
          ls[i][hh] = a0*cA.x + cA.y;
        }
      }
      asm volatile("s_waitcnt lgkmcnt(0)" ::: "memory");
      // ---- phase B: online softmax ----
      const int h = lane & 3, i0 = lane >> 2;
      float cm = -1e30f;
      for (int i2 = i0; i2 < cn; i2 += 16) cm = fmaxf(cm, ls[i2][h]);
      #pragma unroll
      for (int off = 4; off < 64; off <<= 1) cm = fmaxf(cm, __shfl_xor(cm, off, 64));
      const float newm = fmaxf(m_reg, cm);
      const float f = __expf(m_reg - newm);
      float cs = 0.f;
      for (int i2 = i0; i2 < cn; i2 += 16) {
        float a = __expf(ls[i2][h] - newm);
        ls[i2][h] = a;
        cs += a;
      }
      #pragma unroll
      for (int off = 4; off < 64; off <<= 1) cs += __shfl_xor(cs, off, 64);
      m_reg = newm;
      den_reg = den_reg*f + cs;
      asm volatile("s_waitcnt lgkmcnt(0)" ::: "memory");
      // ---- phase C: aggregate, unroll 4 ----
      const float fh = __shfl(f, hd);
      #pragma unroll
      for (int j = 0; j < 8; ++j) agg[j] *= fh;
      i = 0;
      for (; i + 4 <= cn; i += 4) {
        int sA = srcS[i], sB = srcS[i+1], sC = srcS[i+2], sD = srcS[i+3];
        float a0 = ls[i][hd], a1 = ls[i+1][hd], a2 = ls[i+2][hd], a3 = ls[i+3][hd];
        if (lane < 60) {
          u16x8 v0 = *reinterpret_cast<const u16x8*>(xvp + (size_t)sA*DD + lane*8);
          u16x8 v1 = *reinterpret_cast<const u16x8*>(xvp + (size_t)sB*DD + lane*8);
          u16x8 v2 = *reinterpret_cast<const u16x8*>(xvp + (size_t)sC*DD + lane*8);
          u16x8 v3 = *reinterpret_cast<const u16x8*>(xvp + (size_t)sD*DD + lane*8);
          #pragma unroll
          for (int j = 0; j < 8; ++j)
            agg[j] += a0*b2f(v0[j]) + a1*b2f(v1[j]) + a2*b2f(v2[j]) + a3*b2f(v3[j]);
        }
      }
      for (; i < cn; ++i) {
        int sA = srcS[i];
        float a0 = ls[i][hd];
        if (lane < 60) {
          u16x8 v0 = *reinterpret_cast<const u16x8*>(xvp + (size_t)sA*DD + lane*8);
          #pragma unroll
          for (int j = 0; j < 8; ++j) agg[j] += a0*b2f(v0[j]);
        }
      }
    }
    const float dh2 = __shfl(den_reg, hd);
    if (lane < 60) {
      const float sc = INV_SQRT_DEG / (dh2 + 1e-12f);
      u16x8 o;
      #pragma unroll
      for (int j = 0; j < 8; ++j) o[j] = f2b(agg[j]*sc);
      *reinterpret_cast<u16x8*>((unsigned short*)aggout + (size_t)n*DD + lane*8) = o;
    }
  }
}

// ---------------- residual + LayerNorm ----------------
__global__ __launch_bounds__(256) void ln_kernel(float* __restrict__ x, const float* __restrict__ t,
    __hip_bfloat16* __restrict__ xb) {
  const int wid = threadIdx.x >> 6, lane = threadIdx.x & 63;
  for (int n = blockIdx.x*4 + wid; n < NN; n += gridDim.x*4) {
    float4 a0 = make_float4(0,0,0,0), a1 = make_float4(0,0,0,0);
    float s = 0.f, s2 = 0.f;
    if (lane < 60) {
      const float4* xp = (const float4*)(x + (size_t)n*DD + lane*8);
      const float4* tp = (const float4*)(t + (size_t)n*DD + lane*8);
      float4 b0 = tp[0], b1 = tp[1];
      a0 = xp[0]; a1 = xp[1];
      a0.x += b0.x; a0.y += b0.y; a0.z += b0.z; a0.w += b0.w;
      a1.x += b1.x; a1.y += b1.y; a1.z += b1.z; a1.w += b1.w;
      s  = a0.x+a0.y+a0.z+a0.w + a1.x+a1.y+a1.z+a1.w;
      s2 = a0.x*a0.x+a0.y*a0.y+a0.z*a0.z+a0.w*a0.w
         + a1.x*a1.x+a1.y*a1.y+a1.z*a1.z+a1.w*a1.w;
    }
    s = wsum(s); s2 = wsum(s2);
    const float mu = s * (1.f/(float)DD);
    const float var = s2 * (1.f/(float)DD) - mu*mu;
    const float rs = rsqrtf(var + 1e-5f);
    if (lane < 60) {
      float4* xp = (float4*)(x + (size_t)n*DD + lane*8);
      a0.x = (a0.x-mu)*rs; a0.y = (a0.y-mu)*rs; a0.z = (a0.z-mu)*rs; a0.w = (a0.w-mu)*rs;
      a1.x = (a1.x-mu)*rs; a1.y = (a1.y-mu)*rs; a1.z = (a1.z-mu)*rs; a1.w = (a1.w-mu)*rs;
      xp[0] = a0; xp[1] = a1;
      u16x8 o;
      o[0]=f2b(a0.x); o[1]=f2b(a0.y); o[2]=f2b(a0.z); o[3]=f2b(a0.w);
      o[4]=f2b(a1.x); o[5]=f2b(a1.y); o[6]=f2b(a1.z); o[7]=f2b(a1.w);
      *reinterpret_cast<u16x8*>((unsigned short*)xb + (size_t)n*DD + lane*8) = o;
    }
  }
}

// ---------------- final ----------------
__global__ __launch_bounds__(256) void h2_kernel(const float* __restrict__ t,
    const float* __restrict__ Wh2, const int* __restrict__ batch, float* __restrict__ out) {
  const int wid = threadIdx.x >> 6, lane = threadIdx.x & 63;
  for (int n = blockIdx.x*4 + wid; n < NN; n += gridDim.x*4) {
    float s = 0.f;
    if (lane < 60) {
      const float4* tp = (const float4*)(t + (size_t)n*DD + lane*8);
      const float4* wp = (const float4*)(Wh2 + lane*8);
      float4 t0 = tp[0], t1 = tp[1], w0 = wp[0], w1 = wp[1];
      s = t0.x*w0.x+t0.y*w0.y+t0.z*w0.z+t0.w*w0.w
        + t1.x*w1.x+t1.y*w1.y+t1.z*w1.z+t1.w*w1.w;
    }
    s = wsum(s);
    if (lane == 0) atomicAdd(&out[batch[n]], s * INV_AVG_NODES);
  }
}

extern "C" void kernel_launch(void* const* d_in, const int* in_sizes, int n_in,
                              void* d_out, int out_size, void* d_ws, size_t ws_size,
                              hipStream_t stream) {
  const float* pos        = (const float*)d_in[0];
  const int*   node_atom  = (const int*)  d_in[1];
  const int*   edge_src   = (const int*)  d_in[2];
  const int*   edge_dst   = (const int*)  d_in[3];
  const int*   batch      = (const int*)  d_in[4];
  const float* atom_table = (const float*)d_in[5];
  const float* Wdeg       = (const float*)d_in[6];
  const float* Wd1        = (const float*)d_in[7];
  const float* Wd2        = (const float*)d_in[8];
  const float* Wd3        = (const float*)d_in[9];
  const float* Wq         = (const float*)d_in[10];
  const float* Wk         = (const float*)d_in[11];
  const float* Wv         = (const float*)d_in[12];
  const float* Wsh        = (const float*)d_in[13];
  const float* W1         = (const float*)d_in[14];
  const float* W2         = (const float*)d_in[15];
  const float* W3         = (const float*)d_in[16];
  const float* Wo         = (const float*)d_in[17];
  const float* Wf1        = (const float*)d_in[18];
  const float* Wf2        = (const float*)d_in[19];
  const float* Wh1        = (const float*)d_in[20];
  const float* Wh2        = (const float*)d_in[21];
  float* out = (float*)d_out;
  char*  wsb = (char*)d_ws;

  size_t off = 0;
  auto alloc = [&](size_t bytes) { size_t o = off; off += (bytes + 255) & ~(size_t)255; return o; };
  float*  x      = (float*) (wsb + alloc((size_t)NN*DD*4));
  __hip_bfloat16* xb   = (__hip_bfloat16*)(wsb + alloc((size_t)NN*DD*2));
  __hip_bfloat16* xq   = (__hip_bfloat16*)(wsb + alloc((size_t)NN*DD*2));
  __hip_bfloat16* xk   = (__hip_bfloat16*)(wsb + alloc((size_t)NN*DD*2));
  __hip_bfloat16* xv   = (__hip_bfloat16*)(wsb + alloc((size_t)NN*DD*2));
  float*  shb    = (float*) (wsb + alloc((size_t)EE*9*4));
  float*  dedge  = (float*) (wsb + alloc((size_t)EE*4));
  float*  P      = (float*) (wsb + alloc((size_t)NN*36*4));
  float2* sbuf   = (float2*)(wsb + alloc((size_t)EE*4*8));
  __hip_bfloat16* aggb = (__hip_bfloat16*)(wsb + alloc((size_t)NN*DD*2));
  float*  tmp480 = (float*) (wsb + alloc((size_t)NN*DD*4));
  __hip_bfloat16* tmp960 = (__hip_bfloat16*)(wsb + alloc((size_t)NN*960*2));
  float*  Tg     = (float*) (wsb + alloc((size_t)TSIZE*4));
  float*  Tl     = (float*) (wsb + alloc((size_t)LLAYERS*TSIZE*4*4));
  __hip_bfloat16* Wqkvt = (__hip_bfloat16*)(wsb + alloc((size_t)LLAYERS*1536*480*2));
  __hip_bfloat16* Wot   = (__hip_bfloat16*)(wsb + alloc((size_t)LLAYERS*512*480*2));
  __hip_bfloat16* Wf1t  = (__hip_bfloat16*)(wsb + alloc((size_t)LLAYERS*960*480*2));
  __hip_bfloat16* Wf2t  = (__hip_bfloat16*)(wsb + alloc((size_t)LLAYERS*512*960*2));
  __hip_bfloat16* Wh1t  = (__hip_bfloat16*)(wsb + alloc((size_t)512*480*2));
  int* cnt     = (int*)(wsb + alloc((size_t)NN*4));
  int* row_ptr = (int*)(wsb + alloc((size_t)(NN+1)*4));
  int* cursor  = (int*)(wsb + alloc((size_t)NN*4));
  int* eid     = (int*)(wsb + alloc((size_t)EE*4));
  int* srcs    = (int*)(wsb + alloc((size_t)EE*4));
  (void)ws_size;

  auto tr = [&](const float* W, __hip_bfloat16* Wt, int K, int N, int Npad,
                long long lsW, long long lsT, int L) {
    dim3 g((Npad+31)/32, (K+31)/32, L);
    transpose_w_kernel<<<g, 256, 0, stream>>>(W, Wt, K, N, Npad, lsW, lsT);
  };

  tr(Wq,  Wqkvt + 0*512*480,    480, 480, 512, 480*480, 1536*480, LLAYERS);
  tr(Wk,  Wqkvt + 1*512*480,    480, 480, 512, 480*480, 1536*480, LLAYERS);
  tr(Wv,  Wqkvt + 2*512*480,    480, 480, 512, 480*480, 1536*480, LLAYERS);
  tr(Wo,  Wot,  480, 480, 512, 480*480, 512*480, LLAYERS);
  tr(Wf1, Wf1t, 480, 960, 960, 480*960, 960*480, LLAYERS);
  tr(Wf2, Wf2t, 960, 480, 512, 960*480, 512*960, LLAYERS);
  tr(Wh1, Wh1t, 480, 480, 512, 480*480, 512*480, 1);

  zero_kernel<<<(NN+255)/256, 256, 0, stream>>>(cnt, out);
  gather_x_kernel<<<640, 256, 0, stream>>>(atom_table, node_atom, x);
  edge_geom_kernel<<<(EE+255)/256, 256, 0, stream>>>(pos, edge_src, edge_dst, shb, dedge);
  hist_kernel<<<(EE+255)/256, 256, 0, stream>>>(edge_dst, cnt);
  scan_kernel<<<1, 1024, 0, stream>>>(cnt, row_ptr, cursor);
  scatter_kernel<<<(EE+255)/256, 256, 0, stream>>>(edge_src, edge_dst, cursor, eid, srcs);
  table_kernel<<<dim3(TSIZE/256, 1+LLAYERS), 256, 0, stream>>>(Wd1, Wd2, Wd3, W1, W2, W3, Tg, Tl);
  deg_kernel<<<2500, 256, 0, stream>>>(dedge, shb, Tg, row_ptr, eid, Wdeg, x, xb);

  for (int l = 0; l < LLAYERS; ++l) {
    const __hip_bfloat16* Wqkvt_l = Wqkvt + (size_t)l*1536*480;
    const __hip_bfloat16* Wot_l   = Wot   + (size_t)l*512*480;
    const __hip_bfloat16* Wf1t_l  = Wf1t  + (size_t)l*960*480;
    const __hip_bfloat16* Wf2t_l  = Wf2t  + (size_t)l*512*960;
    const float* Wsh_l = Wsh + (size_t)l*9*DD;
    const float* Tl_l  = Tl  + (size_t)l*TSIZE*4;

    gemm_bf16_kernel<0,2><<<dim3(24, 79), 256, 0, stream>>>(xb, Wqkvt_l, nullptr, xq, xk, xv, NN, 480, 480);
    p_kernel<<<2500, 256, 0, stream>>>(xq, Wsh_l, P);
    coef_kernel<<<(EE+255)/256, 256, 0, stream>>>(eid, edge_dst, shb, dedge, Tl_l, P, sbuf);
    attn_kernel<<<2500, 256, 0, stream>>>(xq, xk, xv, sbuf, row_ptr, srcs, aggb);
    gemm_bf16_kernel<0,0><<<dim3(8, 79), 256, 0, stream>>>(aggb, Wot_l, tmp480, nullptr, nullptr, nullptr, NN, 480, 480);
    ln_kernel<<<640, 256, 0, stream>>>(x, tmp480, xb);
    gemm_bf16_kernel<1,1><<<dim3(15, 79), 256, 0, stream>>>(xb, Wf1t_l, nullptr, tmp960, nullptr, nullptr, NN, 480, 960);
    gemm_bf16_kernel<0,0><<<dim3(8, 79), 256, 0, stream>>>(tmp960, Wf2t_l, tmp480, nullptr, nullptr, nullptr, NN, 960, 480);
    ln_kernel<<<640, 256, 0, stream>>>(x, tmp480, xb);
  }

  gemm_bf16_kernel<1,0><<<dim3(8, 79), 256, 0, stream>>>(xb, Wh1t, tmp480, nullptr, nullptr, nullptr, NN, 480, 480);
  h2_kernel<<<640, 256, 0, stream>>>(tmp480, Wh2, batch, out);
}

// Round 8
// 1734.390 us; speedup vs baseline: 3.2486x; 1.0915x over previous
//
#include <hip/hip_runtime.h>
#include <hip/hip_bf16.h>

#define NN 10000
#define EE 160000
#define GG 64
#define DD 480
#define HH 4
#define LLAYERS 6
#define DHD 120
#define NB_ 128
#define TSIZE 4096
#define DMAXT 5.5f
#define LSCALE (4095.0f/5.5f)

#define INV_DH 0.09128709291752768f
#define INV_SQRT_DEG 0.25335277f
#define INV_AVG_NODES (1.0f/18.03065905448718f)

typedef __attribute__((ext_vector_type(8))) short bf16x8;
typedef __attribute__((ext_vector_type(4))) float f32x4;
typedef __attribute__((ext_vector_type(8))) unsigned short u16x8;

__device__ __forceinline__ float b2f(unsigned short u){ return __uint_as_float(((unsigned)u)<<16); }
__device__ __forceinline__ unsigned short f2b(float f){
  unsigned u = __float_as_uint(f);
  return (unsigned short)((u + 0x7fffu + ((u>>16)&1u)) >> 16);
}
__device__ __forceinline__ float wsum(float v){
  #pragma unroll
  for (int off=32; off>0; off>>=1) v += __shfl_xor(v, off, 64);
  return v;
}
__device__ __forceinline__ void glds16(const void* g, void* l) {
  __builtin_amdgcn_global_load_lds((const __attribute__((address_space(1))) unsigned int*)g,
                                   (__attribute__((address_space(3))) unsigned int*)l, 16, 0, 0);
}

// ---------------- zero ----------------
__global__ __launch_bounds__(256) void zero_kernel(int* __restrict__ cnt, float* __restrict__ out){
  int i = blockIdx.x*256 + threadIdx.x;
  if (i < NN) cnt[i] = 0;
  if (i < GG) out[i] = 0.f;
}

// ---------------- x = atom_table[node_atom] ----------------
__global__ __launch_bounds__(256) void gather_x_kernel(const float* __restrict__ at,
    const int* __restrict__ atom, float* __restrict__ x){
  const int wid = threadIdx.x >> 6, lane = threadIdx.x & 63;
  for (int n = blockIdx.x*4 + wid; n < NN; n += gridDim.x*4) {
    int a = atom[n];
    if (lane < 60) {
      const float4* src = (const float4*)(at + (size_t)a*DD + lane*8);
      float4* dst = (float4*)(x + (size_t)n*DD + lane*8);
      dst[0] = src[0]; dst[1] = src[1];
    }
  }
}

// ---------------- edge geometry ----------------
__global__ __launch_bounds__(256) void edge_geom_kernel(const float* __restrict__ pos,
    const int* __restrict__ esrc, const int* __restrict__ edst,
    float* __restrict__ sh, float* __restrict__ dedge){
  const int e = blockIdx.x*256 + threadIdx.x;
  if (e >= EE) return;
  int s = esrc[e], d = edst[e];
  float vx = pos[s*3+0]-pos[d*3+0];
  float vy = pos[s*3+1]-pos[d*3+1];
  float vz = pos[s*3+2]-pos[d*3+2];
  float rr = sqrtf(vx*vx+vy*vy+vz*vz);
  dedge[e] = rr;
  float r = rr + 1e-12f;
  float x = vx/r, y = vy/r, z = vz/r;
  const float s3 = 1.7320508075688772f;
  const float s5 = 2.23606797749979f;
  const float s15 = 3.872983346207417f;
  float* o = sh + (size_t)e*9;
  o[0] = 1.f;
  o[1] = s3*x; o[2] = s3*y; o[3] = s3*z;
  o[4] = s15*x*y; o[5] = s15*y*z;
  o[6] = 0.5f*s5*(3.f*z*z-1.f);
  o[7] = s15*x*z;
  o[8] = 0.5f*s15*(x*x-y*y);
}

// ---------------- sort by dst ----------------
__global__ __launch_bounds__(256) void hist_kernel(const int* __restrict__ edst, int* __restrict__ cnt){
  int e = blockIdx.x*256 + threadIdx.x;
  if (e < EE) atomicAdd(&cnt[edst[e]], 1);
}

__global__ __launch_bounds__(1024) void scan_kernel(const int* __restrict__ cnt,
    int* __restrict__ row_ptr, int* __restrict__ cursor){
  __shared__ int sd[1024];
  __shared__ int s_carry;
  if (threadIdx.x == 0) s_carry = 0;
  __syncthreads();
  for (int base = 0; base < NN; base += 1024) {
    int i = base + threadIdx.x;
    int v = (i < NN) ? cnt[i] : 0;
    sd[threadIdx.x] = v;
    __syncthreads();
    for (int off = 1; off < 1024; off <<= 1) {
      int t = 0;
      if ((int)threadIdx.x >= off) t = sd[threadIdx.x - off];
      __syncthreads();
      sd[threadIdx.x] += t;
      __syncthreads();
    }
    int incl = sd[threadIdx.x];
    int carry = s_carry;
    if (i < NN) { row_ptr[i] = carry + incl - v; cursor[i] = carry + incl - v; }
    __syncthreads();
    if (threadIdx.x == 1023) s_carry = carry + incl;
    __syncthreads();
  }
  if (threadIdx.x == 0) row_ptr[NN] = s_carry;
}

__global__ __launch_bounds__(256) void scatter_kernel(const int* __restrict__ esrc,
    const int* __restrict__ edst, int* __restrict__ cursor,
    int* __restrict__ eid, int* __restrict__ srcs){
  int e = blockIdx.x*256 + threadIdx.x;
  if (e < EE) {
    int n = edst[e];
    int p = atomicAdd(&cursor[n], 1);
    eid[p] = e;
    srcs[p] = esrc[e];
  }
}

// ---------------- gate/g0 lookup tables: WAVE per table point, lane = channel ----------------
__global__ __launch_bounds__(1024) void table_kernel(
    const float* __restrict__ Wd1, const float* __restrict__ Wd2, const float* __restrict__ Wd3,
    const float* __restrict__ W1, const float* __restrict__ W2, const float* __restrict__ W3,
    float* __restrict__ Tg, float* __restrict__ Tl) {
  const int chain = blockIdx.y;
  const float *A1, *A2, *A3; int NC;
  if (chain == 0) { A1 = Wd1; A2 = Wd2; A3 = Wd3; NC = 1; }
  else { int l = chain-1; A1 = W1 + (size_t)l*128*64; A2 = W2 + (size_t)l*64*64; A3 = W3 + (size_t)l*64*4; NC = 4; }
  __shared__ float W1s[128*64];
  __shared__ float W2s[64*64];
  __shared__ float W3s[64*4];
  for (int i = threadIdx.x; i < 128*64; i += 1024) W1s[i] = A1[i];
  for (int i = threadIdx.x; i < 64*64; i += 1024) W2s[i] = A2[i];
  for (int i = threadIdx.x; i < 64*4; i += 1024) W3s[i] = (i < 64*NC) ? A3[i] : 0.f;
  __syncthreads();
  const int wid = threadIdx.x >> 6, lane = threadIdx.x & 63;
  const int t = blockIdx.x*16 + wid;
  const float d = (float)t * (DMAXT/(float)(TSIZE-1));
  // layer 1: per-lane channel accumulation
  float t1 = 0.f;
  #pragma unroll 4
  for (int j = 0; j < 128; ++j) {
    float z = (d - (float)j*(5.0f/127.0f)) * (128.0f/5.0f);
    float f = __expf(-z*z);
    t1 += f * W1s[j*64 + lane];
  }
  t1 = t1 / (1.f + __expf(-t1));
  // layer 2: cross-channel via shfl broadcast
  float t2 = 0.f;
  #pragma unroll 4
  for (int c = 0; c < 64; ++c) {
    float bc = __shfl(t1, c);
    t2 += bc * W2s[c*64 + lane];
  }
  t2 = t2 / (1.f + __expf(-t2));
  // layer 3: reduce
  if (chain == 0) {
    float o = wsum(t2 * W3s[lane]);
    if (lane == 0) Tg[t] = o;
  } else {
    #pragma unroll
    for (int nc = 0; nc < 4; ++nc) {
      float o = wsum(t2 * W3s[lane*4 + nc]);
      if (lane == 0) Tl[((size_t)(chain-1)*TSIZE + t)*4 + nc] = o;
    }
  }
}

__device__ __forceinline__ float lookup1(const float* __restrict__ Tg, float d) {
  float u = d * LSCALE;
  if (u >= (float)(TSIZE-1)) return 0.f;
  int i = (int)u; float fr = u - (float)i;
  float a = Tg[i], b = Tg[i+1];
  return a + fr*(b-a);
}

// ---------------- weight transpose+convert ----------------
__global__ __launch_bounds__(256) void transpose_w_kernel(const float* __restrict__ W,
    __hip_bfloat16* __restrict__ Wt, int K, int N, int Npad,
    long long lstrideW, long long lstrideT) {
  __shared__ float T[32][33];
  const int l = blockIdx.z;
  W  += (size_t)l*lstrideW;
  Wt += (size_t)l*lstrideT;
  const int k0 = blockIdx.y*32, n0 = blockIdx.x*32;
  const int tx = threadIdx.x & 31, ty = threadIdx.x >> 5;
  #pragma unroll
  for (int r = 0; r < 32; r += 8) {
    int k = k0 + ty + r, n = n0 + tx;
    T[ty+r][tx] = (k < K && n < N) ? W[(size_t)k*N + n] : 0.f;
  }
  __syncthreads();
  #pragma unroll
  for (int r = 0; r < 32; r += 8) {
    int n = n0 + ty + r, k = k0 + tx;
    if (n < Npad && k < K)
      ((unsigned short*)Wt)[(size_t)n*K + k] = f2b(T[tx][ty+r]);
  }
}

// ---------------- bf16 MFMA GEMM: tile 128x128x32, 8 waves ----------------
// Bt [Npad][K] transposed; OUT: 0=f32, 1=bf16, 2=QKV 3-way bf16 (512-col segments)
template<int SILU, int OUT>
__global__ __launch_bounds__(512) void gemm_bf16_kernel(
    const __hip_bfloat16* __restrict__ A, const __hip_bfloat16* __restrict__ Bt,
    float* __restrict__ Cf, __hip_bfloat16* __restrict__ Cb0,
    __hip_bfloat16* __restrict__ Cb1, __hip_bfloat16* __restrict__ Cb2,
    int M, int K, int Nc) {
  __shared__ char smem[16384];           // As 8KB [khi][row][16B] + Bs 8KB [khi][col][16B]
  char* AsB = smem;
  char* BsB = smem + 8192;
  const int tid = threadIdx.x;
  const int lane = tid & 63, wid = tid >> 6;      // 8 waves
  const int wm = wid >> 2, wn = wid & 3;          // wave tile: rows wm*64, cols wn*32
  const long long m0 = (long long)blockIdx.y * 128;
  const int n0 = blockIdx.x * 128;

  // staging: wave w stages khi=w>>1, row/col = (w&1)*64+lane  (1 glds16 each for A and B)
  const int skhi = wid >> 1, srow = (wid & 1)*64 + lane;
  long long gra = m0 + srow; if (gra >= M) gra = M - 1;
  const __hip_bfloat16* aptr = A + gra * (size_t)K + skhi*8;
  const __hip_bfloat16* bptr = Bt + (size_t)(n0 + srow) * K + skhi*8;
  char* adst = AsB + (skhi*128 + srow)*16;
  char* bdst = BsB + (skhi*128 + srow)*16;

  f32x4 acc[4][2];
  #pragma unroll
  for (int i = 0; i < 4; ++i)
    #pragma unroll
    for (int j = 0; j < 2; ++j)
      acc[i][j] = (f32x4){0.f,0.f,0.f,0.f};

  const int lr = lane & 15, lkh = lane >> 4;

  for (int kt = 0; kt < K; kt += 32) {
    __syncthreads();
    glds16(aptr + kt, adst);
    glds16(bptr + kt, bdst);
    __syncthreads();
    bf16x8 afr[4], bfr[2];
    #pragma unroll
    for (int fm = 0; fm < 4; ++fm)
      afr[fm] = *reinterpret_cast<const bf16x8*>(AsB + (lkh*128 + wm*64 + fm*16 + lr)*16);
    #pragma unroll
    for (int fn = 0; fn < 2; ++fn)
      bfr[fn] = *reinterpret_cast<const bf16x8*>(BsB + (lkh*128 + wn*32 + fn*16 + lr)*16);
    #pragma unroll
    for (int fm = 0; fm < 4; ++fm)
      #pragma unroll
      for (int fn = 0; fn < 2; ++fn)
        acc[fm][fn] = __builtin_amdgcn_mfma_f32_16x16x32_bf16(afr[fm], bfr[fn], acc[fm][fn], 0, 0, 0);
  }

  const int seg = n0 >> 9;
  const int c0 = (OUT == 2) ? (n0 & 511) : n0;
  unsigned short* qdst = nullptr;
  if (OUT == 2) qdst = (unsigned short*)(seg == 0 ? Cb0 : (seg == 1 ? Cb1 : Cb2));
  #pragma unroll
  for (int fm = 0; fm < 4; ++fm) {
    #pragma unroll
    for (int fn = 0; fn < 2; ++fn) {
      #pragma unroll
      for (int j = 0; j < 4; ++j) {
        long long r = m0 + wm*64 + fm*16 + lkh*4 + j;
        int c = c0 + wn*32 + fn*16 + lr;
        if (r < M && c < Nc) {
          float v = acc[fm][fn][j];
          if (SILU) v = v / (1.f + __expf(-v));
          if (OUT == 0) Cf[r*(size_t)Nc + c] = v;
          else if (OUT == 1) ((unsigned short*)Cb0)[r*(size_t)Nc + c] = f2b(v);
          else qdst[r*(size_t)Nc + c] = f2b(v);
        }
      }
    }
  }
}

// ---------------- deg ----------------
__global__ __launch_bounds__(256) void deg_kernel(const float* __restrict__ dedge,
    const float* __restrict__ sh, const float* __restrict__ Tg,
    const int* __restrict__ row_ptr, const int* __restrict__ eid,
    const float* __restrict__ Wdeg, float* __restrict__ x, __hip_bfloat16* __restrict__ xb) {
  const int wid = threadIdx.x >> 6, lane = threadIdx.x & 63;
  for (int n = blockIdx.x*4 + wid; n < NN; n += gridDim.x*4) {
    const int e0 = row_ptr[n], e1 = row_ptr[n+1];
    float s9[9] = {0,0,0,0,0,0,0,0,0};
    for (int p = e0 + lane; p < e1; p += 64) {
      int e = eid[p];
      float g = lookup1(Tg, dedge[e]);
      const float* srow = sh + (size_t)e*9;
      #pragma unroll
      for (int s = 0; s < 9; ++s) s9[s] += g*srow[s];
    }
    #pragma unroll
    for (int s = 0; s < 9; ++s) s9[s] = wsum(s9[s]);
    #pragma unroll
    for (int r = 0; r < 8; ++r) {
      int d = lane + (r<<6);
      if (d < DD) {
        float acc = 0.f;
        #pragma unroll
        for (int s = 0; s < 9; ++s) acc += s9[s]*Wdeg[s*DD + d];
        float vv = x[(size_t)n*DD + d] + acc * INV_SQRT_DEG;
        x[(size_t)n*DD + d] = vv;
        ((unsigned short*)xb)[(size_t)n*DD + d] = f2b(vv);
      }
    }
  }
}

// ---------------- P[n,h,s] ----------------
__global__ __launch_bounds__(256) void p_kernel(const __hip_bfloat16* __restrict__ xq,
    const float* __restrict__ Wsh_l, float* __restrict__ P) {
  const int wid = threadIdx.x >> 6, lane = threadIdx.x & 63;
  for (int n = blockIdx.x*4 + wid; n < NN; n += gridDim.x*4) {
    if (lane < 36) {
      int h = lane/9, s = lane%9;
      const unsigned short* q = (const unsigned short*)(xq + (size_t)n*DD + h*DHD);
      const float* w = Wsh_l + s*DD + h*DHD;
      float acc = 0.f;
      #pragma unroll
      for (int db = 0; db < 15; ++db) {
        u16x8 v = *reinterpret_cast<const u16x8*>(q + db*8);
        #pragma unroll
        for (int j = 0; j < 8; ++j) acc += b2f(v[j])*w[db*8+j];
      }
      P[(size_t)n*36 + lane] = acc;
    }
  }
}

// ---------------- per-edge logit coefficients ----------------
__global__ __launch_bounds__(256) void coef_kernel(
    const int* __restrict__ eid, const int* __restrict__ edst,
    const float* __restrict__ sh, const float* __restrict__ dedge,
    const float* __restrict__ Tl, const float* __restrict__ P,
    float2* __restrict__ sb) {
  const int p = blockIdx.x*256 + threadIdx.x;
  if (p >= EE) return;
  const int e = eid[p];
  const int n = edst[e];
  const float* srow = sh + (size_t)e*9;
  float s0 = srow[0], s1 = srow[1], s2 = srow[2], s3 = srow[3], s4 = srow[4];
  float s5 = srow[5], s6 = srow[6], s7 = srow[7], s8 = srow[8];
  const float* Pn = P + (size_t)n*36;
  float g[4];
  {
    float u = dedge[e] * LSCALE;
    if (u >= (float)(TSIZE-1)) { g[0]=g[1]=g[2]=g[3]=0.f; }
    else {
      int ti = (int)u; float fr = u - (float)ti;
      const float4 ga = *reinterpret_cast<const float4*>(Tl + ti*4);
      const float4 gb = *reinterpret_cast<const float4*>(Tl + ti*4 + 4);
      g[0] = ga.x + fr*(gb.x-ga.x); g[1] = ga.y + fr*(gb.y-ga.y);
      g[2] = ga.z + fr*(gb.z-ga.z); g[3] = ga.w + fr*(gb.w-ga.w);
    }
  }
  #pragma unroll
  for (int h = 0; h < 4; ++h) {
    const float* Ph = Pn + h*9;
    float lp = s0*Ph[0]+s1*Ph[1]+s2*Ph[2]+s3*Ph[3]+s4*Ph[4]
             + s5*Ph[5]+s6*Ph[6]+s7*Ph[7]+s8*Ph[8];
    float sc = INV_DH * g[h];
    sb[(size_t)p*4 + h] = make_float2(sc, lp*sc);
  }
}

// ---------------- fused attention: 1 node/wave ----------------
__global__ __launch_bounds__(256) void attn_kernel(
    const __hip_bfloat16* __restrict__ xq, const __hip_bfloat16* __restrict__ xk,
    const __hip_bfloat16* __restrict__ xv, const float2* __restrict__ sb,
    const int* __restrict__ row_ptr, const int* __restrict__ srcs,
    __hip_bfloat16* __restrict__ aggout) {
  const int wid = threadIdx.x >> 6, lane = threadIdx.x & 63;
  __shared__ float l_s[4][64][4];
  __shared__ int   src_sh[4][64];
  float (*ls)[4] = l_s[wid];
  int* srcS = src_sh[wid];
  const int hh = lane >> 4, li = lane & 15;
  const int hd = (lane < 60) ? (lane/15) : 3;
  const unsigned short* xkp = (const unsigned short*)xk;
  const unsigned short* xvp = (const unsigned short*)xv;
  const int doff = hh*DHD + li*8;
  for (int n = blockIdx.x*4 + wid; n < NN; n += gridDim.x*4) {
    const int e0 = row_ptr[n], e1 = row_ptr[n+1];
    float qf[8] = {0,0,0,0,0,0,0,0};
    if (li < 15) {
      u16x8 v = *reinterpret_cast<const u16x8*>((const unsigned short*)xq + (size_t)n*DD + doff);
      #pragma unroll
      for (int j = 0; j < 8; ++j) qf[j] = b2f(v[j]);
    }
    float m_reg = -1e30f, den_reg = 0.f;
    float agg[8] = {0,0,0,0,0,0,0,0};
    for (int c0 = e0; c0 < e1; c0 += 64) {
      const int cn = min(64, e1 - c0);
      if (lane < cn) srcS[lane] = srcs[c0 + lane];
      asm volatile("s_waitcnt lgkmcnt(0)" ::: "memory");
      int i = 0;
      for (; i + 4 <= cn; i += 4) {
        int sA = srcS[i], sB = srcS[i+1], sC = srcS[i+2], sD = srcS[i+3];
        float a0 = 0.f, a1 = 0.f, a2 = 0.f, a3 = 0.f;
        if (li < 15) {
          u16x8 k0 = *reinterpret_cast<const u16x8*>(xkp + (size_t)sA*DD + doff);
          u16x8 k1 = *reinterpret_cast<const u16x8*>(xkp + (size_t)sB*DD + doff);
          u16x8 k2 = *reinterpret_cast<const u16x8*>(xkp + (size_t)sC*DD + doff);
          u16x8 k3 = *reinterpret_cast<const u16x8*>(xkp + (size_t)sD*DD + doff);
          #pragma unroll
          for (int j = 0; j < 8; ++j) {
            a0 += qf[j]*b2f(k0[j]);
            a1 += qf[j]*b2f(k1[j]);
            a2 += qf[j]*b2f(k2[j]);
            a3 += qf[j]*b2f(k3[j]);
          }
        }
        #pragma unroll
        for (int off = 1; off < 16; off <<= 1) {
          a0 += __shfl_xor(a0, off, 64);
          a1 += __shfl_xor(a1, off, 64);
          a2 += __shfl_xor(a2, off, 64);
          a3 += __shfl_xor(a3, off, 64);
        }
        if (li == 0) {
          float2 cA = sb[(size_t)(c0+i+0)*4 + hh];
          float2 cB = sb[(size_t)(c0+i+1)*4 + hh];
          float2 cC = sb[(size_t)(c0+i+2)*4 + hh];
          float2 cD = sb[(size_t)(c0+i+3)*4 + hh];
          ls[i+0][hh] = a0*cA.x + cA.y;
          ls[i+1][hh] = a1*cB.x + cB.y;
          ls[i+2][hh] = a2*cC.x + cC.y;
          ls[i+3][hh] = a3*cD.x + cD.y;
        }
      }
      for (; i < cn; ++i) {
        int sA = srcS[i];
        float a0 = 0.f;
        if (li < 15) {
          u16x8 k0 = *reinterpret_cast<const u16x8*>(xkp + (size_t)sA*DD + doff);
          #pragma unroll
          for (int j = 0; j < 8; ++j) a0 += qf[j]*b2f(k0[j]);
        }
        #pragma unroll
        for (int off = 1; off < 16; off <<= 1) a0 += __shfl_xor(a0, off, 64);
        if (li == 0) {
          float2 cA = sb[(size_t)(c0+i)*4 + hh];
          ls[i][hh] = a0*cA.x + cA.y;
        }
      }
      asm volatile("s_waitcnt lgkmcnt(0)" ::: "memory");
      const int h = lane & 3, i0 = lane >> 2;
      float cm = -1e30f;
      for (int i2 = i0; i2 < cn; i2 += 16) cm = fmaxf(cm, ls[i2][h]);
      #pragma unroll
      for (int off = 4; off < 64; off <<= 1) cm = fmaxf(cm, __shfl_xor(cm, off, 64));
      const float newm = fmaxf(m_reg, cm);
      const float f = __expf(m_reg - newm);
      float cs = 0.f;
      for (int i2 = i0; i2 < cn; i2 += 16) {
        float a = __expf(ls[i2][h] - newm);
        ls[i2][h] = a;
        cs += a;
      }
      #pragma unroll
      for (int off = 4; off < 64; off <<= 1) cs += __shfl_xor(cs, off, 64);
      m_reg = newm;
      den_reg = den_reg*f + cs;
      asm volatile("s_waitcnt lgkmcnt(0)" ::: "memory");
      const float fh = __shfl(f, hd);
      #pragma unroll
      for (int j = 0; j < 8; ++j) agg[j] *= fh;
      i = 0;
      for (; i + 4 <= cn; i += 4) {
        int sA = srcS[i], sB = srcS[i+1], sC = srcS[i+2], sD = srcS[i+3];
        float a0 = ls[i][hd], a1 = ls[i+1][hd], a2 = ls[i+2][hd], a3 = ls[i+3][hd];
        if (lane < 60) {
          u16x8 v0 = *reinterpret_cast<const u16x8*>(xvp + (size_t)sA*DD + lane*8);
          u16x8 v1 = *reinterpret_cast<const u16x8*>(xvp + (size_t)sB*DD + lane*8);
          u16x8 v2 = *reinterpret_cast<const u16x8*>(xvp + (size_t)sC*DD + lane*8);
          u16x8 v3 = *reinterpret_cast<const u16x8*>(xvp + (size_t)sD*DD + lane*8);
          #pragma unroll
          for (int j = 0; j < 8; ++j)
            agg[j] += a0*b2f(v0[j]) + a1*b2f(v1[j]) + a2*b2f(v2[j]) + a3*b2f(v3[j]);
        }
      }
      for (; i < cn; ++i) {
        int sA = srcS[i];
        float a0 = ls[i][hd];
        if (lane < 60) {
          u16x8 v0 = *reinterpret_cast<const u16x8*>(xvp + (size_t)sA*DD + lane*8);
          #pragma unroll
          for (int j = 0; j < 8; ++j) agg[j] += a0*b2f(v0[j]);
        }
      }
    }
    const float dh2 = __shfl(den_reg, hd);
    if (lane < 60) {
      const float sc = INV_SQRT_DEG / (dh2 + 1e-12f);
      u16x8 o;
      #pragma unroll
      for (int j = 0; j < 8; ++j) o[j] = f2b(agg[j]*sc);
      *reinterpret_cast<u16x8*>((unsigned short*)aggout + (size_t)n*DD + lane*8) = o;
    }
  }
}

// ---------------- residual + LayerNorm ----------------
__global__ __launch_bounds__(256) void ln_kernel(float* __restrict__ x, const float* __restrict__ t,
    __hip_bfloat16* __restrict__ xb) {
  const int wid = threadIdx.x >> 6, lane = threadIdx.x & 63;
  for (int n = blockIdx.x*4 + wid; n < NN; n += gridDim.x*4) {
    float4 a0 = make_float4(0,0,0,0), a1 = make_float4(0,0,0,0);
    float s = 0.f, s2 = 0.f;
    if (lane < 60) {
      const float4* xp = (const float4*)(x + (size_t)n*DD + lane*8);
      const float4* tp = (const float4*)(t + (size_t)n*DD + lane*8);
      float4 b0 = tp[0], b1 = tp[1];
      a0 = xp[0]; a1 = xp[1];
      a0.x += b0.x; a0.y += b0.y; a0.z += b0.z; a0.w += b0.w;
      a1.x += b1.x; a1.y += b1.y; a1.z += b1.z; a1.w += b1.w;
      s  = a0.x+a0.y+a0.z+a0.w + a1.x+a1.y+a1.z+a1.w;
      s2 = a0.x*a0.x+a0.y*a0.y+a0.z*a0.z+a0.w*a0.w
         + a1.x*a1.x+a1.y*a1.y+a1.z*a1.z+a1.w*a1.w;
    }
    s = wsum(s); s2 = wsum(s2);
    const float mu = s * (1.f/(float)DD);
    const float var = s2 * (1.f/(float)DD) - mu*mu;
    const float rs = rsqrtf(var + 1e-5f);
    if (lane < 60) {
      float4* xp = (float4*)(x + (size_t)n*DD + lane*8);
      a0.x = (a0.x-mu)*rs; a0.y = (a0.y-mu)*rs; a0.z = (a0.z-mu)*rs; a0.w = (a0.w-mu)*rs;
      a1.x = (a1.x-mu)*rs; a1.y = (a1.y-mu)*rs; a1.z = (a1.z-mu)*rs; a1.w = (a1.w-mu)*rs;
      xp[0] = a0; xp[1] = a1;
      u16x8 o;
      o[0]=f2b(a0.x); o[1]=f2b(a0.y); o[2]=f2b(a0.z); o[3]=f2b(a0.w);
      o[4]=f2b(a1.x); o[5]=f2b(a1.y); o[6]=f2b(a1.z); o[7]=f2b(a1.w);
      *reinterpret_cast<u16x8*>((unsigned short*)xb + (size_t)n*DD + lane*8) = o;
    }
  }
}

// ---------------- final: LDS-staged per-group partials, few global atomics ----------------
__global__ __launch_bounds__(256) void h2_kernel(const float* __restrict__ t,
    const float* __restrict__ Wh2, const int* __restrict__ batch, float* __restrict__ out) {
  __shared__ float part[GG];
  for (int i = threadIdx.x; i < GG; i += 256) part[i] = 0.f;
  __syncthreads();
  const int wid = threadIdx.x >> 6, lane = threadIdx.x & 63;
  const int per_block = (NN + gridDim.x - 1) / gridDim.x;
  const int n0 = blockIdx.x * per_block;
  const int n1 = min(NN, n0 + per_block);
  for (int n = n0 + wid; n < n1; n += 4) {
    float s = 0.f;
    if (lane < 60) {
      const float4* tp = (const float4*)(t + (size_t)n*DD + lane*8);
      const float4* wp = (const float4*)(Wh2 + lane*8);
      float4 t0 = tp[0], t1 = tp[1], w0 = wp[0], w1 = wp[1];
      s = t0.x*w0.x+t0.y*w0.y+t0.z*w0.z+t0.w*w0.w
        + t1.x*w1.x+t1.y*w1.y+t1.z*w1.z+t1.w*w1.w;
    }
    s = wsum(s);
    if (lane == 0) atomicAdd(&part[batch[n]], s * INV_AVG_NODES);
  }
  __syncthreads();
  for (int i = threadIdx.x; i < GG; i += 256) {
    float v = part[i];
    if (v != 0.f) atomicAdd(&out[i], v);
  }
}

extern "C" void kernel_launch(void* const* d_in, const int* in_sizes, int n_in,
                              void* d_out, int out_size, void* d_ws, size_t ws_size,
                              hipStream_t stream) {
  const float* pos        = (const float*)d_in[0];
  const int*   node_atom  = (const int*)  d_in[1];
  const int*   edge_src   = (const int*)  d_in[2];
  const int*   edge_dst   = (const int*)  d_in[3];
  const int*   batch      = (const int*)  d_in[4];
  const float* atom_table = (const float*)d_in[5];
  const float* Wdeg       = (const float*)d_in[6];
  const float* Wd1        = (const float*)d_in[7];
  const float* Wd2        = (const float*)d_in[8];
  const float* Wd3        = (const float*)d_in[9];
  const float* Wq         = (const float*)d_in[10];
  const float* Wk         = (const float*)d_in[11];
  const float* Wv         = (const float*)d_in[12];
  const float* Wsh        = (const float*)d_in[13];
  const float* W1         = (const float*)d_in[14];
  const float* W2         = (const float*)d_in[15];
  const float* W3         = (const float*)d_in[16];
  const float* Wo         = (const float*)d_in[17];
  const float* Wf1        = (const float*)d_in[18];
  const float* Wf2        = (const float*)d_in[19];
  const float* Wh1        = (const float*)d_in[20];
  const float* Wh2        = (const float*)d_in[21];
  float* out = (float*)d_out;
  char*  wsb = (char*)d_ws;

  size_t off = 0;
  auto alloc = [&](size_t bytes) { size_t o = off; off += (bytes + 255) & ~(size_t)255; return o; };
  float*  x      = (float*) (wsb + alloc((size_t)NN*DD*4));
  __hip_bfloat16* xb   = (__hip_bfloat16*)(wsb + alloc((size_t)NN*DD*2));
  __hip_bfloat16* xq   = (__hip_bfloat16*)(wsb + alloc((size_t)NN*DD*2));
  __hip_bfloat16* xk   = (__hip_bfloat16*)(wsb + alloc((size_t)NN*DD*2));
  __hip_bfloat16* xv   = (__hip_bfloat16*)(wsb + alloc((size_t)NN*DD*2));
  float*  shb    = (float*) (wsb + alloc((size_t)EE*9*4));
  float*  dedge  = (float*) (wsb + alloc((size_t)EE*4));
  float*  P      = (float*) (wsb + alloc((size_t)NN*36*4));
  float2* sbuf   = (float2*)(wsb + alloc((size_t)EE*4*8));
  __hip_bfloat16* aggb = (__hip_bfloat16*)(wsb + alloc((size_t)NN*DD*2));
  float*  tmp480 = (float*) (wsb + alloc((size_t)NN*DD*4));
  __hip_bfloat16* tmp960 = (__hip_bfloat16*)(wsb + alloc((size_t)NN*960*2));
  float*  Tg     = (float*) (wsb + alloc((size_t)TSIZE*4));
  float*  Tl     = (float*) (wsb + alloc((size_t)LLAYERS*TSIZE*4*4));
  __hip_bfloat16* Wqkvt = (__hip_bfloat16*)(wsb + alloc((size_t)LLAYERS*1536*480*2));
  __hip_bfloat16* Wot   = (__hip_bfloat16*)(wsb + alloc((size_t)LLAYERS*512*480*2));
  __hip_bfloat16* Wf1t  = (__hip_bfloat16*)(wsb + alloc((size_t)LLAYERS*1024*480*2));
  __hip_bfloat16* Wf2t  = (__hip_bfloat16*)(wsb + alloc((size_t)LLAYERS*512*960*2));
  __hip_bfloat16* Wh1t  = (__hip_bfloat16*)(wsb + alloc((size_t)512*480*2));
  int* cnt     = (int*)(wsb + alloc((size_t)NN*4));
  int* row_ptr = (int*)(wsb + alloc((size_t)(NN+1)*4));
  int* cursor  = (int*)(wsb + alloc((size_t)NN*4));
  int* eid     = (int*)(wsb + alloc((size_t)EE*4));
  int* srcs    = (int*)(wsb + alloc((size_t)EE*4));
  (void)ws_size;

  auto tr = [&](const float* W, __hip_bfloat16* Wt, int K, int N, int Npad,
                long long lsW, long long lsT, int L) {
    dim3 g((Npad+31)/32, (K+31)/32, L);
    transpose_w_kernel<<<g, 256, 0, stream>>>(W, Wt, K, N, Npad, lsW, lsT);
  };

  tr(Wq,  Wqkvt + 0*512*480,    480, 480, 512, 480*480, 1536*480, LLAYERS);
  tr(Wk,  Wqkvt + 1*512*480,    480, 480, 512, 480*480, 1536*480, LLAYERS);
  tr(Wv,  Wqkvt + 2*512*480,    480, 480, 512, 480*480, 1536*480, LLAYERS);
  tr(Wo,  Wot,  480, 480, 512, 480*480, 512*480, LLAYERS);
  tr(Wf1, Wf1t, 480, 960, 1024, 480*960, 1024*480, LLAYERS);
  tr(Wf2, Wf2t, 960, 480, 512, 960*480, 512*960, LLAYERS);
  tr(Wh1, Wh1t, 480, 480, 512, 480*480, 512*480, 1);

  zero_kernel<<<(NN+255)/256, 256, 0, stream>>>(cnt, out);
  gather_x_kernel<<<640, 256, 0, stream>>>(atom_table, node_atom, x);
  edge_geom_kernel<<<(EE+255)/256, 256, 0, stream>>>(pos, edge_src, edge_dst, shb, dedge);
  hist_kernel<<<(EE+255)/256, 256, 0, stream>>>(edge_dst, cnt);
  scan_kernel<<<1, 1024, 0, stream>>>(cnt, row_ptr, cursor);
  scatter_kernel<<<(EE+255)/256, 256, 0, stream>>>(edge_src, edge_dst, cursor, eid, srcs);
  table_kernel<<<dim3(TSIZE/16, 1+LLAYERS), 1024, 0, stream>>>(Wd1, Wd2, Wd3, W1, W2, W3, Tg, Tl);
  deg_kernel<<<2500, 256, 0, stream>>>(dedge, shb, Tg, row_ptr, eid, Wdeg, x, xb);

  for (int l = 0; l < LLAYERS; ++l) {
    const __hip_bfloat16* Wqkvt_l = Wqkvt + (size_t)l*1536*480;
    const __hip_bfloat16* Wot_l   = Wot   + (size_t)l*512*480;
    const __hip_bfloat16* Wf1t_l  = Wf1t  + (size_t)l*1024*480;
    const __hip_bfloat16* Wf2t_l  = Wf2t  + (size_t)l*512*960;
    const float* Wsh_l = Wsh + (size_t)l*9*DD;
    const float* Tl_l  = Tl  + (size_t)l*TSIZE*4;

    gemm_bf16_kernel<0,2><<<dim3(12, 79), 512, 0, stream>>>(xb, Wqkvt_l, nullptr, xq, xk, xv, NN, 480, 480);
    p_kernel<<<2500, 256, 0, stream>>>(xq, Wsh_l, P);
    coef_kernel<<<(EE+255)/256, 256, 0, stream>>>(eid, edge_dst, shb, dedge, Tl_l, P, sbuf);
    attn_kernel<<<2500, 256, 0, stream>>>(xq, xk, xv, sbuf, row_ptr, srcs, aggb);
    gemm_bf16_kernel<0,0><<<dim3(4, 79), 512, 0, stream>>>(aggb, Wot_l, tmp480, nullptr, nullptr, nullptr, NN, 480, 480);
    ln_kernel<<<640, 256, 0, stream>>>(x, tmp480, xb);
    gemm_bf16_kernel<1,1><<<dim3(8, 79), 512, 0, stream>>>(xb, Wf1t_l, nullptr, tmp960, nullptr, nullptr, NN, 480, 960);
    gemm_bf16_kernel<0,0><<<dim3(4, 79), 512, 0, stream>>>(tmp960, Wf2t_l, tmp480, nullptr, nullptr, nullptr, NN, 960, 480);
    ln_kernel<<<640, 256, 0, stream>>>(x, tmp480, xb);
  }

  gemm_bf16_kernel<1,0><<<dim3(4, 79), 512, 0, stream>>>(xb, Wh1t, tmp480, nullptr, nullptr, nullptr, NN, 480, 480);
  h2_kernel<<<160, 256, 0, stream>>>(tmp480, Wh2, batch, out);
}

// Round 9
// 1725.791 us; speedup vs baseline: 3.2648x; 1.0050x over previous
//
#include <hip/hip_runtime.h>
#include <hip/hip_bf16.h>

#define NN 10000
#define EE 160000
#define GG 64
#define DD 480
#define HH 4
#define LLAYERS 6
#define DHD 120
#define NB_ 128
#define TSIZE 4096
#define DMAXT 5.5f
#define LSCALE (4095.0f/5.5f)

#define INV_DH 0.09128709291752768f
#define INV_SQRT_DEG 0.25335277f
#define INV_AVG_NODES (1.0f/18.03065905448718f)

typedef __attribute__((ext_vector_type(8))) short bf16x8;
typedef __attribute__((ext_vector_type(4))) float f32x4;
typedef __attribute__((ext_vector_type(8))) unsigned short u16x8;

__device__ __forceinline__ float b2f(unsigned short u){ return __uint_as_float(((unsigned)u)<<16); }
__device__ __forceinline__ unsigned short f2b(float f){
  unsigned u = __float_as_uint(f);
  return (unsigned short)((u + 0x7fffu + ((u>>16)&1u)) >> 16);
}
__device__ __forceinline__ float wsum(float v){
  #pragma unroll
  for (int off=32; off>0; off>>=1) v += __shfl_xor(v, off, 64);
  return v;
}
__device__ __forceinline__ void glds16(const void* g, void* l) {
  __builtin_amdgcn_global_load_lds((const __attribute__((address_space(1))) unsigned int*)g,
                                   (__attribute__((address_space(3))) unsigned int*)l, 16, 0, 0);
}

// ---------------- zero ----------------
__global__ __launch_bounds__(256) void zero_kernel(int* __restrict__ cnt, float* __restrict__ out){
  int i = blockIdx.x*256 + threadIdx.x;
  if (i < NN) cnt[i] = 0;
  if (i < GG) out[i] = 0.f;
}

// ---------------- x = atom_table[node_atom] ----------------
__global__ __launch_bounds__(256) void gather_x_kernel(const float* __restrict__ at,
    const int* __restrict__ atom, float* __restrict__ x){
  const int wid = threadIdx.x >> 6, lane = threadIdx.x & 63;
  for (int n = blockIdx.x*4 + wid; n < NN; n += gridDim.x*4) {
    int a = atom[n];
    if (lane < 60) {
      const float4* src = (const float4*)(at + (size_t)a*DD + lane*8);
      float4* dst = (float4*)(x + (size_t)n*DD + lane*8);
      dst[0] = src[0]; dst[1] = src[1];
    }
  }
}

// ---------------- edge geometry ----------------
__global__ __launch_bounds__(256) void edge_geom_kernel(const float* __restrict__ pos,
    const int* __restrict__ esrc, const int* __restrict__ edst,
    float* __restrict__ sh, float* __restrict__ dedge){
  const int e = blockIdx.x*256 + threadIdx.x;
  if (e >= EE) return;
  int s = esrc[e], d = edst[e];
  float vx = pos[s*3+0]-pos[d*3+0];
  float vy = pos[s*3+1]-pos[d*3+1];
  float vz = pos[s*3+2]-pos[d*3+2];
  float rr = sqrtf(vx*vx+vy*vy+vz*vz);
  dedge[e] = rr;
  float r = rr + 1e-12f;
  float x = vx/r, y = vy/r, z = vz/r;
  const float s3 = 1.7320508075688772f;
  const float s5 = 2.23606797749979f;
  const float s15 = 3.872983346207417f;
  float* o = sh + (size_t)e*9;
  o[0] = 1.f;
  o[1] = s3*x; o[2] = s3*y; o[3] = s3*z;
  o[4] = s15*x*y; o[5] = s15*y*z;
  o[6] = 0.5f*s5*(3.f*z*z-1.f);
  o[7] = s15*x*z;
  o[8] = 0.5f*s15*(x*x-y*y);
}

// ---------------- sort by dst ----------------
__global__ __launch_bounds__(256) void hist_kernel(const int* __restrict__ edst, int* __restrict__ cnt){
  int e = blockIdx.x*256 + threadIdx.x;
  if (e < EE) atomicAdd(&cnt[edst[e]], 1);
}

__global__ __launch_bounds__(1024) void scan_kernel(const int* __restrict__ cnt,
    int* __restrict__ row_ptr, int* __restrict__ cursor){
  __shared__ int sd[1024];
  __shared__ int s_carry;
  if (threadIdx.x == 0) s_carry = 0;
  __syncthreads();
  for (int base = 0; base < NN; base += 1024) {
    int i = base + threadIdx.x;
    int v = (i < NN) ? cnt[i] : 0;
    sd[threadIdx.x] = v;
    __syncthreads();
    for (int off = 1; off < 1024; off <<= 1) {
      int t = 0;
      if ((int)threadIdx.x >= off) t = sd[threadIdx.x - off];
      __syncthreads();
      sd[threadIdx.x] += t;
      __syncthreads();
    }
    int incl = sd[threadIdx.x];
    int carry = s_carry;
    if (i < NN) { row_ptr[i] = carry + incl - v; cursor[i] = carry + incl - v; }
    __syncthreads();
    if (threadIdx.x == 1023) s_carry = carry + incl;
    __syncthreads();
  }
  if (threadIdx.x == 0) row_ptr[NN] = s_carry;
}

__global__ __launch_bounds__(256) void scatter_kernel(const int* __restrict__ esrc,
    const int* __restrict__ edst, int* __restrict__ cursor,
    int* __restrict__ eid, int* __restrict__ srcs){
  int e = blockIdx.x*256 + threadIdx.x;
  if (e < EE) {
    int n = edst[e];
    int p = atomicAdd(&cursor[n], 1);
    eid[p] = e;
    srcs[p] = esrc[e];
  }
}

// ---------------- gate/g0 lookup tables: wave per point, lane = channel, truncated RBF ----------------
__global__ __launch_bounds__(1024) void table_kernel(
    const float* __restrict__ Wd1, const float* __restrict__ Wd2, const float* __restrict__ Wd3,
    const float* __restrict__ W1, const float* __restrict__ W2, const float* __restrict__ W3,
    float* __restrict__ Tg, float* __restrict__ Tl) {
  const int chain = blockIdx.y;
  const float *A1, *A2, *A3; int NC;
  if (chain == 0) { A1 = Wd1; A2 = Wd2; A3 = Wd3; NC = 1; }
  else { int l = chain-1; A1 = W1 + (size_t)l*128*64; A2 = W2 + (size_t)l*64*64; A3 = W3 + (size_t)l*64*4; NC = 4; }
  __shared__ float W1s[128*64];
  __shared__ float W2s[64*64];
  __shared__ float W3s[64*4];
  for (int i = threadIdx.x; i < 128*64; i += 1024) W1s[i] = A1[i];
  for (int i = threadIdx.x; i < 64*64; i += 1024) W2s[i] = A2[i];
  for (int i = threadIdx.x; i < 64*4; i += 1024) W3s[i] = (i < 64*NC) ? A3[i] : 0.f;
  __syncthreads();
  const int wid = threadIdx.x >> 6, lane = threadIdx.x & 63;
  const int t = blockIdx.x*16 + wid;
  const float d = (float)t * (DMAXT/(float)(TSIZE-1));
  // layer 1: truncated RBF sum — only centers within |z|<=~8 contribute (exp(-64)≈1e-28)
  const float cstep = 5.0f/127.0f;
  int jc = (int)(d / cstep + 0.5f);
  int j0 = jc - 8; if (j0 < 0) j0 = 0;
  int j1 = jc + 8; if (j1 > 127) j1 = 127;
  float t1 = 0.f;
  for (int j = j0; j <= j1; ++j) {
    float z = (d - (float)j*cstep) * (128.0f/5.0f);
    float f = __expf(-z*z);
    t1 += f * W1s[j*64 + lane];
  }
  t1 = t1 / (1.f + __expf(-t1));
  // layer 2: cross-channel via shfl broadcast
  float t2 = 0.f;
  #pragma unroll 4
  for (int c = 0; c < 64; ++c) {
    float bc = __shfl(t1, c);
    t2 += bc * W2s[c*64 + lane];
  }
  t2 = t2 / (1.f + __expf(-t2));
  // layer 3: reduce
  if (chain == 0) {
    float o = wsum(t2 * W3s[lane]);
    if (lane == 0) Tg[t] = o;
  } else {
    #pragma unroll
    for (int nc = 0; nc < 4; ++nc) {
      float o = wsum(t2 * W3s[lane*4 + nc]);
      if (lane == 0) Tl[((size_t)(chain-1)*TSIZE + t)*4 + nc] = o;
    }
  }
}

__device__ __forceinline__ float lookup1(const float* __restrict__ Tg, float d) {
  float u = d * LSCALE;
  if (u >= (float)(TSIZE-1)) return 0.f;
  int i = (int)u; float fr = u - (float)i;
  float a = Tg[i], b = Tg[i+1];
  return a + fr*(b-a);
}

// ---------------- weight transpose+convert ----------------
__global__ __launch_bounds__(256) void transpose_w_kernel(const float* __restrict__ W,
    __hip_bfloat16* __restrict__ Wt, int K, int N, int Npad,
    long long lstrideW, long long lstrideT) {
  __shared__ float T[32][33];
  const int l = blockIdx.z;
  W  += (size_t)l*lstrideW;
  Wt += (size_t)l*lstrideT;
  const int k0 = blockIdx.y*32, n0 = blockIdx.x*32;
  const int tx = threadIdx.x & 31, ty = threadIdx.x >> 5;
  #pragma unroll
  for (int r = 0; r < 32; r += 8) {
    int k = k0 + ty + r, n = n0 + tx;
    T[ty+r][tx] = (k < K && n < N) ? W[(size_t)k*N + n] : 0.f;
  }
  __syncthreads();
  #pragma unroll
  for (int r = 0; r < 32; r += 8) {
    int n = n0 + ty + r, k = k0 + tx;
    if (n < Npad && k < K)
      ((unsigned short*)Wt)[(size_t)n*K + k] = f2b(T[tx][ty+r]);
  }
}

// ---------------- bf16 MFMA GEMM: tile 128x128x32, 8 waves, double-buffered single-barrier K-loop ----------------
// Bt [Npad][K] transposed; OUT: 0=f32, 1=bf16, 2=QKV 3-way bf16 (512-col segments)
template<int SILU, int OUT>
__global__ __launch_bounds__(512) void gemm_bf16_kernel(
    const __hip_bfloat16* __restrict__ A, const __hip_bfloat16* __restrict__ Bt,
    float* __restrict__ Cf, __hip_bfloat16* __restrict__ Cb0,
    __hip_bfloat16* __restrict__ Cb1, __hip_bfloat16* __restrict__ Cb2,
    int M, int K, int Nc) {
  __shared__ char smem[32768];   // 2 buffers × (As 8KB + Bs 8KB)
  const int tid = threadIdx.x;
  const int lane = tid & 63, wid = tid >> 6;      // 8 waves
  const int wm = wid >> 2, wn = wid & 3;          // wave tile: rows wm*64, cols wn*32
  const long long m0 = (long long)blockIdx.y * 128;
  const int n0 = blockIdx.x * 128;

  // staging: wave w stages khi=w>>1, row/col = (w&1)*64+lane (1 glds16 each for A and B per step)
  const int skhi = wid >> 1, srow = (wid & 1)*64 + lane;
  long long gra = m0 + srow; if (gra >= M) gra = M - 1;
  const __hip_bfloat16* aptr = A + gra * (size_t)K + skhi*8;
  const __hip_bfloat16* bptr = Bt + (size_t)(n0 + srow) * K + skhi*8;
  const int stoff = (skhi*128 + srow)*16;

  f32x4 acc[4][2];
  #pragma unroll
  for (int i = 0; i < 4; ++i)
    #pragma unroll
    for (int j = 0; j < 2; ++j)
      acc[i][j] = (f32x4){0.f,0.f,0.f,0.f};

  const int lr = lane & 15, lkh = lane >> 4;

  // prologue: stage tile 0 into buffer 0
  glds16(aptr, smem + stoff);
  glds16(bptr, smem + 8192 + stoff);
  __syncthreads();   // drains vmcnt+lgkmcnt, barrier

  int cur = 0;
  for (int kt = 0; kt < K; kt += 32) {
    const int nxt = cur ^ 1;
    if (kt + 32 < K) {
      glds16(aptr + kt + 32, smem + nxt*16384 + stoff);
      glds16(bptr + kt + 32, smem + nxt*16384 + 8192 + stoff);
    }
    const char* AsB = smem + cur*16384;
    const char* BsB = AsB + 8192;
    bf16x8 afr[4], bfr[2];
    #pragma unroll
    for (int fm = 0; fm < 4; ++fm)
      afr[fm] = *reinterpret_cast<const bf16x8*>(AsB + (lkh*128 + wm*64 + fm*16 + lr)*16);
    #pragma unroll
    for (int fn = 0; fn < 2; ++fn)
      bfr[fn] = *reinterpret_cast<const bf16x8*>(BsB + (lkh*128 + wn*32 + fn*16 + lr)*16);
    #pragma unroll
    for (int fm = 0; fm < 4; ++fm)
      #pragma unroll
      for (int fn = 0; fn < 2; ++fn)
        acc[fm][fn] = __builtin_amdgcn_mfma_f32_16x16x32_bf16(afr[fm], bfr[fn], acc[fm][fn], 0, 0, 0);
    // next tile's loads (mine) complete; barrier ⇒ everyone's complete
    asm volatile("s_waitcnt vmcnt(0)" ::: "memory");
    asm volatile("s_barrier" ::: "memory");
    cur = nxt;
  }

  const int seg = n0 >> 9;
  const int c0 = (OUT == 2) ? (n0 & 511) : n0;
  unsigned short* qdst = nullptr;
  if (OUT == 2) qdst = (unsigned short*)(seg == 0 ? Cb0 : (seg == 1 ? Cb1 : Cb2));
  #pragma unroll
  for (int fm = 0; fm < 4; ++fm) {
    #pragma unroll
    for (int fn = 0; fn < 2; ++fn) {
      #pragma unroll
      for (int j = 0; j < 4; ++j) {
        long long r = m0 + wm*64 + fm*16 + lkh*4 + j;
        int c = c0 + wn*32 + fn*16 + lr;
        if (r < M && c < Nc) {
          float v = acc[fm][fn][j];
          if (SILU) v = v / (1.f + __expf(-v));
          if (OUT == 0) Cf[r*(size_t)Nc + c] = v;
          else if (OUT == 1) ((unsigned short*)Cb0)[r*(size_t)Nc + c] = f2b(v);
          else qdst[r*(size_t)Nc + c] = f2b(v);
        }
      }
    }
  }
}

// ---------------- deg ----------------
__global__ __launch_bounds__(256) void deg_kernel(const float* __restrict__ dedge,
    const float* __restrict__ sh, const float* __restrict__ Tg,
    const int* __restrict__ row_ptr, const int* __restrict__ eid,
    const float* __restrict__ Wdeg, float* __restrict__ x, __hip_bfloat16* __restrict__ xb) {
  const int wid = threadIdx.x >> 6, lane = threadIdx.x & 63;
  for (int n = blockIdx.x*4 + wid; n < NN; n += gridDim.x*4) {
    const int e0 = row_ptr[n], e1 = row_ptr[n+1];
    float s9[9] = {0,0,0,0,0,0,0,0,0};
    for (int p = e0 + lane; p < e1; p += 64) {
      int e = eid[p];
      float g = lookup1(Tg, dedge[e]);
      const float* srow = sh + (size_t)e*9;
      #pragma unroll
      for (int s = 0; s < 9; ++s) s9[s] += g*srow[s];
    }
    #pragma unroll
    for (int s = 0; s < 9; ++s) s9[s] = wsum(s9[s]);
    #pragma unroll
    for (int r = 0; r < 8; ++r) {
      int d = lane + (r<<6);
      if (d < DD) {
        float acc = 0.f;
        #pragma unroll
        for (int s = 0; s < 9; ++s) acc += s9[s]*Wdeg[s*DD + d];
        float vv = x[(size_t)n*DD + d] + acc * INV_SQRT_DEG;
        x[(size_t)n*DD + d] = vv;
        ((unsigned short*)xb)[(size_t)n*DD + d] = f2b(vv);
      }
    }
  }
}

// ---------------- P[n,h,s] ----------------
__global__ __launch_bounds__(256) void p_kernel(const __hip_bfloat16* __restrict__ xq,
    const float* __restrict__ Wsh_l, float* __restrict__ P) {
  const int wid = threadIdx.x >> 6, lane = threadIdx.x & 63;
  for (int n = blockIdx.x*4 + wid; n < NN; n += gridDim.x*4) {
    if (lane < 36) {
      int h = lane/9, s = lane%9;
      const unsigned short* q = (const unsigned short*)(xq + (size_t)n*DD + h*DHD);
      const float* w = Wsh_l + s*DD + h*DHD;
      float acc = 0.f;
      #pragma unroll
      for (int db = 0; db < 15; ++db) {
        u16x8 v = *reinterpret_cast<const u16x8*>(q + db*8);
        #pragma unroll
        for (int j = 0; j < 8; ++j) acc += b2f(v[j])*w[db*8+j];
      }
      P[(size_t)n*36 + lane] = acc;
    }
  }
}

// ---------------- per-edge logit coefficients ----------------
__global__ __launch_bounds__(256) void coef_kernel(
    const int* __restrict__ eid, const int* __restrict__ edst,
    const float* __restrict__ sh, const float* __restrict__ dedge,
    const float* __restrict__ Tl, const float* __restrict__ P,
    float2* __restrict__ sb) {
  const int p = blockIdx.x*256 + threadIdx.x;
  if (p >= EE) return;
  const int e = eid[p];
  const int n = edst[e];
  const float* srow = sh + (size_t)e*9;
  float s0 = srow[0], s1 = srow[1], s2 = srow[2], s3 = srow[3], s4 = srow[4];
  float s5 = srow[5], s6 = srow[6], s7 = srow[7], s8 = srow[8];
  const float* Pn = P + (size_t)n*36;
  float g[4];
  {
    float u = dedge[e] * LSCALE;
    if (u >= (float)(TSIZE-1)) { g[0]=g[1]=g[2]=g[3]=0.f; }
    else {
      int ti = (int)u; float fr = u - (float)ti;
      const float4 ga = *reinterpret_cast<const float4*>(Tl + ti*4);
      const float4 gb = *reinterpret_cast<const float4*>(Tl + ti*4 + 4);
      g[0] = ga.x + fr*(gb.x-ga.x); g[1] = ga.y + fr*(gb.y-ga.y);
      g[2] = ga.z + fr*(gb.z-ga.z); g[3] = ga.w + fr*(gb.w-ga.w);
    }
  }
  #pragma unroll
  for (int h = 0; h < 4; ++h) {
    const float* Ph = Pn + h*9;
    float lp = s0*Ph[0]+s1*Ph[1]+s2*Ph[2]+s3*Ph[3]+s4*Ph[4]
             + s5*Ph[5]+s6*Ph[6]+s7*Ph[7]+s8*Ph[8];
    float sc = INV_DH * g[h];
    sb[(size_t)p*4 + h] = make_float2(sc, lp*sc);
  }
}

// ---------------- fused attention: 1 node/wave ----------------
__global__ __launch_bounds__(256) void attn_kernel(
    const __hip_bfloat16* __restrict__ xq, const __hip_bfloat16* __restrict__ xk,
    const __hip_bfloat16* __restrict__ xv, const float2* __restrict__ sb,
    const int* __restrict__ row_ptr, const int* __restrict__ srcs,
    __hip_bfloat16* __restrict__ aggout) {
  const int wid = threadIdx.x >> 6, lane = threadIdx.x & 63;
  __shared__ float l_s[4][64][4];
  __shared__ int   src_sh[4][64];
  float (*ls)[4] = l_s[wid];
  int* srcS = src_sh[wid];
  const int hh = lane >> 4, li = lane & 15;
  const int hd = (lane < 60) ? (lane/15) : 3;
  const unsigned short* xkp = (const unsigned short*)xk;
  const unsigned short* xvp = (const unsigned short*)xv;
  const int doff = hh*DHD + li*8;
  for (int n = blockIdx.x*4 + wid; n < NN; n += gridDim.x*4) {
    const int e0 = row_ptr[n], e1 = row_ptr[n+1];
    float qf[8] = {0,0,0,0,0,0,0,0};
    if (li < 15) {
      u16x8 v = *reinterpret_cast<const u16x8*>((const unsigned short*)xq + (size_t)n*DD + doff);
      #pragma unroll
      for (int j = 0; j < 8; ++j) qf[j] = b2f(v[j]);
    }
    float m_reg = -1e30f, den_reg = 0.f;
    float agg[8] = {0,0,0,0,0,0,0,0};
    for (int c0 = e0; c0 < e1; c0 += 64) {
      const int cn = min(64, e1 - c0);
      if (lane < cn) srcS[lane] = srcs[c0 + lane];
      asm volatile("s_waitcnt lgkmcnt(0)" ::: "memory");
      int i = 0;
      for (; i + 4 <= cn; i += 4) {
        int sA = srcS[i], sB = srcS[i+1], sC = srcS[i+2], sD = srcS[i+3];
        float a0 = 0.f, a1 = 0.f, a2 = 0.f, a3 = 0.f;
        if (li < 15) {
          u16x8 k0 = *reinterpret_cast<const u16x8*>(xkp + (size_t)sA*DD + doff);
          u16x8 k1 = *reinterpret_cast<const u16x8*>(xkp + (size_t)sB*DD + doff);
          u16x8 k2 = *reinterpret_cast<const u16x8*>(xkp + (size_t)sC*DD + doff);
          u16x8 k3 = *reinterpret_cast<const u16x8*>(xkp + (size_t)sD*DD + doff);
          #pragma unroll
          for (int j = 0; j < 8; ++j) {
            a0 += qf[j]*b2f(k0[j]);
            a1 += qf[j]*b2f(k1[j]);
            a2 += qf[j]*b2f(k2[j]);
            a3 += qf[j]*b2f(k3[j]);
          }
        }
        #pragma unroll
        for (int off = 1; off < 16; off <<= 1) {
          a0 += __shfl_xor(a0, off, 64);
          a1 += __shfl_xor(a1, off, 64);
          a2 += __shfl_xor(a2, off, 64);
          a3 += __shfl_xor(a3, off, 64);
        }
        if (li == 0) {
          float2 cA = sb[(size_t)(c0+i+0)*4 + hh];
          float2 cB = sb[(size_t)(c0+i+1)*4 + hh];
          float2 cC = sb[(size_t)(c0+i+2)*4 + hh];
          float2 cD = sb[(size_t)(c0+i+3)*4 + hh];
          ls[i+0][hh] = a0*cA.x + cA.y;
          ls[i+1][hh] = a1*cB.x + cB.y;
          ls[i+2][hh] = a2*cC.x + cC.y;
          ls[i+3][hh] = a3*cD.x + cD.y;
        }
      }
      for (; i < cn; ++i) {
        int sA = srcS[i];
        float a0 = 0.f;
        if (li < 15) {
          u16x8 k0 = *reinterpret_cast<const u16x8*>(xkp + (size_t)sA*DD + doff);
          #pragma unroll
          for (int j = 0; j < 8; ++j) a0 += qf[j]*b2f(k0[j]);
        }
        #pragma unroll
        for (int off = 1; off < 16; off <<= 1) a0 += __shfl_xor(a0, off, 64);
        if (li == 0) {
          float2 cA = sb[(size_t)(c0+i)*4 + hh];
          ls[i][hh] = a0*cA.x + cA.y;
        }
      }
      asm volatile("s_waitcnt lgkmcnt(0)" ::: "memory");
      const int h = lane & 3, i0 = lane >> 2;
      float cm = -1e30f;
      for (int i2 = i0; i2 < cn; i2 += 16) cm = fmaxf(cm, ls[i2][h]);
      #pragma unroll
      for (int off = 4; off < 64; off <<= 1) cm = fmaxf(cm, __shfl_xor(cm, off, 64));
      const float newm = fmaxf(m_reg, cm);
      const float f = __expf(m_reg - newm);
      float cs = 0.f;
      for (int i2 = i0; i2 < cn; i2 += 16) {
        float a = __expf(ls[i2][h] - newm);
        ls[i2][h] = a;
        cs += a;
      }
      #pragma unroll
      for (int off = 4; off < 64; off <<= 1) cs += __shfl_xor(cs, off, 64);
      m_reg = newm;
      den_reg = den_reg*f + cs;
      asm volatile("s_waitcnt lgkmcnt(0)" ::: "memory");
      const float fh = __shfl(f, hd);
      #pragma unroll
      for (int j = 0; j < 8; ++j) agg[j] *= fh;
      i = 0;
      for (; i + 4 <= cn; i += 4) {
        int sA = srcS[i], sB = srcS[i+1], sC = srcS[i+2], sD = srcS[i+3];
        float a0 = ls[i][hd], a1 = ls[i+1][hd], a2 = ls[i+2][hd], a3 = ls[i+3][hd];
        if (lane < 60) {
          u16x8 v0 = *reinterpret_cast<const u16x8*>(xvp + (size_t)sA*DD + lane*8);
          u16x8 v1 = *reinterpret_cast<const u16x8*>(xvp + (size_t)sB*DD + lane*8);
          u16x8 v2 = *reinterpret_cast<const u16x8*>(xvp + (size_t)sC*DD + lane*8);
          u16x8 v3 = *reinterpret_cast<const u16x8*>(xvp + (size_t)sD*DD + lane*8);
          #pragma unroll
          for (int j = 0; j < 8; ++j)
            agg[j] += a0*b2f(v0[j]) + a1*b2f(v1[j]) + a2*b2f(v2[j]) + a3*b2f(v3[j]);
        }
      }
      for (; i < cn; ++i) {
        int sA = srcS[i];
        float a0 = ls[i][hd];
        if (lane < 60) {
          u16x8 v0 = *reinterpret_cast<const u16x8*>(xvp + (size_t)sA*DD + lane*8);
          #pragma unroll
          for (int j = 0; j < 8; ++j) agg[j] += a0*b2f(v0[j]);
        }
      }
    }
    const float dh2 = __shfl(den_reg, hd);
    if (lane < 60) {
      const float sc = INV_SQRT_DEG / (dh2 + 1e-12f);
      u16x8 o;
      #pragma unroll
      for (int j = 0; j < 8; ++j) o[j] = f2b(agg[j]*sc);
      *reinterpret_cast<u16x8*>((unsigned short*)aggout + (size_t)n*DD + lane*8) = o;
    }
  }
}

// ---------------- residual + LayerNorm ----------------
__global__ __launch_bounds__(256) void ln_kernel(float* __restrict__ x, const float* __restrict__ t,
    __hip_bfloat16* __restrict__ xb) {
  const int wid = threadIdx.x >> 6, lane = threadIdx.x & 63;
  for (int n = blockIdx.x*4 + wid; n < NN; n += gridDim.x*4) {
    float4 a0 = make_float4(0,0,0,0), a1 = make_float4(0,0,0,0);
    float s = 0.f, s2 = 0.f;
    if (lane < 60) {
      const float4* xp = (const float4*)(x + (size_t)n*DD + lane*8);
      const float4* tp = (const float4*)(t + (size_t)n*DD + lane*8);
      float4 b0 = tp[0], b1 = tp[1];
      a0 = xp[0]; a1 = xp[1];
      a0.x += b0.x; a0.y += b0.y; a0.z += b0.z; a0.w += b0.w;
      a1.x += b1.x; a1.y += b1.y; a1.z += b1.z; a1.w += b1.w;
      s  = a0.x+a0.y+a0.z+a0.w + a1.x+a1.y+a1.z+a1.w;
      s2 = a0.x*a0.x+a0.y*a0.y+a0.z*a0.z+a0.w*a0.w
         + a1.x*a1.x+a1.y*a1.y+a1.z*a1.z+a1.w*a1.w;
    }
    s = wsum(s); s2 = wsum(s2);
    const float mu = s * (1.f/(float)DD);
    const float var = s2 * (1.f/(float)DD) - mu*mu;
    const float rs = rsqrtf(var + 1e-5f);
    if (lane < 60) {
      float4* xp = (float4*)(x + (size_t)n*DD + lane*8);
      a0.x = (a0.x-mu)*rs; a0.y = (a0.y-mu)*rs; a0.z = (a0.z-mu)*rs; a0.w = (a0.w-mu)*rs;
      a1.x = (a1.x-mu)*rs; a1.y = (a1.y-mu)*rs; a1.z = (a1.z-mu)*rs; a1.w = (a1.w-mu)*rs;
      xp[0] = a0; xp[1] = a1;
      u16x8 o;
      o[0]=f2b(a0.x); o[1]=f2b(a0.y); o[2]=f2b(a0.z); o[3]=f2b(a0.w);
      o[4]=f2b(a1.x); o[5]=f2b(a1.y); o[6]=f2b(a1.z); o[7]=f2b(a1.w);
      *reinterpret_cast<u16x8*>((unsigned short*)xb + (size_t)n*DD + lane*8) = o;
    }
  }
}

// ---------------- final: LDS-staged per-group partials, few global atomics ----------------
__global__ __launch_bounds__(256) void h2_kernel(const float* __restrict__ t,
    const float* __restrict__ Wh2, const int* __restrict__ batch, float* __restrict__ out) {
  __shared__ float part[GG];
  for (int i = threadIdx.x; i < GG; i += 256) part[i] = 0.f;
  __syncthreads();
  const int wid = threadIdx.x >> 6, lane = threadIdx.x & 63;
  const int per_block = (NN + gridDim.x - 1) / gridDim.x;
  const int n0 = blockIdx.x * per_block;
  const int n1 = min(NN, n0 + per_block);
  for (int n = n0 + wid; n < n1; n += 4) {
    float s = 0.f;
    if (lane < 60) {
      const float4* tp = (const float4*)(t + (size_t)n*DD + lane*8);
      const float4* wp = (const float4*)(Wh2 + lane*8);
      float4 t0 = tp[0], t1 = tp[1], w0 = wp[0], w1 = wp[1];
      s = t0.x*w0.x+t0.y*w0.y+t0.z*w0.z+t0.w*w0.w
        + t1.x*w1.x+t1.y*w1.y+t1.z*w1.z+t1.w*w1.w;
    }
    s = wsum(s);
    if (lane == 0) atomicAdd(&part[batch[n]], s * INV_AVG_NODES);
  }
  __syncthreads();
  for (int i = threadIdx.x; i < GG; i += 256) {
    float v = part[i];
    if (v != 0.f) atomicAdd(&out[i], v);
  }
}

extern "C" void kernel_launch(void* const* d_in, const int* in_sizes, int n_in,
                              void* d_out, int out_size, void* d_ws, size_t ws_size,
                              hipStream_t stream) {
  const float* pos        = (const float*)d_in[0];
  const int*   node_atom  = (const int*)  d_in[1];
  const int*   edge_src   = (const int*)  d_in[2];
  const int*   edge_dst   = (const int*)  d_in[3];
  const int*   batch      = (const int*)  d_in[4];
  const float* atom_table = (const float*)d_in[5];
  const float* Wdeg       = (const float*)d_in[6];
  const float* Wd1        = (const float*)d_in[7];
  const float* Wd2        = (const float*)d_in[8];
  const float* Wd3        = (const float*)d_in[9];
  const float* Wq         = (const float*)d_in[10];
  const float* Wk         = (const float*)d_in[11];
  const float* Wv         = (const float*)d_in[12];
  const float* Wsh        = (const float*)d_in[13];
  const float* W1         = (const float*)d_in[14];
  const float* W2         = (const float*)d_in[15];
  const float* W3         = (const float*)d_in[16];
  const float* Wo         = (const float*)d_in[17];
  const float* Wf1        = (const float*)d_in[18];
  const float* Wf2        = (const float*)d_in[19];
  const float* Wh1        = (const float*)d_in[20];
  const float* Wh2        = (const float*)d_in[21];
  float* out = (float*)d_out;
  char*  wsb = (char*)d_ws;

  size_t off = 0;
  auto alloc = [&](size_t bytes) { size_t o = off; off += (bytes + 255) & ~(size_t)255; return o; };
  float*  x      = (float*) (wsb + alloc((size_t)NN*DD*4));
  __hip_bfloat16* xb   = (__hip_bfloat16*)(wsb + alloc((size_t)NN*DD*2));
  __hip_bfloat16* xq   = (__hip_bfloat16*)(wsb + alloc((size_t)NN*DD*2));
  __hip_bfloat16* xk   = (__hip_bfloat16*)(wsb + alloc((size_t)NN*DD*2));
  __hip_bfloat16* xv   = (__hip_bfloat16*)(wsb + alloc((size_t)NN*DD*2));
  float*  shb    = (float*) (wsb + alloc((size_t)EE*9*4));
  float*  dedge  = (float*) (wsb + alloc((size_t)EE*4));
  float*  P      = (float*) (wsb + alloc((size_t)NN*36*4));
  float2* sbuf   = (float2*)(wsb + alloc((size_t)EE*4*8));
  __hip_bfloat16* aggb = (__hip_bfloat16*)(wsb + alloc((size_t)NN*DD*2));
  float*  tmp480 = (float*) (wsb + alloc((size_t)NN*DD*4));
  __hip_bfloat16* tmp960 = (__hip_bfloat16*)(wsb + alloc((size_t)NN*960*2));
  float*  Tg     = (float*) (wsb + alloc((size_t)TSIZE*4));
  float*  Tl     = (float*) (wsb + alloc((size_t)LLAYERS*TSIZE*4*4));
  __hip_bfloat16* Wqkvt = (__hip_bfloat16*)(wsb + alloc((size_t)LLAYERS*1536*480*2));
  __hip_bfloat16* Wot   = (__hip_bfloat16*)(wsb + alloc((size_t)LLAYERS*512*480*2));
  __hip_bfloat16* Wf1t  = (__hip_bfloat16*)(wsb + alloc((size_t)LLAYERS*1024*480*2));
  __hip_bfloat16* Wf2t  = (__hip_bfloat16*)(wsb + alloc((size_t)LLAYERS*512*960*2));
  __hip_bfloat16* Wh1t  = (__hip_bfloat16*)(wsb + alloc((size_t)512*480*2));
  int* cnt     = (int*)(wsb + alloc((size_t)NN*4));
  int* row_ptr = (int*)(wsb + alloc((size_t)(NN+1)*4));
  int* cursor  = (int*)(wsb + alloc((size_t)NN*4));
  int* eid     = (int*)(wsb + alloc((size_t)EE*4));
  int* srcs    = (int*)(wsb + alloc((size_t)EE*4));
  (void)ws_size;

  auto tr = [&](const float* W, __hip_bfloat16* Wt, int K, int N, int Npad,
                long long lsW, long long lsT, int L) {
    dim3 g((Npad+31)/32, (K+31)/32, L);
    transpose_w_kernel<<<g, 256, 0, stream>>>(W, Wt, K, N, Npad, lsW, lsT);
  };

  tr(Wq,  Wqkvt + 0*512*480,    480, 480, 512, 480*480, 1536*480, LLAYERS);
  tr(Wk,  Wqkvt + 1*512*480,    480, 480, 512, 480*480, 1536*480, LLAYERS);
  tr(Wv,  Wqkvt + 2*512*480,    480, 480, 512, 480*480, 1536*480, LLAYERS);
  tr(Wo,  Wot,  480, 480, 512, 480*480, 512*480, LLAYERS);
  tr(Wf1, Wf1t, 480, 960, 1024, 480*960, 1024*480, LLAYERS);
  tr(Wf2, Wf2t, 960, 480, 512, 960*480, 512*960, LLAYERS);
  tr(Wh1, Wh1t, 480, 480, 512, 480*480, 512*480, 1);

  zero_kernel<<<(NN+255)/256, 256, 0, stream>>>(cnt, out);
  gather_x_kernel<<<640, 256, 0, stream>>>(atom_table, node_atom, x);
  edge_geom_kernel<<<(EE+255)/256, 256, 0, stream>>>(pos, edge_src, edge_dst, shb, dedge);
  hist_kernel<<<(EE+255)/256, 256, 0, stream>>>(edge_dst, cnt);
  scan_kernel<<<1, 1024, 0, stream>>>(cnt, row_ptr, cursor);
  scatter_kernel<<<(EE+255)/256, 256, 0, stream>>>(edge_src, edge_dst, cursor, eid, srcs);
  table_kernel<<<dim3(TSIZE/16, 1+LLAYERS), 1024, 0, stream>>>(Wd1, Wd2, Wd3, W1, W2, W3, Tg, Tl);
  deg_kernel<<<2500, 256, 0, stream>>>(dedge, shb, Tg, row_ptr, eid, Wdeg, x, xb);

  for (int l = 0; l < LLAYERS; ++l) {
    const __hip_bfloat16* Wqkvt_l = Wqkvt + (size_t)l*1536*480;
    const __hip_bfloat16* Wot_l   = Wot   + (size_t)l*512*480;
    const __hip_bfloat16* Wf1t_l  = Wf1t  + (size_t)l*1024*480;
    const __hip_bfloat16* Wf2t_l  = Wf2t  + (size_t)l*512*960;
    const float* Wsh_l = Wsh + (size_t)l*9*DD;
    const float* Tl_l  = Tl  + (size_t)l*TSIZE*4;

    gemm_bf16_kernel<0,2><<<dim3(12, 79), 512, 0, stream>>>(xb, Wqkvt_l, nullptr, xq, xk, xv, NN, 480, 480);
    p_kernel<<<2500, 256, 0, stream>>>(xq, Wsh_l, P);
    coef_kernel<<<(EE+255)/256, 256, 0, stream>>>(eid, edge_dst, shb, dedge, Tl_l, P, sbuf);
    attn_kernel<<<2500, 256, 0, stream>>>(xq, xk, xv, sbuf, row_ptr, srcs, aggb);
    gemm_bf16_kernel<0,0><<<dim3(4, 79), 512, 0, stream>>>(aggb, Wot_l, tmp480, nullptr, nullptr, nullptr, NN, 480, 480);
    ln_kernel<<<640, 256, 0, stream>>>(x, tmp480, xb);
    gemm_bf16_kernel<1,1><<<dim3(8, 79), 512, 0, stream>>>(xb, Wf1t_l, nullptr, tmp960, nullptr, nullptr, NN, 480, 960);
    gemm_bf16_kernel<0,0><<<dim3(4, 79), 512, 0, stream>>>(tmp960, Wf2t_l, tmp480, nullptr, nullptr, nullptr, NN, 960, 480);
    ln_kernel<<<640, 256, 0, stream>>>(x, tmp480, xb);
  }

  gemm_bf16_kernel<1,0><<<dim3(4, 79), 512, 0, stream>>>(xb, Wh1t, tmp480, nullptr, nullptr, nullptr, NN, 480, 480);
  h2_kernel<<<160, 256, 0, stream>>>(tmp480, Wh2, batch, out);
}